// Round 4
// baseline (1764.973 us; speedup 1.0000x reference)
//
#include <hip/hip_runtime.h>
#include <hip/hip_bf16.h>

typedef __hip_bfloat16 bf16;
__device__ __forceinline__ float b2f(bf16 v){ return __bfloat162float(v); }
__device__ __forceinline__ bf16 f2b(float v){ return __float2bfloat16(v); }
__device__ __forceinline__ float ldf(const float* p, size_t i){ return p[i]; }
__device__ __forceinline__ float ldf(const bf16* p, size_t i){ return b2f(p[i]); }

#define NN 50000
#define NE 250000
#define NEA 500000
#define NR 300
#define EHD 300
#define THD 100
#define RHD 100

__device__ __forceinline__ int clampi(int v, int n){ return ((unsigned)v < (unsigned)n) ? v : 0; }

// ---------- zero fill ----------
__global__ void k_zero_i32(int* __restrict__ p, int n){
    int i = blockIdx.x*256 + threadIdx.x;
    if(i < n) p[i] = 0;
}
__global__ void k_zero_f32(float* __restrict__ p, int n){
    int i = blockIdx.x*256 + threadIdx.x;
    if(i < n) p[i] = 0.f;
}

// ---------- degree counting ----------
__global__ void k_count(const int* __restrict__ ji, const int* __restrict__ ht,
                        const int* __restrict__ rel,
                        int* deg_all, int* deg_h, int* deg_t, int* cnt_rel){
    int e = blockIdx.x*256 + threadIdx.x;
    if(e < NEA) atomicAdd(&deg_all[clampi(ji[NEA + e], NN)], 1);
    if(e < NE){
        atomicAdd(&deg_h[clampi(ht[e], NN)], 1);
        atomicAdd(&deg_t[clampi(ht[NE + e], NN)], 1);
        atomicAdd(&cnt_rel[clampi(rel[e], NR)], 1);
    }
}

// ---------- exclusive scan (one block per array, 3 arrays) ----------
__global__ void k_scan(const int* deg_all, int* off_all, int* cur_all,
                       const int* deg_h,   int* off_h,   int* cur_h,
                       const int* deg_t,   int* off_t,   int* cur_t){
    const int* deg; int* off; int* cur;
    if(blockIdx.x == 0){ deg=deg_all; off=off_all; cur=cur_all; }
    else if(blockIdx.x == 1){ deg=deg_h; off=off_h; cur=cur_h; }
    else { deg=deg_t; off=off_t; cur=cur_t; }
    __shared__ int lds[1024];
    int tid = threadIdx.x;
    const int CH = (NN + 1023)/1024;           // 49
    int lo = tid*CH, hi = lo+CH; if(hi > NN) hi = NN; if(lo > NN) lo = NN;
    int lsum = 0;
    for(int k=lo;k<hi;k++) lsum += deg[k];
    lds[tid] = lsum; __syncthreads();
    for(int s=1;s<1024;s<<=1){
        int v = (tid >= s) ? lds[tid-s] : 0;
        __syncthreads();
        lds[tid] += v;
        __syncthreads();
    }
    int excl = lds[tid] - lsum;
    int run = excl;
    for(int k=lo;k<hi;k++){ off[k]=run; cur[k]=run; run += deg[k]; }
    if(tid == 1023) off[NN] = lds[1023];
}

// ---------- CSR fill ----------
__global__ void k_fill(const int* __restrict__ ji, const int* __restrict__ ht,
                       const int* __restrict__ rel,
                       int* cur_all, int* adj_all_j,
                       int* cur_h, int* adj_h_rel,
                       int* cur_t, int* adj_t_rel){
    int e = blockIdx.x*256 + threadIdx.x;
    if(e < NEA){
        int i = clampi(ji[NEA + e], NN), j = clampi(ji[e], NN);
        int p = clampi(atomicAdd(&cur_all[i], 1), NEA);
        adj_all_j[p] = j;
    }
    if(e < NE){
        int r = clampi(rel[e], NR);
        int p = clampi(atomicAdd(&cur_h[clampi(ht[e], NN)], 1), NE);      adj_h_rel[p] = r;
        int q = clampi(atomicAdd(&cur_t[clampi(ht[NE + e], NN)], 1), NE); adj_t_rel[q] = r;
    }
}

__global__ void k_dinv(const int* __restrict__ deg, float* __restrict__ dinv){
    int n = blockIdx.x*256 + threadIdx.x;
    if(n < NN){ int d = deg[n]; dinv[n] = d > 0 ? rsqrtf((float)d) : 0.f; }
}

// ---------- GCN gather: xd[n] = relu(sum norm * xs[j]) ; wave per node ----------
template<typename TS>
__global__ void k_gcn(const TS* __restrict__ xs, bf16* __restrict__ xd,
                      const int* __restrict__ off, const int* __restrict__ adjj,
                      const float* __restrict__ dinv){
    int wid = threadIdx.x >> 6, lane = threadIdx.x & 63;
    int n = blockIdx.x*4 + wid;
    if(n >= NN) return;
    float acc[5] = {0,0,0,0,0};
    float di = dinv[n];
    int s0 = off[n], s1 = off[n+1];
    for(int it=s0; it<s1; it++){
        int j = clampi(adjj[it], NN);
        float nr = di * dinv[j];
        const TS* xr = xs + (size_t)j*EHD;
        #pragma unroll
        for(int k=0;k<5;k++){ int d = lane + 64*k; if(d < EHD) acc[k] += nr * ldf(xr, d); }
    }
    bf16* xo = xd + (size_t)n*EHD;
    #pragma unroll
    for(int k=0;k<5;k++){ int d = lane + 64*k; if(d < EHD) xo[d] = f2b(fmaxf(acc[k], 0.f)); }
}

// ---------- tiled GEMM (f32 weights, f32 compute). MODE 0: out = X@W+b (bf16). MODE 1: highway gate combine ----------
template<int MODE, typename TX>
__global__ void k_gemm(const TX* __restrict__ X, const float* __restrict__ W,
                       const float* __restrict__ bias, bf16* __restrict__ out,
                       int M, int K, int Ncols){
    __shared__ float As[20][68];
    __shared__ float Bs[20][68];
    int tid = threadIdx.x;
    int bm = blockIdx.x*64, bn = blockIdx.y*64;
    int tx = tid & 15, ty = tid >> 4;
    float acc[4][4] = {};
    for(int k0=0; k0<K; k0+=20){
        for(int idx=tid; idx<64*20; idx+=256){
            int m = idx/20, kk = idx%20;
            int gm = bm+m, gk = k0+kk;
            As[kk][m] = (gm < M && gk < K) ? ldf(X, (size_t)gm*K + gk) : 0.f;
        }
        for(int idx=tid; idx<20*64; idx+=256){
            int kk = idx/64, nn2 = idx%64;
            int gk = k0+kk, gn = bn+nn2;
            Bs[kk][nn2] = (gk < K && gn < Ncols) ? W[(size_t)gk*Ncols + gn] : 0.f;
        }
        __syncthreads();
        #pragma unroll
        for(int kk=0;kk<20;kk++){
            float a[4], b[4];
            #pragma unroll
            for(int i=0;i<4;i++) a[i] = As[kk][ty*4+i];
            #pragma unroll
            for(int j=0;j<4;j++) b[j] = Bs[kk][tx*4+j];
            #pragma unroll
            for(int i=0;i<4;i++)
                #pragma unroll
                for(int j=0;j<4;j++) acc[i][j] += a[i]*b[j];
        }
        __syncthreads();
    }
    #pragma unroll
    for(int i=0;i<4;i++){
        int gm = bm + ty*4 + i;
        if(gm >= M) continue;
        #pragma unroll
        for(int j=0;j<4;j++){
            int gn = bn + tx*4 + j;
            if(gn >= Ncols) continue;
            float t = acc[i][j] + bias[gn];
            size_t p = (size_t)gm*Ncols + gn;
            if(MODE == 0){
                out[p] = f2b(t);
            } else {
                // out holds gcn agg; X (stride == Ncols here) holds previous x
                float g = 1.f/(1.f + expf(-t));
                out[p] = f2b(g*b2f(out[p]) + (1.f - g)*ldf(X, p));
            }
        }
    }
}

// ---------- per-relation sums of s[h], s[t] (atomic f32) ; wave per edge ----------
__global__ void k_relsum(const bf16* __restrict__ s, const int* __restrict__ ht,
                         const int* __restrict__ rel,
                         float* __restrict__ mh, float* __restrict__ mt){
    int wid = threadIdx.x >> 6, lane = threadIdx.x & 63;
    int e = blockIdx.x*4 + wid;
    if(e >= NE) return;
    int r = clampi(rel[e], NR), hh = clampi(ht[e], NN), tt = clampi(ht[NE + e], NN);
    #pragma unroll
    for(int k=0;k<2;k++){
        int d = lane + 64*k;
        if(d < THD){
            atomicAdd(&mh[r*THD + d], b2f(s[(size_t)hh*THD + d]));
            atomicAdd(&mt[r*THD + d], b2f(s[(size_t)tt*THD + d]));
        }
    }
}

// RF layout per relation r (300 floats): [x_type(0..99) | mh/cnt(100..199) | mt/cnt(200..299)]
__global__ void k_relnorm(const float* __restrict__ mh, const float* __restrict__ mt,
                          const int* __restrict__ cnt, float* __restrict__ RF){
    int r = blockIdx.x, d = threadIdx.x;
    if(d >= THD) return;
    float c = (float)(cnt[r] > 1 ? cnt[r] : 1);
    RF[(size_t)r*EHD + THD   + d] = mh[r*THD + d] / c;
    RF[(size_t)r*EHD + 2*THD + d] = mt[r*THD + d] / c;
}

__global__ void k_relx2(const float* __restrict__ sr1w, const float* __restrict__ sr1b,
                        const int* __restrict__ cnt, float* __restrict__ RF){
    int r = blockIdx.x, k = threadIdx.x;
    if(k >= RHD) return;
    float v = 0.f;
    if(cnt[r] > 0){
        v = sr1b[k];
        for(int d=0; d<2*THD; d++) v += RF[(size_t)r*EHD + THD + d] * sr1w[d*RHD + k];
    }
    RF[(size_t)r*EHD + k] = v;   // x_type (== x_res2 row, or 0 for empty rel)
}

// ER[kk][r][o] = RF[r] @ wr_kk + br_kk
__global__ void k_reler(const float* __restrict__ RF,
                        const float* w0, const float* b0, const float* w1, const float* b1,
                        const float* w2, const float* b2, float* __restrict__ ER){
    int r = blockIdx.x, kk = blockIdx.y;
    const float* w = kk==0 ? w0 : (kk==1 ? w1 : w2);
    const float* b = kk==0 ? b0 : (kk==1 ? b1 : b2);
    for(int o = threadIdx.x; o < EHD; o += 256){
        float v = b[o];
        for(int d=0; d<EHD; d++) v += RF[(size_t)r*EHD + d] * w[(size_t)d*EHD + o];
        ER[((size_t)kk*NR + r)*EHD + o] = v;
    }
}

__global__ void k_relc(const float* __restrict__ ER, const float* ar1, const float* ar2,
                       const float* ar3, float* __restrict__ cvec){
    int r = blockIdx.x, kk = blockIdx.y, lane = threadIdx.x;
    const float* a = kk==0 ? ar1 : (kk==1 ? ar2 : ar3);
    float p = 0;
    #pragma unroll
    for(int k=0;k<5;k++){ int d = lane + 64*k; if(d < EHD) p += ER[((size_t)kk*NR + r)*EHD + d]*a[d]; }
    #pragma unroll
    for(int m=32;m>=1;m>>=1) p += __shfl_xor(p, m);
    if(lane == 0) cvec[kk*NR + r] = p;
}

// ---------- r2e round: x[n] += relu( sum_e alpha_e * ER[rel_e] ) ; wave per node; bf16 x in-place ----------
__global__ void k_r2e(bf16* __restrict__ x, const int* __restrict__ off,
                      const int* __restrict__ adjrel, const float* __restrict__ ERk,
                      const float* __restrict__ ck, const float* __restrict__ anode){
    int wid = threadIdx.x >> 6, lane = threadIdx.x & 63;
    int n = blockIdx.x*4 + wid;
    if(n >= NN) return;
    bf16* xr = x + (size_t)n*EHD;
    float xv[5];
    float p = 0;
    #pragma unroll
    for(int k=0;k<5;k++){
        int d = lane + 64*k;
        xv[k] = (d < EHD) ? b2f(xr[d]) : 0.f;
        if(d < EHD) p += xv[k]*anode[d];
    }
    #pragma unroll
    for(int m=32;m>=1;m>>=1) p += __shfl_xor(p, m);   // p = xdot[n] on every lane
    int s0 = off[n], s1 = off[n+1];
    if(s0 == s1) return;
    float mx = -1e30f;
    for(int it=s0; it<s1; it++){
        float lg = p + ck[clampi(adjrel[it], NR)];
        lg = lg > 0 ? lg : 0.01f*lg;
        mx = fmaxf(mx, lg);
    }
    float ss = 0;
    for(int it=s0; it<s1; it++){
        float lg = p + ck[clampi(adjrel[it], NR)];
        lg = lg > 0 ? lg : 0.01f*lg;
        ss += expf(lg - mx);
    }
    float acc[5] = {0,0,0,0,0};
    for(int it=s0; it<s1; it++){
        int r = clampi(adjrel[it], NR);
        float lg = p + ck[r];
        lg = lg > 0 ? lg : 0.01f*lg;
        float a = expf(lg - mx)/ss;
        const float* er = ERk + (size_t)r*EHD;
        #pragma unroll
        for(int k=0;k<5;k++){ int d = lane + 64*k; if(d < EHD) acc[k] += a*er[d]; }
    }
    #pragma unroll
    for(int k=0;k<5;k++){ int d = lane + 64*k; if(d < EHD) xr[d] = f2b(xv[k] + fmaxf(acc[k], 0.f)); }
}

// ---------- per-node dot (ajv = x @ ajw) ----------
__global__ void k_dot(const bf16* __restrict__ x, const float* __restrict__ a,
                      float* __restrict__ out){
    int wid = threadIdx.x >> 6, lane = threadIdx.x & 63;
    int n = blockIdx.x*4 + wid;
    if(n >= NN) return;
    const bf16* xr = x + (size_t)n*EHD;
    float p = 0;
    #pragma unroll
    for(int k=0;k<5;k++){ int d = lane + 64*k; if(d < EHD) p += b2f(xr[d])*a[d]; }
    #pragma unroll
    for(int m=32;m>=1;m>>=1) p += __shfl_xor(p, m);
    if(lane == 0) out[n] = p;
}

// ---------- final GAT + fc (f32 output) ----------
__global__ void k_final(const bf16* __restrict__ x, const float* __restrict__ ajv,
                        const int* __restrict__ off, const int* __restrict__ adjj,
                        const float* __restrict__ aiw, const float* __restrict__ fcw,
                        const float* __restrict__ fcb, float* __restrict__ out){
    int wid = threadIdx.x >> 6, lane = threadIdx.x & 63;
    int n = blockIdx.x*4 + wid;
    if(n >= NN) return;
    const bf16* xr = x + (size_t)n*EHD;
    float p = 0;
    #pragma unroll
    for(int k=0;k<5;k++){ int d = lane + 64*k; if(d < EHD) p += b2f(xr[d])*aiw[d]; }
    #pragma unroll
    for(int m=32;m>=1;m>>=1) p += __shfl_xor(p, m);   // ai[n]
    int s0 = off[n], s1 = off[n+1];
    float acc[5] = {0,0,0,0,0};
    if(s0 < s1){
        float mx = -1e30f;
        for(int it=s0; it<s1; it++){
            float lg = p + ajv[clampi(adjj[it], NN)];
            lg = lg > 0 ? lg : 0.01f*lg;
            mx = fmaxf(mx, lg);
        }
        float ss = 0;
        for(int it=s0; it<s1; it++){
            float lg = p + ajv[clampi(adjj[it], NN)];
            lg = lg > 0 ? lg : 0.01f*lg;
            ss += expf(lg - mx);
        }
        for(int it=s0; it<s1; it++){
            int j = clampi(adjj[it], NN);
            float lg = p + ajv[j];
            lg = lg > 0 ? lg : 0.01f*lg;
            float a = expf(lg - mx)/ss;
            const bf16* xj = x + (size_t)j*EHD;
            #pragma unroll
            for(int k=0;k<5;k++){ int d = lane + 64*k; if(d < EHD) acc[k] += a*b2f(xj[d]); }
        }
    }
    float part = 0;
    #pragma unroll
    for(int k=0;k<5;k++){
        int d = lane + 64*k;
        if(d < EHD) part += b2f(xr[d])*fcw[d] + fmaxf(acc[k], 0.f)*fcw[EHD + d];
    }
    #pragma unroll
    for(int m=32;m>=1;m>>=1) part += __shfl_xor(part, m);
    if(lane == 0) out[n] = part + fcb[0];
}

extern "C" void kernel_launch(void* const* d_in, const int* in_sizes, int n_in,
                              void* d_out, int out_size, void* d_ws, size_t ws_size,
                              hipStream_t stream){
    // Reference uses jnp.float32 everywhere -> all float tensors are f32 on device.
    const float* x_in = (const float*)d_in[0];
    const int*  ht   = (const int*)d_in[1];   // [0,NE)=h, [NE,2NE)=t
    const int*  rel  = (const int*)d_in[2];
    const int*  ji   = (const int*)d_in[3];   // [0,NEA)=j, [NEA,2NEA)=i
    const float* hw1w=(const float*)d_in[5];  const float* hw1b=(const float*)d_in[6];
    const float* hw2w=(const float*)d_in[7];  const float* hw2b=(const float*)d_in[8];
    const float* tc1w=(const float*)d_in[9];  const float* tc1b=(const float*)d_in[10];
    const float* sr1w=(const float*)d_in[11]; const float* sr1b=(const float*)d_in[12];
    // d_in[13]=a1_w, d_in[14]=a5_w: mathematically dead (uniform per-segment logits)
    const float* wrw =(const float*)d_in[15]; const float* wrb =(const float*)d_in[16];
    const float* wr1w=(const float*)d_in[17]; const float* wr1b=(const float*)d_in[18];
    const float* wr2w=(const float*)d_in[19]; const float* wr2b=(const float*)d_in[20];
    const float* ahw =(const float*)d_in[21]; const float* ah1w=(const float*)d_in[22];
    const float* atw =(const float*)d_in[23];
    const float* ar1 =(const float*)d_in[24]; const float* ar2 =(const float*)d_in[25];
    const float* ar3 =(const float*)d_in[26];
    const float* aiw =(const float*)d_in[27]; const float* ajw =(const float*)d_in[28];
    const float* fcw =(const float*)d_in[29]; const float* fcb =(const float*)d_in[30];
    float* out = (float*)d_out;

    // ---- workspace layout: ~66 MB. Feature scratch bf16, compute f32. ----
    char* w = (char*)d_ws;
    auto alloc = [&](size_t bytes)->char*{ char* p = w; w += (bytes + 255)/256*256; return p; };
    bf16* B  = (bf16*)alloc((size_t)NN*EHD*2);   // 30 MB; agg1 -> x1, dead after hw2 GEMM
    bf16* xF = (bf16*)alloc((size_t)NN*EHD*2);   // 30 MB; agg2 -> x2 .. final x
    char* Bc = (char*)B;
    bf16*  sbuf = (bf16*)(Bc);                        // 10 MB  [NN*THD] bf16
    float* mh   = (float*)(Bc + 11u*1024*1024);       // 120 KB f32
    float* mt   = (float*)(Bc + 12u*1024*1024);       // 120 KB f32
    float* RF   = (float*)(Bc + 13u*1024*1024);       // 360 KB f32
    float* ER   = (float*)(Bc + 14u*1024*1024);       // 1.08 MB f32
    float* cvec = (float*)(Bc + 16u*1024*1024);       // 3.6 KB
    float* ajv  = (float*)(Bc + 17u*1024*1024);       // 200 KB f32
    float* dinv = (float*)alloc((size_t)NN*4);
    int* deg_all=(int*)alloc(NN*4); int* off_all=(int*)alloc((NN+1)*4); int* cur_all=(int*)alloc(NN*4);
    int* adj_all=(int*)alloc((size_t)NEA*4);
    int* deg_h  =(int*)alloc(NN*4); int* off_h  =(int*)alloc((NN+1)*4); int* cur_h  =(int*)alloc(NN*4);
    int* adj_h  =(int*)alloc((size_t)NE*4);
    int* deg_t  =(int*)alloc(NN*4); int* off_t  =(int*)alloc((NN+1)*4); int* cur_t  =(int*)alloc(NN*4);
    int* adj_t  =(int*)alloc((size_t)NE*4);
    int* cnt_rel=(int*)alloc(NR*4);

    const int nbN = (NN+255)/256;
    k_zero_i32<<<dim3(nbN), dim3(256), 0, stream>>>(deg_all, NN);
    k_zero_i32<<<dim3(nbN), dim3(256), 0, stream>>>(deg_h, NN);
    k_zero_i32<<<dim3(nbN), dim3(256), 0, stream>>>(deg_t, NN);
    k_zero_i32<<<dim3(2),   dim3(256), 0, stream>>>(cnt_rel, NR);

    k_count<<<dim3((NEA+255)/256), dim3(256), 0, stream>>>(ji, ht, rel, deg_all, deg_h, deg_t, cnt_rel);
    k_scan<<<dim3(3), dim3(1024), 0, stream>>>(deg_all, off_all, cur_all, deg_h, off_h, cur_h, deg_t, off_t, cur_t);
    k_fill<<<dim3((NEA+255)/256), dim3(256), 0, stream>>>(ji, ht, rel, cur_all, adj_all, cur_h, adj_h, cur_t, adj_t);
    k_dinv<<<dim3(nbN), dim3(256), 0, stream>>>(deg_all, dinv);

    const int nb4 = (NN+3)/4;
    // highway 1: B = gcn(x_in); B = sig(x_in@hw1+b)*B + (1-sig)*x_in   (=> B = x1)
    k_gcn<float><<<dim3(nb4), dim3(256), 0, stream>>>(x_in, B, off_all, adj_all, dinv);
    k_gemm<1,float><<<dim3((NN+63)/64, (EHD+63)/64), dim3(256), 0, stream>>>(x_in, hw1w, hw1b, B, NN, EHD, EHD);
    // highway 2: xF = gcn(B); xF = sig(B@hw2+b)*xF + (1-sig)*B        (=> xF = x2)
    k_gcn<bf16><<<dim3(nb4), dim3(256), 0, stream>>>(B, xF, off_all, adj_all, dinv);
    k_gemm<1,bf16><<<dim3((NN+63)/64, (EHD+63)/64), dim3(256), 0, stream>>>(B, hw2w, hw2b, xF, NN, EHD, EHD);
    // ---- B is now dead; its aliases (sbuf, mh, mt, RF, ER, cvec, ajv) come alive ----
    k_zero_f32<<<dim3((NR*THD+255)/256), dim3(256), 0, stream>>>(mh, NR*THD);
    k_zero_f32<<<dim3((NR*THD+255)/256), dim3(256), 0, stream>>>(mt, NR*THD);
    // s = x2 @ tc1 + b  (bf16 sbuf)
    k_gemm<0,bf16><<<dim3((NN+63)/64, (THD+63)/64), dim3(256), 0, stream>>>(xF, tc1w, tc1b, sbuf, NN, EHD, THD);
    // per-relation tables
    k_relsum<<<dim3((NE+3)/4), dim3(256), 0, stream>>>(sbuf, ht, rel, mh, mt);
    k_relnorm<<<dim3(NR), dim3(128), 0, stream>>>(mh, mt, cnt_rel, RF);
    k_relx2<<<dim3(NR), dim3(128), 0, stream>>>(sr1w, sr1b, cnt_rel, RF);
    k_reler<<<dim3(NR, 3), dim3(256), 0, stream>>>(RF, wrw, wrb, wr1w, wr1b, wr2w, wr2b, ER);
    k_relc<<<dim3(NR, 3), dim3(64), 0, stream>>>(ER, ar1, ar2, ar3, cvec);
    // three r2e rounds (in-place on xF)
    k_r2e<<<dim3(nb4), dim3(256), 0, stream>>>(xF, off_h, adj_h, ER,                     cvec,        ahw);
    k_r2e<<<dim3(nb4), dim3(256), 0, stream>>>(xF, off_t, adj_t, ER + (size_t)NR*EHD,    cvec + NR,   atw);
    k_r2e<<<dim3(nb4), dim3(256), 0, stream>>>(xF, off_h, adj_h, ER + (size_t)2*NR*EHD,  cvec + 2*NR, ah1w);
    // final GAT + fc
    k_dot<<<dim3(nb4), dim3(256), 0, stream>>>(xF, ajw, ajv);
    k_final<<<dim3(nb4), dim3(256), 0, stream>>>(xF, ajv, off_all, adj_all, aiw, fcw, fcb, out);
}

// Round 5
// 1760.047 us; speedup vs baseline: 1.0028x; 1.0028x over previous
//
#include <hip/hip_runtime.h>
#include <hip/hip_bf16.h>

typedef __hip_bfloat16 bf16;
typedef __attribute__((ext_vector_type(8))) short bf16x8_t;
typedef __attribute__((ext_vector_type(4))) float f32x4_t;

__device__ __forceinline__ float b2f(bf16 v){ return __bfloat162float(v); }
__device__ __forceinline__ bf16 f2b(float v){ return __float2bfloat16(v); }
__device__ __forceinline__ short tobits(float v){ bf16 b = f2b(v); return *(short*)&b; }
__device__ __forceinline__ short tobits(bf16 v){ return *(short*)&v; }

#define NN 50000
#define NE 250000
#define NEA 500000
#define NR 300
#define EHD 300
#define THD 100
#define RHD 100

__device__ __forceinline__ int clampi(int v, int n){ return ((unsigned)v < (unsigned)n) ? v : 0; }

// ---------- zero fill ----------
__global__ void k_zero_i32(int* __restrict__ p, int n){
    int i = blockIdx.x*256 + threadIdx.x;
    if(i < n) p[i] = 0;
}

// ---------- f32 -> bf16 cast, 4 elems/thread ----------
__global__ void k_cast4(const float4* __restrict__ in, ushort* __restrict__ out, int n4){
    int i = blockIdx.x*256 + threadIdx.x;
    if(i >= n4) return;
    float4 v = in[i];
    ushort4 o;
    o.x = (ushort)tobits(v.x); o.y = (ushort)tobits(v.y);
    o.z = (ushort)tobits(v.z); o.w = (ushort)tobits(v.w);
    *(ushort4*)(out + 4*(size_t)i) = o;
}

// ---------- W [K][N] f32 -> Wt [N][K] bf16 bits ----------
__global__ void k_prepw(const float* __restrict__ W, short* __restrict__ Wt, int K, int N){
    int i = blockIdx.x*256 + threadIdx.x;
    if(i < N*K){
        int n = i / K, k = i - n*K;
        Wt[i] = tobits(W[(size_t)k*N + n]);
    }
}

// ---------- degree counting ----------
__global__ void k_count(const int* __restrict__ ji, const int* __restrict__ ht,
                        const int* __restrict__ rel,
                        int* deg_all, int* deg_h, int* deg_t, int* cnt_rel){
    int e = blockIdx.x*256 + threadIdx.x;
    if(e < NEA) atomicAdd(&deg_all[clampi(ji[NEA + e], NN)], 1);
    if(e < NE){
        atomicAdd(&deg_h[clampi(ht[e], NN)], 1);
        atomicAdd(&deg_t[clampi(ht[NE + e], NN)], 1);
        atomicAdd(&cnt_rel[clampi(rel[e], NR)], 1);
    }
}

// ---------- exclusive scan (one block per array, 4 arrays) ----------
__global__ void k_scan(const int* d0, int* o0, int* c0,
                       const int* d1, int* o1, int* c1,
                       const int* d2, int* o2, int* c2,
                       const int* d3, int* o3, int* c3){
    const int* deg; int* off; int* cur; int len;
    if(blockIdx.x == 0){ deg=d0; off=o0; cur=c0; len=NN; }
    else if(blockIdx.x == 1){ deg=d1; off=o1; cur=c1; len=NN; }
    else if(blockIdx.x == 2){ deg=d2; off=o2; cur=c2; len=NN; }
    else { deg=d3; off=o3; cur=c3; len=NR; }
    __shared__ int lds[1024];
    int tid = threadIdx.x;
    const int CH = (len + 1023)/1024;
    int lo = tid*CH, hi = lo+CH; if(hi > len) hi = len; if(lo > len) lo = len;
    int lsum = 0;
    for(int k=lo;k<hi;k++) lsum += deg[k];
    lds[tid] = lsum; __syncthreads();
    for(int s=1;s<1024;s<<=1){
        int v = (tid >= s) ? lds[tid-s] : 0;
        __syncthreads();
        lds[tid] += v;
        __syncthreads();
    }
    int excl = lds[tid] - lsum;
    int run = excl;
    for(int k=lo;k<hi;k++){ off[k]=run; cur[k]=run; run += deg[k]; }
    if(tid == 1023) off[len] = lds[1023];
}

// ---------- CSR fill ----------
__global__ void k_fill(const int* __restrict__ ji, const int* __restrict__ ht,
                       const int* __restrict__ rel,
                       int* cur_all, int* adj_all_j,
                       int* cur_h, int* adj_h_rel,
                       int* cur_t, int* adj_t_rel,
                       int* cur_r, int* adj_r_e){
    int e = blockIdx.x*256 + threadIdx.x;
    if(e < NEA){
        int i = clampi(ji[NEA + e], NN), j = clampi(ji[e], NN);
        int p = clampi(atomicAdd(&cur_all[i], 1), NEA);
        adj_all_j[p] = j;
    }
    if(e < NE){
        int r = clampi(rel[e], NR);
        int p = clampi(atomicAdd(&cur_h[clampi(ht[e], NN)], 1), NE);      adj_h_rel[p] = r;
        int q = clampi(atomicAdd(&cur_t[clampi(ht[NE + e], NN)], 1), NE); adj_t_rel[q] = r;
        int u = clampi(atomicAdd(&cur_r[r], 1), NE);                      adj_r_e[u] = e;
    }
}

__global__ void k_dinv(const int* __restrict__ deg, float* __restrict__ dinv){
    int n = blockIdx.x*256 + threadIdx.x;
    if(n < NN){ int d = deg[n]; dinv[n] = d > 0 ? rsqrtf((float)d) : 0.f; }
}

// ---------- GCN gather: xd[n] = relu(sum norm * xs[j]) ; wave per node; bf16 ----------
__global__ void k_gcn(const bf16* __restrict__ xs, bf16* __restrict__ xd,
                      const int* __restrict__ off, const int* __restrict__ adjj,
                      const float* __restrict__ dinv){
    int wid = threadIdx.x >> 6, lane = threadIdx.x & 63;
    int n = blockIdx.x*4 + wid;
    if(n >= NN) return;
    float acc[5] = {0,0,0,0,0};
    float di = dinv[n];
    int s0 = off[n], s1 = off[n+1];
    for(int it=s0; it<s1; it++){
        int j = clampi(adjj[it], NN);
        float nr = di * dinv[j];
        const bf16* xr = xs + (size_t)j*EHD;
        #pragma unroll
        for(int k=0;k<5;k++){ int d = lane + 64*k; if(d < EHD) acc[k] += nr * b2f(xr[d]); }
    }
    bf16* xo = xd + (size_t)n*EHD;
    #pragma unroll
    for(int k=0;k<5;k++){ int d = lane + 64*k; if(d < EHD) xo[d] = f2b(fmaxf(acc[k], 0.f)); }
}

// ---------- MFMA GEMM: out[M,Ncols] = X[M,K] @ Wt^T + bias.  64x64 tile, BK=32, 4 waves ----------
// MODE 0: out = f2b(acc+bias).  MODE 1: highway: g=sig(acc+bias); out = g*out + (1-g)*Xprev
template<int MODE>
__global__ __launch_bounds__(256) void k_gemm_mfma(const bf16* __restrict__ X,
                       const short* __restrict__ Wt, const float* __restrict__ bias,
                       bf16* __restrict__ out, const bf16* __restrict__ Xprev,
                       int M, int K, int Ncols){
    __shared__ short As[64][40];   // stride 40 shorts = 80 B -> <=2-way bank aliasing (free)
    __shared__ short Bs[64][40];
    int tid = threadIdx.x;
    int bm = blockIdx.x*64, bn = blockIdx.y*64;
    int wid = tid>>6, lane = tid&63;
    int wm = (wid&1)*32, wn = (wid>>1)*32;
    int lm = lane&15, lq = lane>>4;
    f32x4_t acc00={0,0,0,0}, acc01={0,0,0,0}, acc10={0,0,0,0}, acc11={0,0,0,0};
    int mrow = tid>>2, kc = (tid&3)*8;

    union U8 { bf16x8_t v; uint2 u[2]; short s[8]; };

    for(int k0=0; k0<K; k0+=32){
        int gk0 = k0 + kc;
        {   // stage A tile (X rows, bf16)
            int gm = bm + mrow;
            U8 a;
            if(gm < M && gk0 + 8 <= K){
                const uint2* src = (const uint2*)(X + (size_t)gm*K + gk0);  // 8-B aligned
                a.u[0] = src[0]; a.u[1] = src[1];
            } else {
                #pragma unroll
                for(int j=0;j<8;j++){
                    int gk = gk0 + j;
                    a.s[j] = (gm < M && gk < K) ? tobits(X[(size_t)gm*K + gk]) : (short)0;
                }
            }
            *(bf16x8_t*)&As[mrow][kc] = a.v;
        }
        {   // stage B tile (Wt rows = W columns, bf16 bits)
            int gn = bn + mrow;
            U8 b;
            if(gn < Ncols && gk0 + 8 <= K){
                const uint2* src = (const uint2*)(Wt + (size_t)gn*K + gk0);
                b.u[0] = src[0]; b.u[1] = src[1];
            } else {
                #pragma unroll
                for(int j=0;j<8;j++){
                    int gk = gk0 + j;
                    b.s[j] = (gn < Ncols && gk < K) ? Wt[(size_t)gn*K + gk] : (short)0;
                }
            }
            *(bf16x8_t*)&Bs[mrow][kc] = b.v;
        }
        __syncthreads();
        bf16x8_t a0 = *(bf16x8_t*)&As[wm + lm][lq*8];
        bf16x8_t a1 = *(bf16x8_t*)&As[wm + 16 + lm][lq*8];
        bf16x8_t b0 = *(bf16x8_t*)&Bs[wn + lm][lq*8];
        bf16x8_t b1 = *(bf16x8_t*)&Bs[wn + 16 + lm][lq*8];
        acc00 = __builtin_amdgcn_mfma_f32_16x16x32_bf16(a0, b0, acc00, 0, 0, 0);
        acc01 = __builtin_amdgcn_mfma_f32_16x16x32_bf16(a0, b1, acc01, 0, 0, 0);
        acc10 = __builtin_amdgcn_mfma_f32_16x16x32_bf16(a1, b0, acc10, 0, 0, 0);
        acc11 = __builtin_amdgcn_mfma_f32_16x16x32_bf16(a1, b1, acc11, 0, 0, 0);
        __syncthreads();
    }
    // epilogue: C/D layout col=lane&15, row=lq*4+reg
    #pragma unroll
    for(int tm=0;tm<2;tm++){
        #pragma unroll
        for(int tn=0;tn<2;tn++){
            f32x4_t a = tm==0 ? (tn==0 ? acc00 : acc01) : (tn==0 ? acc10 : acc11);
            int gn = bn + wn + tn*16 + lm;
            if(gn >= Ncols) continue;
            float bi = bias[gn];
            #pragma unroll
            for(int r=0;r<4;r++){
                int gm = bm + wm + tm*16 + lq*4 + r;
                if(gm >= M) continue;
                float t = a[r] + bi;
                size_t p = (size_t)gm*Ncols + gn;
                if(MODE == 0){
                    out[p] = f2b(t);
                } else {
                    float g = 1.f/(1.f + expf(-t));
                    out[p] = f2b(g*b2f(out[p]) + (1.f - g)*b2f(Xprev[p]));
                }
            }
        }
    }
}

// ---------- per-relation means via rel-CSR (no atomics): RF[r][100..299] ----------
__global__ void k_relmean(const bf16* __restrict__ s, const int* __restrict__ ht,
                          const int* __restrict__ off_r, const int* __restrict__ adj_r,
                          float* __restrict__ RF){
    int r = blockIdx.x, d = threadIdx.x;   // 128 threads
    int s0 = off_r[r], s1 = off_r[r+1];
    float ah = 0.f, at2 = 0.f;
    for(int it=s0; it<s1; it++){
        int e = clampi(adj_r[it], NE);
        int hh = clampi(ht[e], NN), tt = clampi(ht[NE + e], NN);
        if(d < THD){
            ah  += b2f(s[(size_t)hh*THD + d]);
            at2 += b2f(s[(size_t)tt*THD + d]);
        }
    }
    if(d < THD){
        int cnt = s1 - s0;
        float c = (float)(cnt > 1 ? cnt : 1);
        RF[(size_t)r*EHD + THD   + d] = ah / c;
        RF[(size_t)r*EHD + 2*THD + d] = at2 / c;
    }
}

__global__ void k_relx2(const float* __restrict__ sr1w, const float* __restrict__ sr1b,
                        const int* __restrict__ off_r, float* __restrict__ RF){
    int r = blockIdx.x, k = threadIdx.x;
    if(k >= RHD) return;
    float v = 0.f;
    if(off_r[r+1] - off_r[r] > 0){
        v = sr1b[k];
        for(int d=0; d<2*THD; d++) v += RF[(size_t)r*EHD + THD + d] * sr1w[d*RHD + k];
    }
    RF[(size_t)r*EHD + k] = v;   // x_type (== x_res2 row, or 0 for empty rel)
}

// ER[kk][r][o] = RF[r] @ wr_kk + br_kk
__global__ void k_reler(const float* __restrict__ RF,
                        const float* w0, const float* b0, const float* w1, const float* b1,
                        const float* w2, const float* b2, float* __restrict__ ER){
    int r = blockIdx.x, kk = blockIdx.y;
    const float* w = kk==0 ? w0 : (kk==1 ? w1 : w2);
    const float* b = kk==0 ? b0 : (kk==1 ? b1 : b2);
    for(int o = threadIdx.x; o < EHD; o += 256){
        float v = b[o];
        for(int d=0; d<EHD; d++) v += RF[(size_t)r*EHD + d] * w[(size_t)d*EHD + o];
        ER[((size_t)kk*NR + r)*EHD + o] = v;
    }
}

__global__ void k_relc(const float* __restrict__ ER, const float* ar1, const float* ar2,
                       const float* ar3, float* __restrict__ cvec){
    int r = blockIdx.x, kk = blockIdx.y, lane = threadIdx.x;
    const float* a = kk==0 ? ar1 : (kk==1 ? ar2 : ar3);
    float p = 0;
    #pragma unroll
    for(int k=0;k<5;k++){ int d = lane + 64*k; if(d < EHD) p += ER[((size_t)kk*NR + r)*EHD + d]*a[d]; }
    #pragma unroll
    for(int m=32;m>=1;m>>=1) p += __shfl_xor(p, m);
    if(lane == 0) cvec[kk*NR + r] = p;
}

// ---------- r2e round: x[n] += relu( sum_e alpha_e * ER[rel_e] ) ; wave per node ----------
__global__ void k_r2e(bf16* __restrict__ x, const int* __restrict__ off,
                      const int* __restrict__ adjrel, const float* __restrict__ ERk,
                      const float* __restrict__ ck, const float* __restrict__ anode){
    int wid = threadIdx.x >> 6, lane = threadIdx.x & 63;
    int n = blockIdx.x*4 + wid;
    if(n >= NN) return;
    bf16* xr = x + (size_t)n*EHD;
    float xv[5];
    float p = 0;
    #pragma unroll
    for(int k=0;k<5;k++){
        int d = lane + 64*k;
        xv[k] = (d < EHD) ? b2f(xr[d]) : 0.f;
        if(d < EHD) p += xv[k]*anode[d];
    }
    #pragma unroll
    for(int m=32;m>=1;m>>=1) p += __shfl_xor(p, m);   // p = xdot[n] on every lane
    int s0 = off[n], s1 = off[n+1];
    if(s0 == s1) return;
    float mx = -1e30f;
    for(int it=s0; it<s1; it++){
        float lg = p + ck[clampi(adjrel[it], NR)];
        lg = lg > 0 ? lg : 0.01f*lg;
        mx = fmaxf(mx, lg);
    }
    float ss = 0;
    for(int it=s0; it<s1; it++){
        float lg = p + ck[clampi(adjrel[it], NR)];
        lg = lg > 0 ? lg : 0.01f*lg;
        ss += expf(lg - mx);
    }
    float acc[5] = {0,0,0,0,0};
    for(int it=s0; it<s1; it++){
        int r = clampi(adjrel[it], NR);
        float lg = p + ck[r];
        lg = lg > 0 ? lg : 0.01f*lg;
        float a = expf(lg - mx)/ss;
        const float* er = ERk + (size_t)r*EHD;
        #pragma unroll
        for(int k=0;k<5;k++){ int d = lane + 64*k; if(d < EHD) acc[k] += a*er[d]; }
    }
    #pragma unroll
    for(int k=0;k<5;k++){ int d = lane + 64*k; if(d < EHD) xr[d] = f2b(xv[k] + fmaxf(acc[k], 0.f)); }
}

// ---------- per-node dot (ajv = x @ ajw) ----------
__global__ void k_dot(const bf16* __restrict__ x, const float* __restrict__ a,
                      float* __restrict__ out){
    int wid = threadIdx.x >> 6, lane = threadIdx.x & 63;
    int n = blockIdx.x*4 + wid;
    if(n >= NN) return;
    const bf16* xr = x + (size_t)n*EHD;
    float p = 0;
    #pragma unroll
    for(int k=0;k<5;k++){ int d = lane + 64*k; if(d < EHD) p += b2f(xr[d])*a[d]; }
    #pragma unroll
    for(int m=32;m>=1;m>>=1) p += __shfl_xor(p, m);
    if(lane == 0) out[n] = p;
}

// ---------- final GAT + fc (f32 output) ----------
__global__ void k_final(const bf16* __restrict__ x, const float* __restrict__ ajv,
                        const int* __restrict__ off, const int* __restrict__ adjj,
                        const float* __restrict__ aiw, const float* __restrict__ fcw,
                        const float* __restrict__ fcb, float* __restrict__ out){
    int wid = threadIdx.x >> 6, lane = threadIdx.x & 63;
    int n = blockIdx.x*4 + wid;
    if(n >= NN) return;
    const bf16* xr = x + (size_t)n*EHD;
    float p = 0;
    #pragma unroll
    for(int k=0;k<5;k++){ int d = lane + 64*k; if(d < EHD) p += b2f(xr[d])*aiw[d]; }
    #pragma unroll
    for(int m=32;m>=1;m>>=1) p += __shfl_xor(p, m);   // ai[n]
    int s0 = off[n], s1 = off[n+1];
    float acc[5] = {0,0,0,0,0};
    if(s0 < s1){
        float mx = -1e30f;
        for(int it=s0; it<s1; it++){
            float lg = p + ajv[clampi(adjj[it], NN)];
            lg = lg > 0 ? lg : 0.01f*lg;
            mx = fmaxf(mx, lg);
        }
        float ss = 0;
        for(int it=s0; it<s1; it++){
            float lg = p + ajv[clampi(adjj[it], NN)];
            lg = lg > 0 ? lg : 0.01f*lg;
            ss += expf(lg - mx);
        }
        for(int it=s0; it<s1; it++){
            int j = clampi(adjj[it], NN);
            float lg = p + ajv[j];
            lg = lg > 0 ? lg : 0.01f*lg;
            float a = expf(lg - mx)/ss;
            const bf16* xj = x + (size_t)j*EHD;
            #pragma unroll
            for(int k=0;k<5;k++){ int d = lane + 64*k; if(d < EHD) acc[k] += a*b2f(xj[d]); }
        }
    }
    float part = 0;
    #pragma unroll
    for(int k=0;k<5;k++){
        int d = lane + 64*k;
        if(d < EHD) part += b2f(xr[d])*fcw[d] + fmaxf(acc[k], 0.f)*fcw[EHD + d];
    }
    #pragma unroll
    for(int m=32;m>=1;m>>=1) part += __shfl_xor(part, m);
    if(lane == 0) out[n] = part + fcb[0];
}

extern "C" void kernel_launch(void* const* d_in, const int* in_sizes, int n_in,
                              void* d_out, int out_size, void* d_ws, size_t ws_size,
                              hipStream_t stream){
    const float* x_in = (const float*)d_in[0];
    const int*  ht   = (const int*)d_in[1];   // [0,NE)=h, [NE,2NE)=t
    const int*  rel  = (const int*)d_in[2];
    const int*  ji   = (const int*)d_in[3];   // [0,NEA)=j, [NEA,2NEA)=i
    const float* hw1w=(const float*)d_in[5];  const float* hw1b=(const float*)d_in[6];
    const float* hw2w=(const float*)d_in[7];  const float* hw2b=(const float*)d_in[8];
    const float* tc1w=(const float*)d_in[9];  const float* tc1b=(const float*)d_in[10];
    const float* sr1w=(const float*)d_in[11]; const float* sr1b=(const float*)d_in[12];
    // d_in[13]=a1_w, d_in[14]=a5_w: mathematically dead (uniform per-segment logits)
    const float* wrw =(const float*)d_in[15]; const float* wrb =(const float*)d_in[16];
    const float* wr1w=(const float*)d_in[17]; const float* wr1b=(const float*)d_in[18];
    const float* wr2w=(const float*)d_in[19]; const float* wr2b=(const float*)d_in[20];
    const float* ahw =(const float*)d_in[21]; const float* ah1w=(const float*)d_in[22];
    const float* atw =(const float*)d_in[23];
    const float* ar1 =(const float*)d_in[24]; const float* ar2 =(const float*)d_in[25];
    const float* ar3 =(const float*)d_in[26];
    const float* aiw =(const float*)d_in[27]; const float* ajw =(const float*)d_in[28];
    const float* fcw =(const float*)d_in[29]; const float* fcb =(const float*)d_in[30];
    float* out = (float*)d_out;

    // ---- workspace layout: ~68 MB. Feature scratch bf16, compute f32. ----
    char* w = (char*)d_ws;
    auto alloc = [&](size_t bytes)->char*{ char* p = w; w += (bytes + 255)/256*256; return p; };
    bf16* xF = (bf16*)alloc((size_t)NN*EHD*2);   // 30 MB; bf16(x_in) -> then x2..final x
    bf16* B  = (bf16*)alloc((size_t)NN*EHD*2);   // 30 MB; agg1 -> x1, dead after hw2 GEMM
    char* Bc = (char*)B;
    bf16*  sbuf = (bf16*)(Bc);                        // 10 MB  [NN*THD] bf16
    float* RF   = (float*)(Bc + 11u*1024*1024);       // 360 KB
    float* ER   = (float*)(Bc + 12u*1024*1024);       // 1.08 MB
    float* cvec = (float*)(Bc + 14u*1024*1024);       // 3.6 KB
    float* ajv  = (float*)(Bc + 15u*1024*1024);       // 200 KB
    short* Wt1 = (short*)alloc((size_t)EHD*EHD*2);    // 180 KB
    short* Wt2 = (short*)alloc((size_t)EHD*EHD*2);
    short* Wtc = (short*)alloc((size_t)EHD*THD*2);    // 60 KB
    float* dinv = (float*)alloc((size_t)NN*4);
    int* deg_all=(int*)alloc(NN*4); int* off_all=(int*)alloc((NN+1)*4); int* cur_all=(int*)alloc(NN*4);
    int* adj_all=(int*)alloc((size_t)NEA*4);
    int* deg_h  =(int*)alloc(NN*4); int* off_h  =(int*)alloc((NN+1)*4); int* cur_h  =(int*)alloc(NN*4);
    int* adj_h  =(int*)alloc((size_t)NE*4);
    int* deg_t  =(int*)alloc(NN*4); int* off_t  =(int*)alloc((NN+1)*4); int* cur_t  =(int*)alloc(NN*4);
    int* adj_t  =(int*)alloc((size_t)NE*4);
    int* cnt_rel=(int*)alloc(NR*4); int* off_r =(int*)alloc((NR+1)*4);  int* cur_r  =(int*)alloc(NR*4);
    int* adj_r  =(int*)alloc((size_t)NE*4);

    const int nbN = (NN+255)/256;
    k_zero_i32<<<dim3(nbN), dim3(256), 0, stream>>>(deg_all, NN);
    k_zero_i32<<<dim3(nbN), dim3(256), 0, stream>>>(deg_h, NN);
    k_zero_i32<<<dim3(nbN), dim3(256), 0, stream>>>(deg_t, NN);
    k_zero_i32<<<dim3(2),   dim3(256), 0, stream>>>(cnt_rel, NR);

    // prep: bf16 cast of x_in (into xF), transposed bf16 weights
    const int N4 = NN*EHD/4;
    k_cast4<<<dim3((N4+255)/256), dim3(256), 0, stream>>>((const float4*)x_in, (ushort*)xF, N4);
    k_prepw<<<dim3((EHD*EHD+255)/256), dim3(256), 0, stream>>>(hw1w, Wt1, EHD, EHD);
    k_prepw<<<dim3((EHD*EHD+255)/256), dim3(256), 0, stream>>>(hw2w, Wt2, EHD, EHD);
    k_prepw<<<dim3((EHD*THD+255)/256), dim3(256), 0, stream>>>(tc1w, Wtc, EHD, THD);

    k_count<<<dim3((NEA+255)/256), dim3(256), 0, stream>>>(ji, ht, rel, deg_all, deg_h, deg_t, cnt_rel);
    k_scan<<<dim3(4), dim3(1024), 0, stream>>>(deg_all, off_all, cur_all, deg_h, off_h, cur_h,
                                               deg_t, off_t, cur_t, cnt_rel, off_r, cur_r);
    k_fill<<<dim3((NEA+255)/256), dim3(256), 0, stream>>>(ji, ht, rel, cur_all, adj_all,
                                                          cur_h, adj_h, cur_t, adj_t, cur_r, adj_r);
    k_dinv<<<dim3(nbN), dim3(256), 0, stream>>>(deg_all, dinv);

    const int nb4 = (NN+3)/4;
    const dim3 gg((NN+63)/64, (EHD+63)/64);   // 782 x 5
    // highway 1: B = gcn(xC); B = sig(xC@hw1+b)*B + (1-sig)*xC   (xC == xF holds bf16(x_in))
    k_gcn<<<dim3(nb4), dim3(256), 0, stream>>>(xF, B, off_all, adj_all, dinv);
    k_gemm_mfma<1><<<gg, dim3(256), 0, stream>>>(xF, Wt1, hw1b, B, xF, NN, EHD, EHD);
    // highway 2: xF = gcn(B); xF = sig(B@hw2+b)*xF + (1-sig)*B
    k_gcn<<<dim3(nb4), dim3(256), 0, stream>>>(B, xF, off_all, adj_all, dinv);
    k_gemm_mfma<1><<<gg, dim3(256), 0, stream>>>(B, Wt2, hw2b, xF, B, NN, EHD, EHD);
    // ---- B is now dead; aliases (sbuf, RF, ER, cvec, ajv) come alive ----
    // s = x2 @ tc1 + b
    k_gemm_mfma<0><<<dim3((NN+63)/64, (THD+63)/64), dim3(256), 0, stream>>>(xF, Wtc, tc1b, sbuf, xF, NN, EHD, THD);
    // per-relation tables (atomic-free)
    k_relmean<<<dim3(NR), dim3(128), 0, stream>>>(sbuf, ht, off_r, adj_r, RF);
    k_relx2<<<dim3(NR), dim3(128), 0, stream>>>(sr1w, sr1b, off_r, RF);
    k_reler<<<dim3(NR, 3), dim3(256), 0, stream>>>(RF, wrw, wrb, wr1w, wr1b, wr2w, wr2b, ER);
    k_relc<<<dim3(NR, 3), dim3(64), 0, stream>>>(ER, ar1, ar2, ar3, cvec);
    // three r2e rounds (in-place on xF)
    k_r2e<<<dim3(nb4), dim3(256), 0, stream>>>(xF, off_h, adj_h, ER,                     cvec,        ahw);
    k_r2e<<<dim3(nb4), dim3(256), 0, stream>>>(xF, off_t, adj_t, ER + (size_t)NR*EHD,    cvec + NR,   atw);
    k_r2e<<<dim3(nb4), dim3(256), 0, stream>>>(xF, off_h, adj_h, ER + (size_t)2*NR*EHD,  cvec + 2*NR, ah1w);
    // final GAT + fc
    k_dot<<<dim3(nb4), dim3(256), 0, stream>>>(xF, ajw, ajv);
    k_final<<<dim3(nb4), dim3(256), 0, stream>>>(xF, ajv, off_all, adj_all, aiw, fcw, fcb, out);
}

// Round 6
// 1418.133 us; speedup vs baseline: 1.2446x; 1.2411x over previous
//
#include <hip/hip_runtime.h>
#include <hip/hip_bf16.h>

typedef __hip_bfloat16 bf16;
typedef __attribute__((ext_vector_type(8))) short bf16x8_t;
typedef __attribute__((ext_vector_type(4))) float f32x4_t;

__device__ __forceinline__ float b2f(bf16 v){ return __bfloat162float(v); }
__device__ __forceinline__ bf16 f2b(float v){ return __float2bfloat16(v); }
__device__ __forceinline__ short tobits(float v){ bf16 b = f2b(v); return *(short*)&b; }
__device__ __forceinline__ float us2f(ushort u){ return __uint_as_float(((unsigned)u)<<16); }
__device__ __forceinline__ ushort f2us(float v){ bf16 b = f2b(v); return *(ushort*)&b; }

#define NN 50000
#define NE 250000
#define NEA 500000
#define NR 300
#define EHD 300
#define THD 100
#define RHD 100
#define RCH 8      // chunks per relation for the mean reduction

__device__ __forceinline__ int clampi(int v, int n){ return ((unsigned)v < (unsigned)n) ? v : 0; }

// ---------- zero fill ----------
__global__ void k_zero_i32(int* __restrict__ p, int n){
    int i = blockIdx.x*256 + threadIdx.x;
    if(i < n) p[i] = 0;
}
__global__ void k_zero_f32(float* __restrict__ p, int n){
    int i = blockIdx.x*256 + threadIdx.x;
    if(i < n) p[i] = 0.f;
}

// ---------- f32 -> bf16 cast, 4 elems/thread ----------
__global__ void k_cast4(const float4* __restrict__ in, ushort* __restrict__ out, int n4){
    int i = blockIdx.x*256 + threadIdx.x;
    if(i >= n4) return;
    float4 v = in[i];
    ushort4 o;
    o.x = (ushort)tobits(v.x); o.y = (ushort)tobits(v.y);
    o.z = (ushort)tobits(v.z); o.w = (ushort)tobits(v.w);
    *(ushort4*)(out + 4*(size_t)i) = o;
}

// ---------- W [K][N] f32 -> Wt [N][K] bf16 bits ----------
__global__ void k_prepw(const float* __restrict__ W, short* __restrict__ Wt, int K, int N){
    int i = blockIdx.x*256 + threadIdx.x;
    if(i < N*K){
        int n = i / K, k = i - n*K;
        Wt[i] = tobits(W[(size_t)k*N + n]);
    }
}

// ---------- degree counting ----------
__global__ void k_count(const int* __restrict__ ji, const int* __restrict__ ht,
                        const int* __restrict__ rel,
                        int* deg_all, int* deg_h, int* deg_t, int* cnt_rel){
    int e = blockIdx.x*256 + threadIdx.x;
    if(e < NEA) atomicAdd(&deg_all[clampi(ji[NEA + e], NN)], 1);
    if(e < NE){
        atomicAdd(&deg_h[clampi(ht[e], NN)], 1);
        atomicAdd(&deg_t[clampi(ht[NE + e], NN)], 1);
        atomicAdd(&cnt_rel[clampi(rel[e], NR)], 1);
    }
}

// ---------- exclusive scan (one block per array, 4 arrays) ----------
__global__ void k_scan(const int* d0, int* o0, int* c0,
                       const int* d1, int* o1, int* c1,
                       const int* d2, int* o2, int* c2,
                       const int* d3, int* o3, int* c3){
    const int* deg; int* off; int* cur; int len;
    if(blockIdx.x == 0){ deg=d0; off=o0; cur=c0; len=NN; }
    else if(blockIdx.x == 1){ deg=d1; off=o1; cur=c1; len=NN; }
    else if(blockIdx.x == 2){ deg=d2; off=o2; cur=c2; len=NN; }
    else { deg=d3; off=o3; cur=c3; len=NR; }
    __shared__ int lds[1024];
    int tid = threadIdx.x;
    const int CH = (len + 1023)/1024;
    int lo = tid*CH, hi = lo+CH; if(hi > len) hi = len; if(lo > len) lo = len;
    int lsum = 0;
    for(int k=lo;k<hi;k++) lsum += deg[k];
    lds[tid] = lsum; __syncthreads();
    for(int s=1;s<1024;s<<=1){
        int v = (tid >= s) ? lds[tid-s] : 0;
        __syncthreads();
        lds[tid] += v;
        __syncthreads();
    }
    int excl = lds[tid] - lsum;
    int run = excl;
    for(int k=lo;k<hi;k++){ off[k]=run; cur[k]=run; run += deg[k]; }
    if(tid == 1023) off[len] = lds[1023];
}

// ---------- CSR fill ----------
__global__ void k_fill(const int* __restrict__ ji, const int* __restrict__ ht,
                       const int* __restrict__ rel,
                       int* cur_all, int* adj_all_j,
                       int* cur_h, int* adj_h_rel,
                       int* cur_t, int* adj_t_rel,
                       int* cur_r, int* adj_r_e){
    int e = blockIdx.x*256 + threadIdx.x;
    if(e < NEA){
        int i = clampi(ji[NEA + e], NN), j = clampi(ji[e], NN);
        int p = clampi(atomicAdd(&cur_all[i], 1), NEA);
        adj_all_j[p] = j;
    }
    if(e < NE){
        int r = clampi(rel[e], NR);
        int p = clampi(atomicAdd(&cur_h[clampi(ht[e], NN)], 1), NE);      adj_h_rel[p] = r;
        int q = clampi(atomicAdd(&cur_t[clampi(ht[NE + e], NN)], 1), NE); adj_t_rel[q] = r;
        int u = clampi(atomicAdd(&cur_r[r], 1), NE);                      adj_r_e[u] = e;
    }
}

__global__ void k_dinv(const int* __restrict__ deg, float* __restrict__ dinv){
    int n = blockIdx.x*256 + threadIdx.x;
    if(n < NN){ int d = deg[n]; dinv[n] = d > 0 ? rsqrtf((float)d) : 0.f; }
}

// ---------- GCN gather: xd[n] = relu(sum norm * xs[j]) ; wave per node; ushort4 rows ----------
// lane owns dims [4L,4L+4); lanes 0..10 also own [256+4L, 256+4L+4)
__global__ void k_gcn(const bf16* __restrict__ xs, bf16* __restrict__ xd,
                      const int* __restrict__ off, const int* __restrict__ adjj,
                      const float* __restrict__ dinv){
    int wid = threadIdx.x >> 6, lane = threadIdx.x & 63;
    int n = blockIdx.x*4 + wid;
    if(n >= NN) return;
    float a0=0,a1=0,a2=0,a3=0, t0=0,t1=0,t2=0,t3=0;
    float di = dinv[n];
    int s0 = off[n], s1 = off[n+1];
    bool tail = lane < 11;
    for(int it=s0; it<s1; it++){
        int j = clampi(adjj[it], NN);
        float nr = di * dinv[j];
        const ushort4* row = (const ushort4*)(xs + (size_t)j*EHD);
        ushort4 v = row[lane];
        a0 += nr*us2f(v.x); a1 += nr*us2f(v.y); a2 += nr*us2f(v.z); a3 += nr*us2f(v.w);
        if(tail){
            ushort4 u = row[64+lane];
            t0 += nr*us2f(u.x); t1 += nr*us2f(u.y); t2 += nr*us2f(u.z); t3 += nr*us2f(u.w);
        }
    }
    ushort4* o = (ushort4*)(xd + (size_t)n*EHD);
    ushort4 w0; w0.x=f2us(fmaxf(a0,0.f)); w0.y=f2us(fmaxf(a1,0.f)); w0.z=f2us(fmaxf(a2,0.f)); w0.w=f2us(fmaxf(a3,0.f));
    o[lane] = w0;
    if(tail){
        ushort4 w1; w1.x=f2us(fmaxf(t0,0.f)); w1.y=f2us(fmaxf(t1,0.f)); w1.z=f2us(fmaxf(t2,0.f)); w1.w=f2us(fmaxf(t3,0.f));
        o[64+lane] = w1;
    }
}

// ---------- MFMA GEMM: out[M,Ncols] = X[M,K] @ Wt^T + bias.  64x64 tile, BK=32, 4 waves ----------
template<int MODE>
__global__ __launch_bounds__(256) void k_gemm_mfma(const bf16* __restrict__ X,
                       const short* __restrict__ Wt, const float* __restrict__ bias,
                       bf16* __restrict__ out, const bf16* __restrict__ Xprev,
                       int M, int K, int Ncols){
    __shared__ short As[64][40];
    __shared__ short Bs[64][40];
    int tid = threadIdx.x;
    int bm = blockIdx.x*64, bn = blockIdx.y*64;
    int wid = tid>>6, lane = tid&63;
    int wm = (wid&1)*32, wn = (wid>>1)*32;
    int lm = lane&15, lq = lane>>4;
    f32x4_t acc00={0,0,0,0}, acc01={0,0,0,0}, acc10={0,0,0,0}, acc11={0,0,0,0};
    int mrow = tid>>2, kc = (tid&3)*8;

    union U8 { bf16x8_t v; uint2 u[2]; short s[8]; };

    for(int k0=0; k0<K; k0+=32){
        int gk0 = k0 + kc;
        {
            int gm = bm + mrow;
            U8 a;
            if(gm < M && gk0 + 8 <= K){
                const uint2* src = (const uint2*)(X + (size_t)gm*K + gk0);
                a.u[0] = src[0]; a.u[1] = src[1];
            } else {
                #pragma unroll
                for(int j=0;j<8;j++){
                    int gk = gk0 + j;
                    a.s[j] = (gm < M && gk < K) ? (short)*(const short*)(X + (size_t)gm*K + gk) : (short)0;
                }
                if(gm >= M){ a.u[0] = {0,0}; a.u[1] = {0,0}; }
            }
            *(bf16x8_t*)&As[mrow][kc] = a.v;
        }
        {
            int gn = bn + mrow;
            U8 b;
            if(gn < Ncols && gk0 + 8 <= K){
                const uint2* src = (const uint2*)(Wt + (size_t)gn*K + gk0);
                b.u[0] = src[0]; b.u[1] = src[1];
            } else {
                #pragma unroll
                for(int j=0;j<8;j++){
                    int gk = gk0 + j;
                    b.s[j] = (gn < Ncols && gk < K) ? Wt[(size_t)gn*K + gk] : (short)0;
                }
                if(gn >= Ncols){ b.u[0] = {0,0}; b.u[1] = {0,0}; }
            }
            *(bf16x8_t*)&Bs[mrow][kc] = b.v;
        }
        __syncthreads();
        bf16x8_t a0 = *(bf16x8_t*)&As[wm + lm][lq*8];
        bf16x8_t a1 = *(bf16x8_t*)&As[wm + 16 + lm][lq*8];
        bf16x8_t b0 = *(bf16x8_t*)&Bs[wn + lm][lq*8];
        bf16x8_t b1 = *(bf16x8_t*)&Bs[wn + 16 + lm][lq*8];
        acc00 = __builtin_amdgcn_mfma_f32_16x16x32_bf16(a0, b0, acc00, 0, 0, 0);
        acc01 = __builtin_amdgcn_mfma_f32_16x16x32_bf16(a0, b1, acc01, 0, 0, 0);
        acc10 = __builtin_amdgcn_mfma_f32_16x16x32_bf16(a1, b0, acc10, 0, 0, 0);
        acc11 = __builtin_amdgcn_mfma_f32_16x16x32_bf16(a1, b1, acc11, 0, 0, 0);
        __syncthreads();
    }
    #pragma unroll
    for(int tm=0;tm<2;tm++){
        #pragma unroll
        for(int tn=0;tn<2;tn++){
            f32x4_t a = tm==0 ? (tn==0 ? acc00 : acc01) : (tn==0 ? acc10 : acc11);
            int gn = bn + wn + tn*16 + lm;
            if(gn >= Ncols) continue;
            float bi = bias[gn];
            #pragma unroll
            for(int r=0;r<4;r++){
                int gm = bm + wm + tm*16 + lq*4 + r;
                if(gm >= M) continue;
                float t = a[r] + bi;
                size_t p = (size_t)gm*Ncols + gn;
                if(MODE == 0){
                    out[p] = f2b(t);
                } else {
                    float g = 1.f/(1.f + expf(-t));
                    out[p] = f2b(g*b2f(out[p]) + (1.f - g)*b2f(Xprev[p]));
                }
            }
        }
    }
}

// ---------- chunked per-relation sums into RF[r][100..299] (480K atomics total) ----------
__global__ void k_relsum2(const bf16* __restrict__ s, const int* __restrict__ ht,
                          const int* __restrict__ off_r, const int* __restrict__ adj_r,
                          float* __restrict__ RF){
    int r = blockIdx.x, c = blockIdx.y, d = threadIdx.x;   // 128 threads
    int s0 = off_r[r], s1 = off_r[r+1];
    int cnt = s1 - s0;
    if(cnt <= 0) return;
    int per = (cnt + RCH - 1)/RCH;
    int lo = s0 + c*per, hi = lo + per; if(hi > s1) hi = s1;
    if(lo >= hi) return;
    if(d >= THD) return;
    float ah = 0.f, at2 = 0.f;
    for(int it=lo; it<hi; it++){
        int e = clampi(adj_r[it], NE);
        int hh = clampi(ht[e], NN), tt = clampi(ht[NE + e], NN);
        ah  += b2f(s[(size_t)hh*THD + d]);
        at2 += b2f(s[(size_t)tt*THD + d]);
    }
    atomicAdd(&RF[(size_t)r*EHD + THD   + d], ah);
    atomicAdd(&RF[(size_t)r*EHD + 2*THD + d], at2);
}

__global__ void k_relnorm2(const int* __restrict__ off_r, float* __restrict__ RF){
    int r = blockIdx.x, d = threadIdx.x;
    if(d >= THD) return;
    int cnt = off_r[r+1] - off_r[r];
    float inv = 1.f/(float)(cnt > 1 ? cnt : 1);
    RF[(size_t)r*EHD + THD   + d] *= inv;
    RF[(size_t)r*EHD + 2*THD + d] *= inv;
}

__global__ void k_relx2(const float* __restrict__ sr1w, const float* __restrict__ sr1b,
                        const int* __restrict__ off_r, float* __restrict__ RF){
    int r = blockIdx.x, k = threadIdx.x;
    if(k >= RHD) return;
    float v = 0.f;
    if(off_r[r+1] - off_r[r] > 0){
        v = sr1b[k];
        for(int d=0; d<2*THD; d++) v += RF[(size_t)r*EHD + THD + d] * sr1w[d*RHD + k];
    }
    RF[(size_t)r*EHD + k] = v;   // x_type (== x_res2 row, or 0 for empty rel)
}

// ER[kk][r][o] = RF[r] @ wr_kk + br_kk
__global__ void k_reler(const float* __restrict__ RF,
                        const float* w0, const float* b0, const float* w1, const float* b1,
                        const float* w2, const float* b2, float* __restrict__ ER){
    int r = blockIdx.x, kk = blockIdx.y;
    const float* w = kk==0 ? w0 : (kk==1 ? w1 : w2);
    const float* b = kk==0 ? b0 : (kk==1 ? b1 : b2);
    for(int o = threadIdx.x; o < EHD; o += 256){
        float v = b[o];
        for(int d=0; d<EHD; d++) v += RF[(size_t)r*EHD + d] * w[(size_t)d*EHD + o];
        ER[((size_t)kk*NR + r)*EHD + o] = v;
    }
}

__global__ void k_relc(const float* __restrict__ ER, const float* ar1, const float* ar2,
                       const float* ar3, float* __restrict__ cvec){
    int r = blockIdx.x, kk = blockIdx.y, lane = threadIdx.x;
    const float* a = kk==0 ? ar1 : (kk==1 ? ar2 : ar3);
    float p = 0;
    #pragma unroll
    for(int k=0;k<5;k++){ int d = lane + 64*k; if(d < EHD) p += ER[((size_t)kk*NR + r)*EHD + d]*a[d]; }
    #pragma unroll
    for(int m=32;m>=1;m>>=1) p += __shfl_xor(p, m);
    if(lane == 0) cvec[kk*NR + r] = p;
}

// ---------- r2e round: x[n] += relu( sum_e alpha_e * ER[rel_e] ) ; wave per node; vector rows ----------
__global__ void k_r2e(bf16* __restrict__ x, const int* __restrict__ off,
                      const int* __restrict__ adjrel, const float* __restrict__ ERk,
                      const float* __restrict__ ck, const float* __restrict__ anode){
    int wid = threadIdx.x >> 6, lane = threadIdx.x & 63;
    int n = blockIdx.x*4 + wid;
    if(n >= NN) return;
    bool tail = lane < 11;
    ushort4* xr4 = (ushort4*)(x + (size_t)n*EHD);
    const float4* an4 = (const float4*)anode;
    ushort4 xv = xr4[lane];
    ushort4 xt = tail ? xr4[64+lane] : ushort4{0,0,0,0};
    float4 am = an4[lane];
    float4 at = tail ? an4[64+lane] : float4{0,0,0,0};
    float p = us2f(xv.x)*am.x + us2f(xv.y)*am.y + us2f(xv.z)*am.z + us2f(xv.w)*am.w;
    if(tail) p += us2f(xt.x)*at.x + us2f(xt.y)*at.y + us2f(xt.z)*at.z + us2f(xt.w)*at.w;
    #pragma unroll
    for(int m=32;m>=1;m>>=1) p += __shfl_xor(p, m);   // p = xdot[n] on every lane
    int s0 = off[n], s1 = off[n+1];
    if(s0 == s1) return;
    float mx = -1e30f;
    for(int it=s0; it<s1; it++){
        float lg = p + ck[clampi(adjrel[it], NR)];
        lg = lg > 0 ? lg : 0.01f*lg;
        mx = fmaxf(mx, lg);
    }
    float ss = 0;
    for(int it=s0; it<s1; it++){
        float lg = p + ck[clampi(adjrel[it], NR)];
        lg = lg > 0 ? lg : 0.01f*lg;
        ss += expf(lg - mx);
    }
    float a0=0,a1=0,a2=0,a3=0, t0=0,t1=0,t2=0,t3=0;
    for(int it=s0; it<s1; it++){
        int r = clampi(adjrel[it], NR);
        float lg = p + ck[r];
        lg = lg > 0 ? lg : 0.01f*lg;
        float a = expf(lg - mx)/ss;
        const float4* er4 = (const float4*)(ERk + (size_t)r*EHD);
        float4 e0 = er4[lane];
        a0 += a*e0.x; a1 += a*e0.y; a2 += a*e0.z; a3 += a*e0.w;
        if(tail){
            float4 e1 = er4[64+lane];
            t0 += a*e1.x; t1 += a*e1.y; t2 += a*e1.z; t3 += a*e1.w;
        }
    }
    ushort4 w0;
    w0.x = f2us(us2f(xv.x) + fmaxf(a0,0.f)); w0.y = f2us(us2f(xv.y) + fmaxf(a1,0.f));
    w0.z = f2us(us2f(xv.z) + fmaxf(a2,0.f)); w0.w = f2us(us2f(xv.w) + fmaxf(a3,0.f));
    xr4[lane] = w0;
    if(tail){
        ushort4 w1;
        w1.x = f2us(us2f(xt.x) + fmaxf(t0,0.f)); w1.y = f2us(us2f(xt.y) + fmaxf(t1,0.f));
        w1.z = f2us(us2f(xt.z) + fmaxf(t2,0.f)); w1.w = f2us(us2f(xt.w) + fmaxf(t3,0.f));
        xr4[64+lane] = w1;
    }
}

// ---------- per-node dot (ajv = x @ ajw) ----------
__global__ void k_dot(const bf16* __restrict__ x, const float* __restrict__ a,
                      float* __restrict__ out){
    int wid = threadIdx.x >> 6, lane = threadIdx.x & 63;
    int n = blockIdx.x*4 + wid;
    if(n >= NN) return;
    bool tail = lane < 11;
    const ushort4* xr4 = (const ushort4*)(x + (size_t)n*EHD);
    const float4* a4 = (const float4*)a;
    ushort4 xv = xr4[lane];
    float4 am = a4[lane];
    float p = us2f(xv.x)*am.x + us2f(xv.y)*am.y + us2f(xv.z)*am.z + us2f(xv.w)*am.w;
    if(tail){
        ushort4 xt = xr4[64+lane];
        float4 at = a4[64+lane];
        p += us2f(xt.x)*at.x + us2f(xt.y)*at.y + us2f(xt.z)*at.z + us2f(xt.w)*at.w;
    }
    #pragma unroll
    for(int m=32;m>=1;m>>=1) p += __shfl_xor(p, m);
    if(lane == 0) out[n] = p;
}

// ---------- final GAT + fc (f32 output) ----------
__global__ void k_final(const bf16* __restrict__ x, const float* __restrict__ ajv,
                        const int* __restrict__ off, const int* __restrict__ adjj,
                        const float* __restrict__ aiw, const float* __restrict__ fcw,
                        const float* __restrict__ fcb, float* __restrict__ out){
    int wid = threadIdx.x >> 6, lane = threadIdx.x & 63;
    int n = blockIdx.x*4 + wid;
    if(n >= NN) return;
    bool tail = lane < 11;
    const ushort4* xr4 = (const ushort4*)(x + (size_t)n*EHD);
    const float4* ai4 = (const float4*)aiw;
    ushort4 xv = xr4[lane];
    ushort4 xt = tail ? xr4[64+lane] : ushort4{0,0,0,0};
    float4 am = ai4[lane];
    float4 at = tail ? ai4[64+lane] : float4{0,0,0,0};
    float p = us2f(xv.x)*am.x + us2f(xv.y)*am.y + us2f(xv.z)*am.z + us2f(xv.w)*am.w;
    if(tail) p += us2f(xt.x)*at.x + us2f(xt.y)*at.y + us2f(xt.z)*at.z + us2f(xt.w)*at.w;
    #pragma unroll
    for(int m=32;m>=1;m>>=1) p += __shfl_xor(p, m);   // ai[n]
    int s0 = off[n], s1 = off[n+1];
    float a0=0,a1=0,a2=0,a3=0, t0=0,t1=0,t2=0,t3=0;
    if(s0 < s1){
        float mx = -1e30f;
        for(int it=s0; it<s1; it++){
            float lg = p + ajv[clampi(adjj[it], NN)];
            lg = lg > 0 ? lg : 0.01f*lg;
            mx = fmaxf(mx, lg);
        }
        float ss = 0;
        for(int it=s0; it<s1; it++){
            float lg = p + ajv[clampi(adjj[it], NN)];
            lg = lg > 0 ? lg : 0.01f*lg;
            ss += expf(lg - mx);
        }
        for(int it=s0; it<s1; it++){
            int j = clampi(adjj[it], NN);
            float lg = p + ajv[j];
            lg = lg > 0 ? lg : 0.01f*lg;
            float a = expf(lg - mx)/ss;
            const ushort4* row = (const ushort4*)(x + (size_t)j*EHD);
            ushort4 v = row[lane];
            a0 += a*us2f(v.x); a1 += a*us2f(v.y); a2 += a*us2f(v.z); a3 += a*us2f(v.w);
            if(tail){
                ushort4 u = row[64+lane];
                t0 += a*us2f(u.x); t1 += a*us2f(u.y); t2 += a*us2f(u.z); t3 += a*us2f(u.w);
            }
        }
    }
    const float4* f4 = (const float4*)fcw;    // fcw[600]
    float4 f0 = f4[lane];
    float4 g0 = f4[75 + lane];                // fcw[300 + 4L ..]
    float part = us2f(xv.x)*f0.x + us2f(xv.y)*f0.y + us2f(xv.z)*f0.z + us2f(xv.w)*f0.w
               + fmaxf(a0,0.f)*g0.x + fmaxf(a1,0.f)*g0.y + fmaxf(a2,0.f)*g0.z + fmaxf(a3,0.f)*g0.w;
    if(tail){
        float4 f1 = f4[64 + lane];
        float4 g1 = f4[139 + lane];           // fcw[300 + 256 + 4L ..]
        part += us2f(xt.x)*f1.x + us2f(xt.y)*f1.y + us2f(xt.z)*f1.z + us2f(xt.w)*f1.w
              + fmaxf(t0,0.f)*g1.x + fmaxf(t1,0.f)*g1.y + fmaxf(t2,0.f)*g1.z + fmaxf(t3,0.f)*g1.w;
    }
    #pragma unroll
    for(int m=32;m>=1;m>>=1) part += __shfl_xor(part, m);
    if(lane == 0) out[n] = part + fcb[0];
}

extern "C" void kernel_launch(void* const* d_in, const int* in_sizes, int n_in,
                              void* d_out, int out_size, void* d_ws, size_t ws_size,
                              hipStream_t stream){
    const float* x_in = (const float*)d_in[0];
    const int*  ht   = (const int*)d_in[1];   // [0,NE)=h, [NE,2NE)=t
    const int*  rel  = (const int*)d_in[2];
    const int*  ji   = (const int*)d_in[3];   // [0,NEA)=j, [NEA,2NEA)=i
    const float* hw1w=(const float*)d_in[5];  const float* hw1b=(const float*)d_in[6];
    const float* hw2w=(const float*)d_in[7];  const float* hw2b=(const float*)d_in[8];
    const float* tc1w=(const float*)d_in[9];  const float* tc1b=(const float*)d_in[10];
    const float* sr1w=(const float*)d_in[11]; const float* sr1b=(const float*)d_in[12];
    // d_in[13]=a1_w, d_in[14]=a5_w: mathematically dead (uniform per-segment logits)
    const float* wrw =(const float*)d_in[15]; const float* wrb =(const float*)d_in[16];
    const float* wr1w=(const float*)d_in[17]; const float* wr1b=(const float*)d_in[18];
    const float* wr2w=(const float*)d_in[19]; const float* wr2b=(const float*)d_in[20];
    const float* ahw =(const float*)d_in[21]; const float* ah1w=(const float*)d_in[22];
    const float* atw =(const float*)d_in[23];
    const float* ar1 =(const float*)d_in[24]; const float* ar2 =(const float*)d_in[25];
    const float* ar3 =(const float*)d_in[26];
    const float* aiw =(const float*)d_in[27]; const float* ajw =(const float*)d_in[28];
    const float* fcw =(const float*)d_in[29]; const float* fcb =(const float*)d_in[30];
    float* out = (float*)d_out;

    // ---- workspace layout: ~68 MB. Feature scratch bf16, compute f32. ----
    char* w = (char*)d_ws;
    auto alloc = [&](size_t bytes)->char*{ char* p = w; w += (bytes + 255)/256*256; return p; };
    bf16* xF = (bf16*)alloc((size_t)NN*EHD*2);   // 30 MB; bf16(x_in) -> then x2..final x
    bf16* B  = (bf16*)alloc((size_t)NN*EHD*2);   // 30 MB; agg1 -> x1, dead after hw2 GEMM
    char* Bc = (char*)B;
    bf16*  sbuf = (bf16*)(Bc);                        // 10 MB  [NN*THD] bf16
    float* RF   = (float*)(Bc + 11u*1024*1024);       // 360 KB
    float* ER   = (float*)(Bc + 12u*1024*1024);       // 1.08 MB
    float* cvec = (float*)(Bc + 14u*1024*1024);       // 3.6 KB
    float* ajv  = (float*)(Bc + 15u*1024*1024);       // 200 KB
    short* Wt1 = (short*)alloc((size_t)EHD*EHD*2);    // 180 KB
    short* Wt2 = (short*)alloc((size_t)EHD*EHD*2);
    short* Wtc = (short*)alloc((size_t)EHD*THD*2);    // 60 KB
    float* dinv = (float*)alloc((size_t)NN*4);
    int* deg_all=(int*)alloc(NN*4); int* off_all=(int*)alloc((NN+1)*4); int* cur_all=(int*)alloc(NN*4);
    int* adj_all=(int*)alloc((size_t)NEA*4);
    int* deg_h  =(int*)alloc(NN*4); int* off_h  =(int*)alloc((NN+1)*4); int* cur_h  =(int*)alloc(NN*4);
    int* adj_h  =(int*)alloc((size_t)NE*4);
    int* deg_t  =(int*)alloc(NN*4); int* off_t  =(int*)alloc((NN+1)*4); int* cur_t  =(int*)alloc(NN*4);
    int* adj_t  =(int*)alloc((size_t)NE*4);
    int* cnt_rel=(int*)alloc(NR*4); int* off_r =(int*)alloc((NR+1)*4);  int* cur_r  =(int*)alloc(NR*4);
    int* adj_r  =(int*)alloc((size_t)NE*4);

    const int nbN = (NN+255)/256;
    k_zero_i32<<<dim3(nbN), dim3(256), 0, stream>>>(deg_all, NN);
    k_zero_i32<<<dim3(nbN), dim3(256), 0, stream>>>(deg_h, NN);
    k_zero_i32<<<dim3(nbN), dim3(256), 0, stream>>>(deg_t, NN);
    k_zero_i32<<<dim3(2),   dim3(256), 0, stream>>>(cnt_rel, NR);

    // prep: bf16 cast of x_in (into xF), transposed bf16 weights
    const int N4 = NN*EHD/4;
    k_cast4<<<dim3((N4+255)/256), dim3(256), 0, stream>>>((const float4*)x_in, (ushort*)xF, N4);
    k_prepw<<<dim3((EHD*EHD+255)/256), dim3(256), 0, stream>>>(hw1w, Wt1, EHD, EHD);
    k_prepw<<<dim3((EHD*EHD+255)/256), dim3(256), 0, stream>>>(hw2w, Wt2, EHD, EHD);
    k_prepw<<<dim3((EHD*THD+255)/256), dim3(256), 0, stream>>>(tc1w, Wtc, EHD, THD);

    k_count<<<dim3((NEA+255)/256), dim3(256), 0, stream>>>(ji, ht, rel, deg_all, deg_h, deg_t, cnt_rel);
    k_scan<<<dim3(4), dim3(1024), 0, stream>>>(deg_all, off_all, cur_all, deg_h, off_h, cur_h,
                                               deg_t, off_t, cur_t, cnt_rel, off_r, cur_r);
    k_fill<<<dim3((NEA+255)/256), dim3(256), 0, stream>>>(ji, ht, rel, cur_all, adj_all,
                                                          cur_h, adj_h, cur_t, adj_t, cur_r, adj_r);
    k_dinv<<<dim3(nbN), dim3(256), 0, stream>>>(deg_all, dinv);

    const int nb4 = (NN+3)/4;
    const dim3 gg((NN+63)/64, (EHD+63)/64);
    // highway 1: B = gcn(xF); B = sig(xF@hw1+b)*B + (1-sig)*xF   (xF holds bf16(x_in))
    k_gcn<<<dim3(nb4), dim3(256), 0, stream>>>(xF, B, off_all, adj_all, dinv);
    k_gemm_mfma<1><<<gg, dim3(256), 0, stream>>>(xF, Wt1, hw1b, B, xF, NN, EHD, EHD);
    // highway 2: xF = gcn(B); xF = sig(B@hw2+b)*xF + (1-sig)*B
    k_gcn<<<dim3(nb4), dim3(256), 0, stream>>>(B, xF, off_all, adj_all, dinv);
    k_gemm_mfma<1><<<gg, dim3(256), 0, stream>>>(B, Wt2, hw2b, xF, B, NN, EHD, EHD);
    // ---- B is now dead; aliases (sbuf, RF, ER, cvec, ajv) come alive ----
    // s = x2 @ tc1 + b
    k_gemm_mfma<0><<<dim3((NN+63)/64, (THD+63)/64), dim3(256), 0, stream>>>(xF, Wtc, tc1b, sbuf, xF, NN, EHD, THD);
    // per-relation tables (chunk-parallel partial sums, few atomics)
    k_zero_f32<<<dim3((NR*EHD+255)/256), dim3(256), 0, stream>>>(RF, NR*EHD);
    k_relsum2<<<dim3(NR, RCH), dim3(128), 0, stream>>>(sbuf, ht, off_r, adj_r, RF);
    k_relnorm2<<<dim3(NR), dim3(128), 0, stream>>>(off_r, RF);
    k_relx2<<<dim3(NR), dim3(128), 0, stream>>>(sr1w, sr1b, off_r, RF);
    k_reler<<<dim3(NR, 3), dim3(256), 0, stream>>>(RF, wrw, wrb, wr1w, wr1b, wr2w, wr2b, ER);
    k_relc<<<dim3(NR, 3), dim3(64), 0, stream>>>(ER, ar1, ar2, ar3, cvec);
    // three r2e rounds (in-place on xF)
    k_r2e<<<dim3(nb4), dim3(256), 0, stream>>>(xF, off_h, adj_h, ER,                     cvec,        ahw);
    k_r2e<<<dim3(nb4), dim3(256), 0, stream>>>(xF, off_t, adj_t, ER + (size_t)NR*EHD,    cvec + NR,   atw);
    k_r2e<<<dim3(nb4), dim3(256), 0, stream>>>(xF, off_h, adj_h, ER + (size_t)2*NR*EHD,  cvec + 2*NR, ah1w);
    // final GAT + fc
    k_dot<<<dim3(nb4), dim3(256), 0, stream>>>(xF, ajw, ajv);
    k_final<<<dim3(nb4), dim3(256), 0, stream>>>(xF, ajv, off_all, adj_all, aiw, fcw, fcb, out);
}

// Round 7
// 1091.062 us; speedup vs baseline: 1.6177x; 1.2998x over previous
//
#include <hip/hip_runtime.h>
#include <hip/hip_bf16.h>

typedef __hip_bfloat16 bf16;
typedef __attribute__((ext_vector_type(8))) short bf16x8_t;
typedef __attribute__((ext_vector_type(4))) float f32x4_t;

__device__ __forceinline__ float b2f(bf16 v){ return __bfloat162float(v); }
__device__ __forceinline__ bf16 f2b(float v){ return __float2bfloat16(v); }
__device__ __forceinline__ short tobits(float v){ bf16 b = f2b(v); return *(short*)&b; }
__device__ __forceinline__ float us2f(ushort u){ return __uint_as_float(((unsigned)u)<<16); }
__device__ __forceinline__ ushort f2us(float v){ bf16 b = f2b(v); return *(ushort*)&b; }

#define NN 50000
#define NE 250000
#define NEA 500000
#define NR 300
#define EHD 300
#define THD 100
#define RHD 100
#define RCH 8

__device__ __forceinline__ int clampi(int v, int n){ return ((unsigned)v < (unsigned)n) ? v : 0; }

__device__ __forceinline__ float wred_sum(float p){
    #pragma unroll
    for(int m=32;m>=1;m>>=1) p += __shfl_xor(p, m);
    return p;
}
__device__ __forceinline__ float wred_max(float p){
    #pragma unroll
    for(int m=32;m>=1;m>>=1) p = fmaxf(p, __shfl_xor(p, m));
    return p;
}

// ---------- zero fill ----------
__global__ void k_zero_i32(int* __restrict__ p, int n){
    int i = blockIdx.x*256 + threadIdx.x;
    if(i < n) p[i] = 0;
}
__global__ void k_zero_f32(float* __restrict__ p, int n){
    int i = blockIdx.x*256 + threadIdx.x;
    if(i < n) p[i] = 0.f;
}

// ---------- f32 -> bf16 cast, 4 elems/thread ----------
__global__ void k_cast4(const float4* __restrict__ in, ushort* __restrict__ out, int n4){
    int i = blockIdx.x*256 + threadIdx.x;
    if(i >= n4) return;
    float4 v = in[i];
    ushort4 o;
    o.x = (ushort)tobits(v.x); o.y = (ushort)tobits(v.y);
    o.z = (ushort)tobits(v.z); o.w = (ushort)tobits(v.w);
    *(ushort4*)(out + 4*(size_t)i) = o;
}

// ---------- all three weight transposes in one kernel ----------
__global__ void k_prepw3(const float* __restrict__ hw1w, const float* __restrict__ hw2w,
                         const float* __restrict__ tc1w,
                         short* __restrict__ Wt1, short* __restrict__ Wt2, short* __restrict__ Wtc){
    int i = blockIdx.x*256 + threadIdx.x;
    const int S1 = EHD*EHD, S2 = 2*EHD*EHD, S3 = 2*EHD*EHD + EHD*THD;
    if(i < S1){
        int n = i/EHD, k = i - n*EHD;
        Wt1[i] = tobits(hw1w[(size_t)k*EHD + n]);
    } else if(i < S2){
        int ii = i - S1; int n = ii/EHD, k = ii - n*EHD;
        Wt2[ii] = tobits(hw2w[(size_t)k*EHD + n]);
    } else if(i < S3){
        int ii = i - S2; int n = ii/EHD, k = ii - n*EHD;   // Wtc[n][k], n<THD
        Wtc[ii] = tobits(tc1w[(size_t)k*THD + n]);
    }
}

// ---------- degree counting ----------
__global__ void k_count(const int* __restrict__ ji, const int* __restrict__ ht,
                        const int* __restrict__ rel,
                        int* deg_all, int* deg_h, int* deg_t, int* cnt_rel){
    int e = blockIdx.x*256 + threadIdx.x;
    if(e < NEA) atomicAdd(&deg_all[clampi(ji[NEA + e], NN)], 1);
    if(e < NE){
        atomicAdd(&deg_h[clampi(ht[e], NN)], 1);
        atomicAdd(&deg_t[clampi(ht[NE + e], NN)], 1);
        atomicAdd(&cnt_rel[clampi(rel[e], NR)], 1);
    }
}

// ---------- exclusive scan (one block per array, 4 arrays) ----------
__global__ void k_scan(const int* d0, int* o0, int* c0,
                       const int* d1, int* o1, int* c1,
                       const int* d2, int* o2, int* c2,
                       const int* d3, int* o3, int* c3){
    const int* deg; int* off; int* cur; int len;
    if(blockIdx.x == 0){ deg=d0; off=o0; cur=c0; len=NN; }
    else if(blockIdx.x == 1){ deg=d1; off=o1; cur=c1; len=NN; }
    else if(blockIdx.x == 2){ deg=d2; off=o2; cur=c2; len=NN; }
    else { deg=d3; off=o3; cur=c3; len=NR; }
    __shared__ int lds[1024];
    int tid = threadIdx.x;
    const int CH = (len + 1023)/1024;
    int lo = tid*CH, hi = lo+CH; if(hi > len) hi = len; if(lo > len) lo = len;
    int lsum = 0;
    for(int k=lo;k<hi;k++) lsum += deg[k];
    lds[tid] = lsum; __syncthreads();
    for(int s=1;s<1024;s<<=1){
        int v = (tid >= s) ? lds[tid-s] : 0;
        __syncthreads();
        lds[tid] += v;
        __syncthreads();
    }
    int excl = lds[tid] - lsum;
    int run = excl;
    for(int k=lo;k<hi;k++){ off[k]=run; cur[k]=run; run += deg[k]; }
    if(tid == 1023) off[len] = lds[1023];
}

// ---------- CSR fill ----------
__global__ void k_fill(const int* __restrict__ ji, const int* __restrict__ ht,
                       const int* __restrict__ rel,
                       int* cur_all, int* adj_all_j,
                       int* cur_h, int* adj_h_rel,
                       int* cur_t, int* adj_t_rel,
                       int* cur_r, int* adj_r_e){
    int e = blockIdx.x*256 + threadIdx.x;
    if(e < NEA){
        int i = clampi(ji[NEA + e], NN), j = clampi(ji[e], NN);
        int p = clampi(atomicAdd(&cur_all[i], 1), NEA);
        adj_all_j[p] = j;
    }
    if(e < NE){
        int r = clampi(rel[e], NR);
        int p = clampi(atomicAdd(&cur_h[clampi(ht[e], NN)], 1), NE);      adj_h_rel[p] = r;
        int q = clampi(atomicAdd(&cur_t[clampi(ht[NE + e], NN)], 1), NE); adj_t_rel[q] = r;
        int u = clampi(atomicAdd(&cur_r[r], 1), NE);                      adj_r_e[u] = e;
    }
}

__global__ void k_dinv(const int* __restrict__ deg, float* __restrict__ dinv){
    int n = blockIdx.x*256 + threadIdx.x;
    if(n < NN){ int d = deg[n]; dinv[n] = d > 0 ? rsqrtf((float)d) : 0.f; }
}

// ---------- GCN gather: xd[n] = relu(sum norm * xs[j]) ; wave per node; lane-prefetch + unroll2 ----------
__global__ void k_gcn(const bf16* __restrict__ xs, bf16* __restrict__ xd,
                      const int* __restrict__ off, const int* __restrict__ adjj,
                      const float* __restrict__ dinv){
    int wid = threadIdx.x >> 6, lane = threadIdx.x & 63;
    int n = blockIdx.x*4 + wid;
    if(n >= NN) return;
    float di = dinv[n];
    int s0 = off[n], s1 = off[n+1], cnt = s1 - s0;
    bool tail = lane < 11;
    float a0=0,a1=0,a2=0,a3=0, t0=0,t1=0,t2=0,t3=0;
    if(cnt > 0 && cnt <= 64){
        int jl = (lane < cnt) ? clampi(adjj[s0+lane], NN) : 0;
        float dl = (lane < cnt) ? dinv[jl] : 0.f;
        int it = 0;
        for(; it+2 <= cnt; it += 2){
            int j0 = __shfl(jl, it), j1 = __shfl(jl, it+1);
            float n0 = di*__shfl(dl, it), n1 = di*__shfl(dl, it+1);
            const ushort4* r0 = (const ushort4*)(xs + (size_t)j0*EHD);
            const ushort4* r1 = (const ushort4*)(xs + (size_t)j1*EHD);
            ushort4 v0 = r0[lane], v1 = r1[lane];
            a0 += n0*us2f(v0.x) + n1*us2f(v1.x);
            a1 += n0*us2f(v0.y) + n1*us2f(v1.y);
            a2 += n0*us2f(v0.z) + n1*us2f(v1.z);
            a3 += n0*us2f(v0.w) + n1*us2f(v1.w);
            if(tail){
                ushort4 u0 = r0[64+lane], u1 = r1[64+lane];
                t0 += n0*us2f(u0.x) + n1*us2f(u1.x);
                t1 += n0*us2f(u0.y) + n1*us2f(u1.y);
                t2 += n0*us2f(u0.z) + n1*us2f(u1.z);
                t3 += n0*us2f(u0.w) + n1*us2f(u1.w);
            }
        }
        if(it < cnt){
            int j0 = __shfl(jl, it);
            float n0 = di*__shfl(dl, it);
            const ushort4* r0 = (const ushort4*)(xs + (size_t)j0*EHD);
            ushort4 v0 = r0[lane];
            a0 += n0*us2f(v0.x); a1 += n0*us2f(v0.y); a2 += n0*us2f(v0.z); a3 += n0*us2f(v0.w);
            if(tail){
                ushort4 u0 = r0[64+lane];
                t0 += n0*us2f(u0.x); t1 += n0*us2f(u0.y); t2 += n0*us2f(u0.z); t3 += n0*us2f(u0.w);
            }
        }
    } else if(cnt > 64){
        for(int it=s0; it<s1; it++){
            int j = clampi(adjj[it], NN);
            float nr = di * dinv[j];
            const ushort4* row = (const ushort4*)(xs + (size_t)j*EHD);
            ushort4 v = row[lane];
            a0 += nr*us2f(v.x); a1 += nr*us2f(v.y); a2 += nr*us2f(v.z); a3 += nr*us2f(v.w);
            if(tail){
                ushort4 u = row[64+lane];
                t0 += nr*us2f(u.x); t1 += nr*us2f(u.y); t2 += nr*us2f(u.z); t3 += nr*us2f(u.w);
            }
        }
    }
    ushort4* o = (ushort4*)(xd + (size_t)n*EHD);
    ushort4 w0; w0.x=f2us(fmaxf(a0,0.f)); w0.y=f2us(fmaxf(a1,0.f)); w0.z=f2us(fmaxf(a2,0.f)); w0.w=f2us(fmaxf(a3,0.f));
    o[lane] = w0;
    if(tail){
        ushort4 w1; w1.x=f2us(fmaxf(t0,0.f)); w1.y=f2us(fmaxf(t1,0.f)); w1.z=f2us(fmaxf(t2,0.f)); w1.w=f2us(fmaxf(t3,0.f));
        o[64+lane] = w1;
    }
}

// ---------- MFMA GEMM: out[M,Ncols] = X[M,K] @ Wt^T + bias.  64x64 tile, BK=32, 4 waves ----------
template<int MODE>
__global__ __launch_bounds__(256) void k_gemm_mfma(const bf16* __restrict__ X,
                       const short* __restrict__ Wt, const float* __restrict__ bias,
                       bf16* __restrict__ out, const bf16* __restrict__ Xprev,
                       int M, int K, int Ncols){
    __shared__ short As[64][40];
    __shared__ short Bs[64][40];
    int tid = threadIdx.x;
    int bm = blockIdx.x*64, bn = blockIdx.y*64;
    int wid = tid>>6, lane = tid&63;
    int wm = (wid&1)*32, wn = (wid>>1)*32;
    int lm = lane&15, lq = lane>>4;
    f32x4_t acc00={0,0,0,0}, acc01={0,0,0,0}, acc10={0,0,0,0}, acc11={0,0,0,0};
    int mrow = tid>>2, kc = (tid&3)*8;

    union U8 { bf16x8_t v; uint2 u[2]; short s[8]; };

    for(int k0=0; k0<K; k0+=32){
        int gk0 = k0 + kc;
        {
            int gm = bm + mrow;
            U8 a;
            if(gm < M && gk0 + 8 <= K){
                const uint2* src = (const uint2*)(X + (size_t)gm*K + gk0);
                a.u[0] = src[0]; a.u[1] = src[1];
            } else {
                #pragma unroll
                for(int j=0;j<8;j++){
                    int gk = gk0 + j;
                    a.s[j] = (gm < M && gk < K) ? (short)*(const short*)(X + (size_t)gm*K + gk) : (short)0;
                }
                if(gm >= M){ a.u[0] = {0,0}; a.u[1] = {0,0}; }
            }
            *(bf16x8_t*)&As[mrow][kc] = a.v;
        }
        {
            int gn = bn + mrow;
            U8 b;
            if(gn < Ncols && gk0 + 8 <= K){
                const uint2* src = (const uint2*)(Wt + (size_t)gn*K + gk0);
                b.u[0] = src[0]; b.u[1] = src[1];
            } else {
                #pragma unroll
                for(int j=0;j<8;j++){
                    int gk = gk0 + j;
                    b.s[j] = (gn < Ncols && gk < K) ? Wt[(size_t)gn*K + gk] : (short)0;
                }
                if(gn >= Ncols){ b.u[0] = {0,0}; b.u[1] = {0,0}; }
            }
            *(bf16x8_t*)&Bs[mrow][kc] = b.v;
        }
        __syncthreads();
        bf16x8_t a0 = *(bf16x8_t*)&As[wm + lm][lq*8];
        bf16x8_t a1 = *(bf16x8_t*)&As[wm + 16 + lm][lq*8];
        bf16x8_t b0 = *(bf16x8_t*)&Bs[wn + lm][lq*8];
        bf16x8_t b1 = *(bf16x8_t*)&Bs[wn + 16 + lm][lq*8];
        acc00 = __builtin_amdgcn_mfma_f32_16x16x32_bf16(a0, b0, acc00, 0, 0, 0);
        acc01 = __builtin_amdgcn_mfma_f32_16x16x32_bf16(a0, b1, acc01, 0, 0, 0);
        acc10 = __builtin_amdgcn_mfma_f32_16x16x32_bf16(a1, b0, acc10, 0, 0, 0);
        acc11 = __builtin_amdgcn_mfma_f32_16x16x32_bf16(a1, b1, acc11, 0, 0, 0);
        __syncthreads();
    }
    #pragma unroll
    for(int tm=0;tm<2;tm++){
        #pragma unroll
        for(int tn=0;tn<2;tn++){
            f32x4_t a = tm==0 ? (tn==0 ? acc00 : acc01) : (tn==0 ? acc10 : acc11);
            int gn = bn + wn + tn*16 + lm;
            if(gn >= Ncols) continue;
            float bi = bias[gn];
            #pragma unroll
            for(int r=0;r<4;r++){
                int gm = bm + wm + tm*16 + lq*4 + r;
                if(gm >= M) continue;
                float t = a[r] + bi;
                size_t p = (size_t)gm*Ncols + gn;
                if(MODE == 0){
                    out[p] = f2b(t);
                } else {
                    float g = 1.f/(1.f + expf(-t));
                    out[p] = f2b(g*b2f(out[p]) + (1.f - g)*b2f(Xprev[p]));
                }
            }
        }
    }
}

// ---------- chunked per-relation sums into RF[r][100..299] ----------
__global__ void k_relsum2(const bf16* __restrict__ s, const int* __restrict__ ht,
                          const int* __restrict__ off_r, const int* __restrict__ adj_r,
                          float* __restrict__ RF){
    int r = blockIdx.x, c = blockIdx.y, d = threadIdx.x;
    int s0 = off_r[r], s1 = off_r[r+1];
    int cnt = s1 - s0;
    if(cnt <= 0) return;
    int per = (cnt + RCH - 1)/RCH;
    int lo = s0 + c*per, hi = lo + per; if(hi > s1) hi = s1;
    if(lo >= hi) return;
    if(d >= THD) return;
    float ah = 0.f, at2 = 0.f;
    for(int it=lo; it<hi; it++){
        int e = clampi(adj_r[it], NE);
        int hh = clampi(ht[e], NN), tt = clampi(ht[NE + e], NN);
        ah  += b2f(s[(size_t)hh*THD + d]);
        at2 += b2f(s[(size_t)tt*THD + d]);
    }
    atomicAdd(&RF[(size_t)r*EHD + THD   + d], ah);
    atomicAdd(&RF[(size_t)r*EHD + 2*THD + d], at2);
}

// ---------- normalize means + x_type in one kernel ----------
__global__ void k_relfin(const float* __restrict__ sr1w, const float* __restrict__ sr1b,
                         const int* __restrict__ off_r, float* __restrict__ RF){
    int r = blockIdx.x, d = threadIdx.x;   // 128 threads
    int cnt = off_r[r+1] - off_r[r];
    float inv = 1.f/(float)(cnt > 1 ? cnt : 1);
    if(d < THD){
        RF[(size_t)r*EHD + THD   + d] *= inv;
        RF[(size_t)r*EHD + 2*THD + d] *= inv;
    }
    __syncthreads();
    if(d < RHD){
        float v = 0.f;
        if(cnt > 0){
            v = sr1b[d];
            for(int k2=0; k2<2*THD; k2++) v += RF[(size_t)r*EHD + THD + k2] * sr1w[k2*RHD + d];
        }
        RF[(size_t)r*EHD + d] = v;
    }
}

// ER[kk][r][o] = RF[r] @ wr_kk + br_kk
__global__ void k_reler(const float* __restrict__ RF,
                        const float* w0, const float* b0, const float* w1, const float* b1,
                        const float* w2, const float* b2, float* __restrict__ ER){
    int r = blockIdx.x, kk = blockIdx.y;
    const float* w = kk==0 ? w0 : (kk==1 ? w1 : w2);
    const float* b = kk==0 ? b0 : (kk==1 ? b1 : b2);
    for(int o = threadIdx.x; o < EHD; o += 256){
        float v = b[o];
        for(int d=0; d<EHD; d++) v += RF[(size_t)r*EHD + d] * w[(size_t)d*EHD + o];
        ER[((size_t)kk*NR + r)*EHD + o] = v;
    }
}

__global__ void k_relc(const float* __restrict__ ER, const float* ar1, const float* ar2,
                       const float* ar3, float* __restrict__ cvec){
    int r = blockIdx.x, kk = blockIdx.y, lane = threadIdx.x;
    const float* a = kk==0 ? ar1 : (kk==1 ? ar2 : ar3);
    float p = 0;
    #pragma unroll
    for(int k=0;k<5;k++){ int d = lane + 64*k; if(d < EHD) p += ER[((size_t)kk*NR + r)*EHD + d]*a[d]; }
    p = wred_sum(p);
    if(lane == 0) cvec[kk*NR + r] = p;
}

// ---------- one r2e round on a register-resident x row ----------
__device__ __forceinline__ void r2e_round(float* xv, bool tail, int lane, int s0, int s1,
        const int* __restrict__ adjrel, const float* __restrict__ ERk,
        const float* __restrict__ ck, const float* __restrict__ anode){
    const float4* an4 = (const float4*)anode;
    float4 am = an4[lane];
    float p = xv[0]*am.x + xv[1]*am.y + xv[2]*am.z + xv[3]*am.w;
    if(tail){
        float4 at = an4[64+lane];
        p += xv[4]*at.x + xv[5]*at.y + xv[6]*at.z + xv[7]*at.w;
    }
    p = wred_sum(p);
    int cnt = s1 - s0;
    if(cnt <= 0) return;
    float a0=0,a1=0,a2=0,a3=0, t0=0,t1=0,t2=0,t3=0;
    if(cnt <= 64){
        int rl = (lane < cnt) ? clampi(adjrel[s0+lane], NR) : 0;
        float lg = p + ck[rl];
        lg = lg > 0 ? lg : 0.01f*lg;
        float mx = wred_max((lane < cnt) ? lg : -1e30f);
        float ex = (lane < cnt) ? expf(lg - mx) : 0.f;
        float ss = wred_sum(ex);
        float al = ex/ss;
        int it = 0;
        for(; it+2 <= cnt; it += 2){
            int r0i = __shfl(rl, it), r1i = __shfl(rl, it+1);
            float q0 = __shfl(al, it), q1 = __shfl(al, it+1);
            const float4* e0p = (const float4*)(ERk + (size_t)r0i*EHD);
            const float4* e1p = (const float4*)(ERk + (size_t)r1i*EHD);
            float4 e0 = e0p[lane], e1 = e1p[lane];
            a0 += q0*e0.x + q1*e1.x; a1 += q0*e0.y + q1*e1.y;
            a2 += q0*e0.z + q1*e1.z; a3 += q0*e0.w + q1*e1.w;
            if(tail){
                float4 f0 = e0p[64+lane], f1 = e1p[64+lane];
                t0 += q0*f0.x + q1*f1.x; t1 += q0*f0.y + q1*f1.y;
                t2 += q0*f0.z + q1*f1.z; t3 += q0*f0.w + q1*f1.w;
            }
        }
        if(it < cnt){
            int r0i = __shfl(rl, it);
            float q0 = __shfl(al, it);
            const float4* e0p = (const float4*)(ERk + (size_t)r0i*EHD);
            float4 e0 = e0p[lane];
            a0 += q0*e0.x; a1 += q0*e0.y; a2 += q0*e0.z; a3 += q0*e0.w;
            if(tail){
                float4 f0 = e0p[64+lane];
                t0 += q0*f0.x; t1 += q0*f0.y; t2 += q0*f0.z; t3 += q0*f0.w;
            }
        }
    } else {
        float mx = -1e30f;
        for(int it=s0; it<s1; it++){
            float lg = p + ck[clampi(adjrel[it], NR)];
            lg = lg > 0 ? lg : 0.01f*lg;
            mx = fmaxf(mx, lg);
        }
        float ss = 0;
        for(int it=s0; it<s1; it++){
            float lg = p + ck[clampi(adjrel[it], NR)];
            lg = lg > 0 ? lg : 0.01f*lg;
            ss += expf(lg - mx);
        }
        for(int it=s0; it<s1; it++){
            int r = clampi(adjrel[it], NR);
            float lg = p + ck[r];
            lg = lg > 0 ? lg : 0.01f*lg;
            float a = expf(lg - mx)/ss;
            const float4* er4 = (const float4*)(ERk + (size_t)r*EHD);
            float4 e0 = er4[lane];
            a0 += a*e0.x; a1 += a*e0.y; a2 += a*e0.z; a3 += a*e0.w;
            if(tail){
                float4 e1 = er4[64+lane];
                t0 += a*e1.x; t1 += a*e1.y; t2 += a*e1.z; t3 += a*e1.w;
            }
        }
    }
    xv[0] += fmaxf(a0,0.f); xv[1] += fmaxf(a1,0.f); xv[2] += fmaxf(a2,0.f); xv[3] += fmaxf(a3,0.f);
    if(tail){
        xv[4] += fmaxf(t0,0.f); xv[5] += fmaxf(t1,0.f); xv[6] += fmaxf(t2,0.f); xv[7] += fmaxf(t3,0.f);
    }
}

// ---------- fused: three r2e rounds + ajv, x row stays in registers ----------
__global__ void k_r2e3(bf16* __restrict__ x,
                       const int* __restrict__ off_h, const int* __restrict__ adj_h,
                       const int* __restrict__ off_t, const int* __restrict__ adj_t,
                       const float* __restrict__ ER, const float* __restrict__ cvec,
                       const float* __restrict__ ahw, const float* __restrict__ atw,
                       const float* __restrict__ ah1w, const float* __restrict__ ajw,
                       float* __restrict__ ajv){
    int wid = threadIdx.x >> 6, lane = threadIdx.x & 63;
    int n = blockIdx.x*4 + wid;
    if(n >= NN) return;
    bool tail = lane < 11;
    ushort4* xr4 = (ushort4*)(x + (size_t)n*EHD);
    float xv[8];
    {
        ushort4 v = xr4[lane];
        xv[0]=us2f(v.x); xv[1]=us2f(v.y); xv[2]=us2f(v.z); xv[3]=us2f(v.w);
        if(tail){
            ushort4 u = xr4[64+lane];
            xv[4]=us2f(u.x); xv[5]=us2f(u.y); xv[6]=us2f(u.z); xv[7]=us2f(u.w);
        } else { xv[4]=0; xv[5]=0; xv[6]=0; xv[7]=0; }
    }
    int h0 = off_h[n], h1 = off_h[n+1];
    int t0_ = off_t[n], t1_ = off_t[n+1];
    r2e_round(xv, tail, lane, h0, h1, adj_h, ER,                    cvec,      ahw);
    r2e_round(xv, tail, lane, t0_, t1_, adj_t, ER + (size_t)NR*EHD, cvec+NR,   atw);
    r2e_round(xv, tail, lane, h0, h1, adj_h, ER + (size_t)2*NR*EHD, cvec+2*NR, ah1w);
    // ajv[n] = x · ajw
    {
        const float4* aj4 = (const float4*)ajw;
        float4 am = aj4[lane];
        float p = xv[0]*am.x + xv[1]*am.y + xv[2]*am.z + xv[3]*am.w;
        if(tail){
            float4 at = aj4[64+lane];
            p += xv[4]*at.x + xv[5]*at.y + xv[6]*at.z + xv[7]*at.w;
        }
        p = wred_sum(p);
        if(lane == 0) ajv[n] = p;
    }
    ushort4 w0; w0.x=f2us(xv[0]); w0.y=f2us(xv[1]); w0.z=f2us(xv[2]); w0.w=f2us(xv[3]);
    xr4[lane] = w0;
    if(tail){
        ushort4 w1; w1.x=f2us(xv[4]); w1.y=f2us(xv[5]); w1.z=f2us(xv[6]); w1.w=f2us(xv[7]);
        xr4[64+lane] = w1;
    }
}

// ---------- final GAT + fc (f32 output); lane-parallel softmax + unroll2 gather ----------
__global__ void k_final(const bf16* __restrict__ x, const float* __restrict__ ajv,
                        const int* __restrict__ off, const int* __restrict__ adjj,
                        const float* __restrict__ aiw, const float* __restrict__ fcw,
                        const float* __restrict__ fcb, float* __restrict__ out){
    int wid = threadIdx.x >> 6, lane = threadIdx.x & 63;
    int n = blockIdx.x*4 + wid;
    if(n >= NN) return;
    bool tail = lane < 11;
    const ushort4* xr4 = (const ushort4*)(x + (size_t)n*EHD);
    const float4* ai4 = (const float4*)aiw;
    ushort4 xv = xr4[lane];
    ushort4 xt = tail ? xr4[64+lane] : ushort4{0,0,0,0};
    float4 am = ai4[lane];
    float4 at = tail ? ai4[64+lane] : float4{0,0,0,0};
    float p = us2f(xv.x)*am.x + us2f(xv.y)*am.y + us2f(xv.z)*am.z + us2f(xv.w)*am.w;
    if(tail) p += us2f(xt.x)*at.x + us2f(xt.y)*at.y + us2f(xt.z)*at.z + us2f(xt.w)*at.w;
    p = wred_sum(p);   // ai[n]
    int s0 = off[n], s1 = off[n+1], cnt = s1 - s0;
    float a0=0,a1=0,a2=0,a3=0, t0=0,t1=0,t2=0,t3=0;
    if(cnt > 0 && cnt <= 64){
        int jl = (lane < cnt) ? clampi(adjj[s0+lane], NN) : 0;
        float av = (lane < cnt) ? ajv[jl] : 0.f;
        float lg = p + av;
        lg = lg > 0 ? lg : 0.01f*lg;
        float mx = wred_max((lane < cnt) ? lg : -1e30f);
        float ex = (lane < cnt) ? expf(lg - mx) : 0.f;
        float ss = wred_sum(ex);
        float al = ex/ss;
        int it = 0;
        for(; it+2 <= cnt; it += 2){
            int j0 = __shfl(jl, it), j1 = __shfl(jl, it+1);
            float q0 = __shfl(al, it), q1 = __shfl(al, it+1);
            const ushort4* r0 = (const ushort4*)(x + (size_t)j0*EHD);
            const ushort4* r1 = (const ushort4*)(x + (size_t)j1*EHD);
            ushort4 v0 = r0[lane], v1 = r1[lane];
            a0 += q0*us2f(v0.x) + q1*us2f(v1.x);
            a1 += q0*us2f(v0.y) + q1*us2f(v1.y);
            a2 += q0*us2f(v0.z) + q1*us2f(v1.z);
            a3 += q0*us2f(v0.w) + q1*us2f(v1.w);
            if(tail){
                ushort4 u0 = r0[64+lane], u1 = r1[64+lane];
                t0 += q0*us2f(u0.x) + q1*us2f(u1.x);
                t1 += q0*us2f(u0.y) + q1*us2f(u1.y);
                t2 += q0*us2f(u0.z) + q1*us2f(u1.z);
                t3 += q0*us2f(u0.w) + q1*us2f(u1.w);
            }
        }
        if(it < cnt){
            int j0 = __shfl(jl, it);
            float q0 = __shfl(al, it);
            const ushort4* r0 = (const ushort4*)(x + (size_t)j0*EHD);
            ushort4 v0 = r0[lane];
            a0 += q0*us2f(v0.x); a1 += q0*us2f(v0.y); a2 += q0*us2f(v0.z); a3 += q0*us2f(v0.w);
            if(tail){
                ushort4 u0 = r0[64+lane];
                t0 += q0*us2f(u0.x); t1 += q0*us2f(u0.y); t2 += q0*us2f(u0.z); t3 += q0*us2f(u0.w);
            }
        }
    } else if(cnt > 64){
        float mx = -1e30f;
        for(int it=s0; it<s1; it++){
            float lg = p + ajv[clampi(adjj[it], NN)];
            lg = lg > 0 ? lg : 0.01f*lg;
            mx = fmaxf(mx, lg);
        }
        float ss = 0;
        for(int it=s0; it<s1; it++){
            float lg = p + ajv[clampi(adjj[it], NN)];
            lg = lg > 0 ? lg : 0.01f*lg;
            ss += expf(lg - mx);
        }
        for(int it=s0; it<s1; it++){
            int j = clampi(adjj[it], NN);
            float lg = p + ajv[j];
            lg = lg > 0 ? lg : 0.01f*lg;
            float a = expf(lg - mx)/ss;
            const ushort4* row = (const ushort4*)(x + (size_t)j*EHD);
            ushort4 v = row[lane];
            a0 += a*us2f(v.x); a1 += a*us2f(v.y); a2 += a*us2f(v.z); a3 += a*us2f(v.w);
            if(tail){
                ushort4 u = row[64+lane];
                t0 += a*us2f(u.x); t1 += a*us2f(u.y); t2 += a*us2f(u.z); t3 += a*us2f(u.w);
            }
        }
    }
    const float4* f4 = (const float4*)fcw;    // fcw[600]
    float4 f0 = f4[lane];
    float4 g0 = f4[75 + lane];
    float part = us2f(xv.x)*f0.x + us2f(xv.y)*f0.y + us2f(xv.z)*f0.z + us2f(xv.w)*f0.w
               + fmaxf(a0,0.f)*g0.x + fmaxf(a1,0.f)*g0.y + fmaxf(a2,0.f)*g0.z + fmaxf(a3,0.f)*g0.w;
    if(tail){
        float4 f1 = f4[64 + lane];
        float4 g1 = f4[139 + lane];
        part += us2f(xt.x)*f1.x + us2f(xt.y)*f1.y + us2f(xt.z)*f1.z + us2f(xt.w)*f1.w
              + fmaxf(t0,0.f)*g1.x + fmaxf(t1,0.f)*g1.y + fmaxf(t2,0.f)*g1.z + fmaxf(t3,0.f)*g1.w;
    }
    part = wred_sum(part);
    if(lane == 0) out[n] = part + fcb[0];
}

extern "C" void kernel_launch(void* const* d_in, const int* in_sizes, int n_in,
                              void* d_out, int out_size, void* d_ws, size_t ws_size,
                              hipStream_t stream){
    const float* x_in = (const float*)d_in[0];
    const int*  ht   = (const int*)d_in[1];   // [0,NE)=h, [NE,2NE)=t
    const int*  rel  = (const int*)d_in[2];
    const int*  ji   = (const int*)d_in[3];   // [0,NEA)=j, [NEA,2NEA)=i
    const float* hw1w=(const float*)d_in[5];  const float* hw1b=(const float*)d_in[6];
    const float* hw2w=(const float*)d_in[7];  const float* hw2b=(const float*)d_in[8];
    const float* tc1w=(const float*)d_in[9];  const float* tc1b=(const float*)d_in[10];
    const float* sr1w=(const float*)d_in[11]; const float* sr1b=(const float*)d_in[12];
    // d_in[13]=a1_w, d_in[14]=a5_w: mathematically dead (uniform per-segment logits)
    const float* wrw =(const float*)d_in[15]; const float* wrb =(const float*)d_in[16];
    const float* wr1w=(const float*)d_in[17]; const float* wr1b=(const float*)d_in[18];
    const float* wr2w=(const float*)d_in[19]; const float* wr2b=(const float*)d_in[20];
    const float* ahw =(const float*)d_in[21]; const float* ah1w=(const float*)d_in[22];
    const float* atw =(const float*)d_in[23];
    const float* ar1 =(const float*)d_in[24]; const float* ar2 =(const float*)d_in[25];
    const float* ar3 =(const float*)d_in[26];
    const float* aiw =(const float*)d_in[27]; const float* ajw =(const float*)d_in[28];
    const float* fcw =(const float*)d_in[29]; const float* fcb =(const float*)d_in[30];
    float* out = (float*)d_out;

    // ---- workspace layout: ~68 MB. Feature scratch bf16, compute f32. ----
    char* w = (char*)d_ws;
    auto alloc = [&](size_t bytes)->char*{ char* p = w; w += (bytes + 255)/256*256; return p; };
    bf16* xF = (bf16*)alloc((size_t)NN*EHD*2);   // 30 MB; bf16(x_in) -> then x2..final x
    bf16* B  = (bf16*)alloc((size_t)NN*EHD*2);   // 30 MB; agg -> x1, dead after hw2 GEMM
    char* Bc = (char*)B;
    bf16*  sbuf = (bf16*)(Bc);                        // 10 MB  [NN*THD] bf16
    float* RF   = (float*)(Bc + 11u*1024*1024);       // 360 KB
    float* ER   = (float*)(Bc + 12u*1024*1024);       // 1.08 MB
    float* cvec = (float*)(Bc + 14u*1024*1024);       // 3.6 KB
    float* ajv  = (float*)(Bc + 15u*1024*1024);       // 200 KB
    short* Wt1 = (short*)alloc((size_t)EHD*EHD*2);
    short* Wt2 = (short*)alloc((size_t)EHD*EHD*2);
    short* Wtc = (short*)alloc((size_t)EHD*THD*2);
    float* dinv = (float*)alloc((size_t)NN*4);
    int* degs   = (int*)alloc((size_t)(3*NN + NR)*4);  // contiguous: deg_all|deg_h|deg_t|cnt_rel
    int* deg_all = degs, *deg_h = degs + NN, *deg_t = degs + 2*NN, *cnt_rel = degs + 3*NN;
    int* off_all=(int*)alloc((NN+1)*4); int* cur_all=(int*)alloc(NN*4);
    int* adj_all=(int*)alloc((size_t)NEA*4);
    int* off_h  =(int*)alloc((NN+1)*4); int* cur_h  =(int*)alloc(NN*4);
    int* adj_h  =(int*)alloc((size_t)NE*4);
    int* off_t  =(int*)alloc((NN+1)*4); int* cur_t  =(int*)alloc(NN*4);
    int* adj_t  =(int*)alloc((size_t)NE*4);
    int* off_r =(int*)alloc((NR+1)*4);  int* cur_r  =(int*)alloc(NR*4);
    int* adj_r  =(int*)alloc((size_t)NE*4);

    const int NZ = 3*NN + NR;
    k_zero_i32<<<dim3((NZ+255)/256), dim3(256), 0, stream>>>(degs, NZ);

    // prep: bf16 cast of x_in (into xF), transposed bf16 weights
    const int N4 = NN*EHD/4;
    k_cast4<<<dim3((N4+255)/256), dim3(256), 0, stream>>>((const float4*)x_in, (ushort*)xF, N4);
    const int NPW = 2*EHD*EHD + EHD*THD;
    k_prepw3<<<dim3((NPW+255)/256), dim3(256), 0, stream>>>(hw1w, hw2w, tc1w, Wt1, Wt2, Wtc);

    k_count<<<dim3((NEA+255)/256), dim3(256), 0, stream>>>(ji, ht, rel, deg_all, deg_h, deg_t, cnt_rel);
    k_scan<<<dim3(4), dim3(1024), 0, stream>>>(deg_all, off_all, cur_all, deg_h, off_h, cur_h,
                                               deg_t, off_t, cur_t, cnt_rel, off_r, cur_r);
    k_fill<<<dim3((NEA+255)/256), dim3(256), 0, stream>>>(ji, ht, rel, cur_all, adj_all,
                                                          cur_h, adj_h, cur_t, adj_t, cur_r, adj_r);
    k_dinv<<<dim3((NN+255)/256), dim3(256), 0, stream>>>(deg_all, dinv);

    const int nb4 = (NN+3)/4;
    const dim3 gg((NN+63)/64, (EHD+63)/64);
    // highway 1: B = gcn(xF); B = sig(xF@hw1+b)*B + (1-sig)*xF
    k_gcn<<<dim3(nb4), dim3(256), 0, stream>>>(xF, B, off_all, adj_all, dinv);
    k_gemm_mfma<1><<<gg, dim3(256), 0, stream>>>(xF, Wt1, hw1b, B, xF, NN, EHD, EHD);
    // highway 2: xF = gcn(B); xF = sig(B@hw2+b)*xF + (1-sig)*B
    k_gcn<<<dim3(nb4), dim3(256), 0, stream>>>(B, xF, off_all, adj_all, dinv);
    k_gemm_mfma<1><<<gg, dim3(256), 0, stream>>>(B, Wt2, hw2b, xF, B, NN, EHD, EHD);
    // ---- B is now dead; aliases (sbuf, RF, ER, cvec, ajv) come alive ----
    k_gemm_mfma<0><<<dim3((NN+63)/64, (THD+63)/64), dim3(256), 0, stream>>>(xF, Wtc, tc1b, sbuf, xF, NN, EHD, THD);
    k_zero_f32<<<dim3((NR*EHD+255)/256), dim3(256), 0, stream>>>(RF, NR*EHD);
    k_relsum2<<<dim3(NR, RCH), dim3(128), 0, stream>>>(sbuf, ht, off_r, adj_r, RF);
    k_relfin<<<dim3(NR), dim3(128), 0, stream>>>(sr1w, sr1b, off_r, RF);
    k_reler<<<dim3(NR, 3), dim3(256), 0, stream>>>(RF, wrw, wrb, wr1w, wr1b, wr2w, wr2b, ER);
    k_relc<<<dim3(NR, 3), dim3(64), 0, stream>>>(ER, ar1, ar2, ar3, cvec);
    // fused three r2e rounds + ajv
    k_r2e3<<<dim3(nb4), dim3(256), 0, stream>>>(xF, off_h, adj_h, off_t, adj_t, ER, cvec,
                                                ahw, atw, ah1w, ajw, ajv);
    // final GAT + fc
    k_final<<<dim3(nb4), dim3(256), 0, stream>>>(xF, ajv, off_all, adj_all, aiw, fcw, fcb, out);
}

// Round 8
// 972.117 us; speedup vs baseline: 1.8156x; 1.1224x over previous
//
#include <hip/hip_runtime.h>
#include <hip/hip_bf16.h>

typedef __hip_bfloat16 bf16;
typedef __attribute__((ext_vector_type(8))) short bf16x8_t;
typedef __attribute__((ext_vector_type(4))) float f32x4_t;

__device__ __forceinline__ float b2f(bf16 v){ return __bfloat162float(v); }
__device__ __forceinline__ bf16 f2b(float v){ return __float2bfloat16(v); }
__device__ __forceinline__ short tobits(float v){ bf16 b = f2b(v); return *(short*)&b; }
__device__ __forceinline__ float us2f(ushort u){ return __uint_as_float(((unsigned)u)<<16); }
__device__ __forceinline__ ushort f2us(float v){ bf16 b = f2b(v); return *(ushort*)&b; }

#define NN 50000
#define NE 250000
#define NEA 500000
#define NR 300
#define EHD 300
#define THD 100
#define RHD 100
#define RCH 8
#define NBN 98      // node buckets (512 wide)
#define NBR 75      // rel buckets (4 wide)

__device__ __forceinline__ int clampi(int v, int n){ return ((unsigned)v < (unsigned)n) ? v : 0; }

__device__ __forceinline__ float wred_sum(float p){
    #pragma unroll
    for(int m=32;m>=1;m>>=1) p += __shfl_xor(p, m);
    return p;
}
__device__ __forceinline__ float wred_max(float p){
    #pragma unroll
    for(int m=32;m>=1;m>>=1) p = fmaxf(p, __shfl_xor(p, m));
    return p;
}

__global__ void k_zero_f32(float* __restrict__ p, int n){
    int i = blockIdx.x*256 + threadIdx.x;
    if(i < n) p[i] = 0.f;
}

// ---------- fused prep: zero degs | bf16 cast of x | 3 weight transposes ----------
__global__ void k_prep(const float4* __restrict__ xin4, ushort* __restrict__ xFu,
                       const float* __restrict__ hw1w, const float* __restrict__ hw2w,
                       const float* __restrict__ tc1w,
                       short* __restrict__ Wt1, short* __restrict__ Wt2, short* __restrict__ Wtc,
                       int* __restrict__ degs){
    int i = blockIdx.x*256 + threadIdx.x;
    const int NZ = 3*NN + NR;
    if(i < NZ) degs[i] = 0;
    const int N4 = NN*EHD/4;
    if(i < N4){
        float4 v = xin4[i];
        ushort4 o;
        o.x = (ushort)tobits(v.x); o.y = (ushort)tobits(v.y);
        o.z = (ushort)tobits(v.z); o.w = (ushort)tobits(v.w);
        *(ushort4*)(xFu + 4*(size_t)i) = o;
    }
    const int S1 = EHD*EHD, S2 = 2*EHD*EHD, S3 = 2*EHD*EHD + EHD*THD;
    if(i < S1){
        int n = i/EHD, k = i - n*EHD;
        Wt1[i] = tobits(hw1w[(size_t)k*EHD + n]);
    } else if(i < S2){
        int ii = i - S1; int n = ii/EHD, k = ii - n*EHD;
        Wt2[ii] = tobits(hw2w[(size_t)k*EHD + n]);
    } else if(i < S3){
        int ii = i - S2; int n = ii/EHD, k = ii - n*EHD;
        Wtc[ii] = tobits(tc1w[(size_t)k*THD + n]);
    }
}

// ---------- degree counting ----------
__global__ void k_count(const int* __restrict__ ji, const int* __restrict__ ht,
                        const int* __restrict__ rel,
                        int* deg_all, int* deg_h, int* deg_t, int* cnt_rel){
    int e = blockIdx.x*256 + threadIdx.x;
    if(e < NEA) atomicAdd(&deg_all[clampi(ji[NEA + e], NN)], 1);
    if(e < NE){
        atomicAdd(&deg_h[clampi(ht[e], NN)], 1);
        atomicAdd(&deg_t[clampi(ht[NE + e], NN)], 1);
        atomicAdd(&cnt_rel[clampi(rel[e], NR)], 1);
    }
}

// ---------- scan (4 segments) + dinv + bucket-cursor init ----------
__global__ void k_scan(const int* d0, int* o0, const int* d1, int* o1,
                       const int* d2, int* o2, const int* d3, int* o3,
                       int* gc0, int* gc1, int* gc2, int* gc3,
                       float* __restrict__ dinv){
    const int* deg; int* off; int* gc; int len;
    if(blockIdx.x == 0){ deg=d0; off=o0; gc=gc0; len=NN; }
    else if(blockIdx.x == 1){ deg=d1; off=o1; gc=gc1; len=NN; }
    else if(blockIdx.x == 2){ deg=d2; off=o2; gc=gc2; len=NN; }
    else { deg=d3; off=o3; gc=gc3; len=NR; }
    __shared__ int lds[1024];
    int tid = threadIdx.x;
    const int CH = (len + 1023)/1024;
    int lo = tid*CH, hi = lo+CH; if(hi > len) hi = len; if(lo > len) lo = len;
    int lsum = 0;
    for(int k=lo;k<hi;k++){
        int d = deg[k];
        lsum += d;
        if(blockIdx.x == 0) dinv[k] = d > 0 ? rsqrtf((float)d) : 0.f;
    }
    lds[tid] = lsum; __syncthreads();
    for(int s=1;s<1024;s<<=1){
        int v = (tid >= s) ? lds[tid-s] : 0;
        __syncthreads();
        lds[tid] += v;
        __syncthreads();
    }
    int excl = lds[tid] - lsum;
    int run = excl;
    for(int k=lo;k<hi;k++){ off[k]=run; run += deg[k]; }
    if(tid == 1023) off[len] = lds[1023];
    __syncthreads();
    int NB = (len == NN) ? NBN : NBR;
    int W  = (len == NN) ? 512 : 4;
    for(int b=tid; b<NB; b+=1024) gc[b] = off[b*W];
}

// ---------- Phase C: LDS-staged binning into bucket-ordered tmp (int2 = key,payload) ----------
__global__ __launch_bounds__(256) void k_bin(const int* __restrict__ ji, const int* __restrict__ ht,
                      const int* __restrict__ rel,
                      int* gc0, int* gc1, int* gc2, int* gc3,
                      int2* __restrict__ t0, int2* __restrict__ t1,
                      int2* __restrict__ t2, int2* __restrict__ t3){
    int s = blockIdx.y;
    int n_s = (s == 0) ? NEA : NE;
    int base_e = blockIdx.x*2048;
    if(base_e >= n_s) return;
    int shift = (s < 3) ? 9 : 2;
    int tid = threadIdx.x;
    __shared__ int cnt[128], lof[128], base[128];
    __shared__ int2 buf[2048];
    if(tid < 128) cnt[tid] = 0;
    __syncthreads();
    int kk[8], pp[8], bb[8], ss[8];
    #pragma unroll
    for(int u=0;u<8;u++){
        int e = base_e + u*256 + tid;
        bb[u] = -1;
        if(e < n_s){
            int key, pay;
            if(s == 0){ key = clampi(ji[NEA + e], NN); pay = clampi(ji[e], NN); }
            else if(s == 1){ key = clampi(ht[e], NN); pay = clampi(rel[e], NR); }
            else if(s == 2){ key = clampi(ht[NE + e], NN); pay = clampi(rel[e], NR); }
            else { key = clampi(rel[e], NR); pay = e; }
            int b = key >> shift;
            kk[u] = key; pp[u] = pay; bb[u] = b;
            ss[u] = atomicAdd(&cnt[b], 1);
        }
    }
    __syncthreads();
    if(tid == 0){
        int run = 0;
        for(int b=0;b<128;b++){ lof[b] = run; run += cnt[b]; }
    }
    __syncthreads();
    #pragma unroll
    for(int u=0;u<8;u++){
        if(bb[u] >= 0){
            int pos = lof[bb[u]] + ss[u];
            buf[pos] = make_int2(kk[u], pp[u]);
        }
    }
    __syncthreads();
    int* gc = (s==0) ? gc0 : (s==1) ? gc1 : (s==2) ? gc2 : gc3;
    if(tid < 128 && cnt[tid] > 0) base[tid] = atomicAdd(&gc[tid], cnt[tid]);
    __syncthreads();
    int2* tmp = (s==0) ? t0 : (s==1) ? t1 : (s==2) ? t2 : t3;
    int total = lof[127] + cnt[127];
    for(int idx=tid; idx<total; idx+=256){
        int2 kp = buf[idx];
        int b = kp.x >> shift;
        tmp[base[b] + (idx - lof[b])] = kp;
    }
}

// ---------- Phase D: windowed CSR fill with LDS cursors ----------
__global__ __launch_bounds__(256) void k_place(const int* __restrict__ off_all, const int* __restrict__ off_h,
                        const int* __restrict__ off_t, const int* __restrict__ off_r,
                        const int2* __restrict__ t0, const int2* __restrict__ t1,
                        const int2* __restrict__ t2, const int2* __restrict__ t3,
                        int* __restrict__ adj_all, int* __restrict__ adj_h,
                        int* __restrict__ adj_t, int* __restrict__ adj_r){
    int s = blockIdx.y, b = blockIdx.x;
    int NB = (s < 3) ? NBN : NBR;
    if(b >= NB) return;
    int W = (s < 3) ? 512 : 4;
    int NNN = (s < 3) ? NN : NR;
    const int* off = (s==0) ? off_all : (s==1) ? off_h : (s==2) ? off_t : off_r;
    const int2* tmp = (s==0) ? t0 : (s==1) ? t1 : (s==2) ? t2 : t3;
    int* adj = (s==0) ? adj_all : (s==1) ? adj_h : (s==2) ? adj_t : adj_r;
    int node0 = b*W;
    int node1 = node0 + W; if(node1 > NNN) node1 = NNN;
    __shared__ int cur[512];
    int tid = threadIdx.x;
    for(int k=tid; k<node1-node0; k+=256) cur[k] = off[node0 + k];
    __syncthreads();
    int gstart = off[node0], gend = off[node1];
    for(int idx = gstart + tid; idx < gend; idx += 256){
        int2 kp = tmp[idx];
        int local = kp.x - node0;
        if((unsigned)local < (unsigned)(node1-node0)){
            int slot = atomicAdd(&cur[local], 1);
            adj[slot] = kp.y;
        }
    }
}

// ---------- GCN gather: wave per node, unroll-4 ----------
__global__ void k_gcn(const bf16* __restrict__ xs, bf16* __restrict__ xd,
                      const int* __restrict__ off, const int* __restrict__ adjj,
                      const float* __restrict__ dinv){
    int wid = threadIdx.x >> 6, lane = threadIdx.x & 63;
    int n = blockIdx.x*4 + wid;
    if(n >= NN) return;
    float di = dinv[n];
    int s0 = off[n], s1 = off[n+1], cnt = s1 - s0;
    bool tail = lane < 11;
    float a0=0,a1=0,a2=0,a3=0, t0=0,t1=0,t2=0,t3=0;
    if(cnt > 0 && cnt <= 64){
        int jl = (lane < cnt) ? clampi(adjj[s0+lane], NN) : 0;
        float dl = (lane < cnt) ? dinv[jl] : 0.f;
        int it = 0;
        for(; it+4 <= cnt; it += 4){
            int j0=__shfl(jl,it), j1=__shfl(jl,it+1), j2=__shfl(jl,it+2), j3=__shfl(jl,it+3);
            float n0=di*__shfl(dl,it), n1=di*__shfl(dl,it+1), n2=di*__shfl(dl,it+2), n3=di*__shfl(dl,it+3);
            const ushort4* r0 = (const ushort4*)(xs + (size_t)j0*EHD);
            const ushort4* r1 = (const ushort4*)(xs + (size_t)j1*EHD);
            const ushort4* r2 = (const ushort4*)(xs + (size_t)j2*EHD);
            const ushort4* r3 = (const ushort4*)(xs + (size_t)j3*EHD);
            ushort4 v0=r0[lane], v1=r1[lane], v2=r2[lane], v3=r3[lane];
            a0 += n0*us2f(v0.x)+n1*us2f(v1.x)+n2*us2f(v2.x)+n3*us2f(v3.x);
            a1 += n0*us2f(v0.y)+n1*us2f(v1.y)+n2*us2f(v2.y)+n3*us2f(v3.y);
            a2 += n0*us2f(v0.z)+n1*us2f(v1.z)+n2*us2f(v2.z)+n3*us2f(v3.z);
            a3 += n0*us2f(v0.w)+n1*us2f(v1.w)+n2*us2f(v2.w)+n3*us2f(v3.w);
            if(tail){
                ushort4 u0=r0[64+lane], u1=r1[64+lane], u2=r2[64+lane], u3=r3[64+lane];
                t0 += n0*us2f(u0.x)+n1*us2f(u1.x)+n2*us2f(u2.x)+n3*us2f(u3.x);
                t1 += n0*us2f(u0.y)+n1*us2f(u1.y)+n2*us2f(u2.y)+n3*us2f(u3.y);
                t2 += n0*us2f(u0.z)+n1*us2f(u1.z)+n2*us2f(u2.z)+n3*us2f(u3.z);
                t3 += n0*us2f(u0.w)+n1*us2f(u1.w)+n2*us2f(u2.w)+n3*us2f(u3.w);
            }
        }
        for(; it < cnt; it++){
            int j0 = __shfl(jl, it);
            float n0 = di*__shfl(dl, it);
            const ushort4* r0 = (const ushort4*)(xs + (size_t)j0*EHD);
            ushort4 v0 = r0[lane];
            a0 += n0*us2f(v0.x); a1 += n0*us2f(v0.y); a2 += n0*us2f(v0.z); a3 += n0*us2f(v0.w);
            if(tail){
                ushort4 u0 = r0[64+lane];
                t0 += n0*us2f(u0.x); t1 += n0*us2f(u0.y); t2 += n0*us2f(u0.z); t3 += n0*us2f(u0.w);
            }
        }
    } else if(cnt > 64){
        for(int it=s0; it<s1; it++){
            int j = clampi(adjj[it], NN);
            float nr = di * dinv[j];
            const ushort4* row = (const ushort4*)(xs + (size_t)j*EHD);
            ushort4 v = row[lane];
            a0 += nr*us2f(v.x); a1 += nr*us2f(v.y); a2 += nr*us2f(v.z); a3 += nr*us2f(v.w);
            if(tail){
                ushort4 u = row[64+lane];
                t0 += nr*us2f(u.x); t1 += nr*us2f(u.y); t2 += nr*us2f(u.z); t3 += nr*us2f(u.w);
            }
        }
    }
    ushort4* o = (ushort4*)(xd + (size_t)n*EHD);
    ushort4 w0; w0.x=f2us(fmaxf(a0,0.f)); w0.y=f2us(fmaxf(a1,0.f)); w0.z=f2us(fmaxf(a2,0.f)); w0.w=f2us(fmaxf(a3,0.f));
    o[lane] = w0;
    if(tail){
        ushort4 w1; w1.x=f2us(fmaxf(t0,0.f)); w1.y=f2us(fmaxf(t1,0.f)); w1.z=f2us(fmaxf(t2,0.f)); w1.w=f2us(fmaxf(t3,0.f));
        o[64+lane] = w1;
    }
}

// ---------- MFMA GEMM ----------
template<int MODE>
__global__ __launch_bounds__(256) void k_gemm_mfma(const bf16* __restrict__ X,
                       const short* __restrict__ Wt, const float* __restrict__ bias,
                       bf16* __restrict__ out, const bf16* __restrict__ Xprev,
                       int M, int K, int Ncols){
    __shared__ short As[64][40];
    __shared__ short Bs[64][40];
    int tid = threadIdx.x;
    int bm = blockIdx.x*64, bn = blockIdx.y*64;
    int wid = tid>>6, lane = tid&63;
    int wm = (wid&1)*32, wn = (wid>>1)*32;
    int lm = lane&15, lq = lane>>4;
    f32x4_t acc00={0,0,0,0}, acc01={0,0,0,0}, acc10={0,0,0,0}, acc11={0,0,0,0};
    int mrow = tid>>2, kc = (tid&3)*8;
    union U8 { bf16x8_t v; uint2 u[2]; short s[8]; };
    for(int k0=0; k0<K; k0+=32){
        int gk0 = k0 + kc;
        {
            int gm = bm + mrow;
            U8 a;
            if(gm < M && gk0 + 8 <= K){
                const uint2* src = (const uint2*)(X + (size_t)gm*K + gk0);
                a.u[0] = src[0]; a.u[1] = src[1];
            } else {
                #pragma unroll
                for(int j=0;j<8;j++){
                    int gk = gk0 + j;
                    a.s[j] = (gm < M && gk < K) ? (short)*(const short*)(X + (size_t)gm*K + gk) : (short)0;
                }
                if(gm >= M){ a.u[0] = {0,0}; a.u[1] = {0,0}; }
            }
            *(bf16x8_t*)&As[mrow][kc] = a.v;
        }
        {
            int gn = bn + mrow;
            U8 b;
            if(gn < Ncols && gk0 + 8 <= K){
                const uint2* src = (const uint2*)(Wt + (size_t)gn*K + gk0);
                b.u[0] = src[0]; b.u[1] = src[1];
            } else {
                #pragma unroll
                for(int j=0;j<8;j++){
                    int gk = gk0 + j;
                    b.s[j] = (gn < Ncols && gk < K) ? Wt[(size_t)gn*K + gk] : (short)0;
                }
                if(gn >= Ncols){ b.u[0] = {0,0}; b.u[1] = {0,0}; }
            }
            *(bf16x8_t*)&Bs[mrow][kc] = b.v;
        }
        __syncthreads();
        bf16x8_t a0 = *(bf16x8_t*)&As[wm + lm][lq*8];
        bf16x8_t a1 = *(bf16x8_t*)&As[wm + 16 + lm][lq*8];
        bf16x8_t b0 = *(bf16x8_t*)&Bs[wn + lm][lq*8];
        bf16x8_t b1 = *(bf16x8_t*)&Bs[wn + 16 + lm][lq*8];
        acc00 = __builtin_amdgcn_mfma_f32_16x16x32_bf16(a0, b0, acc00, 0, 0, 0);
        acc01 = __builtin_amdgcn_mfma_f32_16x16x32_bf16(a0, b1, acc01, 0, 0, 0);
        acc10 = __builtin_amdgcn_mfma_f32_16x16x32_bf16(a1, b0, acc10, 0, 0, 0);
        acc11 = __builtin_amdgcn_mfma_f32_16x16x32_bf16(a1, b1, acc11, 0, 0, 0);
        __syncthreads();
    }
    #pragma unroll
    for(int tm=0;tm<2;tm++){
        #pragma unroll
        for(int tn=0;tn<2;tn++){
            f32x4_t a = tm==0 ? (tn==0 ? acc00 : acc01) : (tn==0 ? acc10 : acc11);
            int gn = bn + wn + tn*16 + lm;
            if(gn >= Ncols) continue;
            float bi = bias[gn];
            #pragma unroll
            for(int r=0;r<4;r++){
                int gm = bm + wm + tm*16 + lq*4 + r;
                if(gm >= M) continue;
                float t = a[r] + bi;
                size_t p = (size_t)gm*Ncols + gn;
                if(MODE == 0){
                    out[p] = f2b(t);
                } else {
                    float g = 1.f/(1.f + expf(-t));
                    out[p] = f2b(g*b2f(out[p]) + (1.f - g)*b2f(Xprev[p]));
                }
            }
        }
    }
}

// ---------- chunked per-relation sums into RF[r][100..299] ----------
__global__ void k_relsum2(const bf16* __restrict__ s, const int* __restrict__ ht,
                          const int* __restrict__ off_r, const int* __restrict__ adj_r,
                          float* __restrict__ RF){
    int r = blockIdx.x, c = blockIdx.y, d = threadIdx.x;
    int s0 = off_r[r], s1 = off_r[r+1];
    int cnt = s1 - s0;
    if(cnt <= 0) return;
    int per = (cnt + RCH - 1)/RCH;
    int lo = s0 + c*per, hi = lo + per; if(hi > s1) hi = s1;
    if(lo >= hi) return;
    if(d >= THD) return;
    float ah = 0.f, at2 = 0.f;
    for(int it=lo; it<hi; it++){
        int e = clampi(adj_r[it], NE);
        int hh = clampi(ht[e], NN), tt = clampi(ht[NE + e], NN);
        ah  += b2f(s[(size_t)hh*THD + d]);
        at2 += b2f(s[(size_t)tt*THD + d]);
    }
    atomicAdd(&RF[(size_t)r*EHD + THD   + d], ah);
    atomicAdd(&RF[(size_t)r*EHD + 2*THD + d], at2);
}

// ---------- normalize means + x_type ----------
__global__ void k_relfin(const float* __restrict__ sr1w, const float* __restrict__ sr1b,
                         const int* __restrict__ off_r, float* __restrict__ RF){
    int r = blockIdx.x, d = threadIdx.x;
    int cnt = off_r[r+1] - off_r[r];
    float inv = 1.f/(float)(cnt > 1 ? cnt : 1);
    if(d < THD){
        RF[(size_t)r*EHD + THD   + d] *= inv;
        RF[(size_t)r*EHD + 2*THD + d] *= inv;
    }
    __syncthreads();
    if(d < RHD){
        float v = 0.f;
        if(cnt > 0){
            v = sr1b[d];
            for(int k2=0; k2<2*THD; k2++) v += RF[(size_t)r*EHD + THD + k2] * sr1w[k2*RHD + d];
        }
        RF[(size_t)r*EHD + d] = v;
    }
}

// ---------- ER + cvec fused ----------
__global__ void k_reler(const float* __restrict__ RF,
                        const float* w0, const float* b0, const float* w1, const float* b1,
                        const float* w2, const float* b2,
                        const float* ar1, const float* ar2, const float* ar3,
                        float* __restrict__ ER, float* __restrict__ cvec){
    int r = blockIdx.x, kk = blockIdx.y;
    const float* w = kk==0 ? w0 : (kk==1 ? w1 : w2);
    const float* b = kk==0 ? b0 : (kk==1 ? b1 : b2);
    const float* a = kk==0 ? ar1 : (kk==1 ? ar2 : ar3);
    int tid = threadIdx.x;
    float pd = 0.f;
    for(int o = tid; o < EHD; o += 256){
        float v = b[o];
        for(int d=0; d<EHD; d++) v += RF[(size_t)r*EHD + d] * w[(size_t)d*EHD + o];
        ER[((size_t)kk*NR + r)*EHD + o] = v;
        pd += v * a[o];
    }
    __shared__ float red[4];
    pd = wred_sum(pd);
    if((tid & 63) == 0) red[tid>>6] = pd;
    __syncthreads();
    if(tid == 0) cvec[kk*NR + r] = red[0]+red[1]+red[2]+red[3];
}

// ---------- one r2e round on a register-resident x row ----------
__device__ __forceinline__ void r2e_round(float* xv, bool tail, int lane, int s0, int s1,
        const int* __restrict__ adjrel, const float* __restrict__ ERk,
        const float* __restrict__ ck, const float* __restrict__ anode){
    const float4* an4 = (const float4*)anode;
    float4 am = an4[lane];
    float p = xv[0]*am.x + xv[1]*am.y + xv[2]*am.z + xv[3]*am.w;
    if(tail){
        float4 at = an4[64+lane];
        p += xv[4]*at.x + xv[5]*at.y + xv[6]*at.z + xv[7]*at.w;
    }
    p = wred_sum(p);
    int cnt = s1 - s0;
    if(cnt <= 0) return;
    float a0=0,a1=0,a2=0,a3=0, t0=0,t1=0,t2=0,t3=0;
    if(cnt <= 64){
        int rl = (lane < cnt) ? clampi(adjrel[s0+lane], NR) : 0;
        float lg = p + ck[rl];
        lg = lg > 0 ? lg : 0.01f*lg;
        float mx = wred_max((lane < cnt) ? lg : -1e30f);
        float ex = (lane < cnt) ? expf(lg - mx) : 0.f;
        float ss = wred_sum(ex);
        float al = ex/ss;
        int it = 0;
        for(; it+2 <= cnt; it += 2){
            int r0i = __shfl(rl, it), r1i = __shfl(rl, it+1);
            float q0 = __shfl(al, it), q1 = __shfl(al, it+1);
            const float4* e0p = (const float4*)(ERk + (size_t)r0i*EHD);
            const float4* e1p = (const float4*)(ERk + (size_t)r1i*EHD);
            float4 e0 = e0p[lane], e1 = e1p[lane];
            a0 += q0*e0.x + q1*e1.x; a1 += q0*e0.y + q1*e1.y;
            a2 += q0*e0.z + q1*e1.z; a3 += q0*e0.w + q1*e1.w;
            if(tail){
                float4 f0 = e0p[64+lane], f1 = e1p[64+lane];
                t0 += q0*f0.x + q1*f1.x; t1 += q0*f0.y + q1*f1.y;
                t2 += q0*f0.z + q1*f1.z; t3 += q0*f0.w + q1*f1.w;
            }
        }
        if(it < cnt){
            int r0i = __shfl(rl, it);
            float q0 = __shfl(al, it);
            const float4* e0p = (const float4*)(ERk + (size_t)r0i*EHD);
            float4 e0 = e0p[lane];
            a0 += q0*e0.x; a1 += q0*e0.y; a2 += q0*e0.z; a3 += q0*e0.w;
            if(tail){
                float4 f0 = e0p[64+lane];
                t0 += q0*f0.x; t1 += q0*f0.y; t2 += q0*f0.z; t3 += q0*f0.w;
            }
        }
    } else {
        float mx = -1e30f;
        for(int it=s0; it<s1; it++){
            float lg = p + ck[clampi(adjrel[it], NR)];
            lg = lg > 0 ? lg : 0.01f*lg;
            mx = fmaxf(mx, lg);
        }
        float ss = 0;
        for(int it=s0; it<s1; it++){
            float lg = p + ck[clampi(adjrel[it], NR)];
            lg = lg > 0 ? lg : 0.01f*lg;
            ss += expf(lg - mx);
        }
        for(int it=s0; it<s1; it++){
            int r = clampi(adjrel[it], NR);
            float lg = p + ck[r];
            lg = lg > 0 ? lg : 0.01f*lg;
            float a = expf(lg - mx)/ss;
            const float4* er4 = (const float4*)(ERk + (size_t)r*EHD);
            float4 e0 = er4[lane];
            a0 += a*e0.x; a1 += a*e0.y; a2 += a*e0.z; a3 += a*e0.w;
            if(tail){
                float4 e1 = er4[64+lane];
                t0 += a*e1.x; t1 += a*e1.y; t2 += a*e1.z; t3 += a*e1.w;
            }
        }
    }
    xv[0] += fmaxf(a0,0.f); xv[1] += fmaxf(a1,0.f); xv[2] += fmaxf(a2,0.f); xv[3] += fmaxf(a3,0.f);
    if(tail){
        xv[4] += fmaxf(t0,0.f); xv[5] += fmaxf(t1,0.f); xv[6] += fmaxf(t2,0.f); xv[7] += fmaxf(t3,0.f);
    }
}

// ---------- fused: three r2e rounds + ajv ----------
__global__ void k_r2e3(bf16* __restrict__ x,
                       const int* __restrict__ off_h, const int* __restrict__ adj_h,
                       const int* __restrict__ off_t, const int* __restrict__ adj_t,
                       const float* __restrict__ ER, const float* __restrict__ cvec,
                       const float* __restrict__ ahw, const float* __restrict__ atw,
                       const float* __restrict__ ah1w, const float* __restrict__ ajw,
                       float* __restrict__ ajv){
    int wid = threadIdx.x >> 6, lane = threadIdx.x & 63;
    int n = blockIdx.x*4 + wid;
    if(n >= NN) return;
    bool tail = lane < 11;
    ushort4* xr4 = (ushort4*)(x + (size_t)n*EHD);
    float xv[8];
    {
        ushort4 v = xr4[lane];
        xv[0]=us2f(v.x); xv[1]=us2f(v.y); xv[2]=us2f(v.z); xv[3]=us2f(v.w);
        if(tail){
            ushort4 u = xr4[64+lane];
            xv[4]=us2f(u.x); xv[5]=us2f(u.y); xv[6]=us2f(u.z); xv[7]=us2f(u.w);
        } else { xv[4]=0; xv[5]=0; xv[6]=0; xv[7]=0; }
    }
    int h0 = off_h[n], h1 = off_h[n+1];
    int t0_ = off_t[n], t1_ = off_t[n+1];
    r2e_round(xv, tail, lane, h0, h1, adj_h, ER,                    cvec,      ahw);
    r2e_round(xv, tail, lane, t0_, t1_, adj_t, ER + (size_t)NR*EHD, cvec+NR,   atw);
    r2e_round(xv, tail, lane, h0, h1, adj_h, ER + (size_t)2*NR*EHD, cvec+2*NR, ah1w);
    {
        const float4* aj4 = (const float4*)ajw;
        float4 am = aj4[lane];
        float p = xv[0]*am.x + xv[1]*am.y + xv[2]*am.z + xv[3]*am.w;
        if(tail){
            float4 at = aj4[64+lane];
            p += xv[4]*at.x + xv[5]*at.y + xv[6]*at.z + xv[7]*at.w;
        }
        p = wred_sum(p);
        if(lane == 0) ajv[n] = p;
    }
    ushort4 w0; w0.x=f2us(xv[0]); w0.y=f2us(xv[1]); w0.z=f2us(xv[2]); w0.w=f2us(xv[3]);
    xr4[lane] = w0;
    if(tail){
        ushort4 w1; w1.x=f2us(xv[4]); w1.y=f2us(xv[5]); w1.z=f2us(xv[6]); w1.w=f2us(xv[7]);
        xr4[64+lane] = w1;
    }
}

// ---------- final GAT + fc; lane-parallel softmax + unroll-4 gather ----------
__global__ void k_final(const bf16* __restrict__ x, const float* __restrict__ ajv,
                        const int* __restrict__ off, const int* __restrict__ adjj,
                        const float* __restrict__ aiw, const float* __restrict__ fcw,
                        const float* __restrict__ fcb, float* __restrict__ out){
    int wid = threadIdx.x >> 6, lane = threadIdx.x & 63;
    int n = blockIdx.x*4 + wid;
    if(n >= NN) return;
    bool tail = lane < 11;
    const ushort4* xr4 = (const ushort4*)(x + (size_t)n*EHD);
    const float4* ai4 = (const float4*)aiw;
    ushort4 xv = xr4[lane];
    ushort4 xt = tail ? xr4[64+lane] : ushort4{0,0,0,0};
    float4 am = ai4[lane];
    float4 at = tail ? ai4[64+lane] : float4{0,0,0,0};
    float p = us2f(xv.x)*am.x + us2f(xv.y)*am.y + us2f(xv.z)*am.z + us2f(xv.w)*am.w;
    if(tail) p += us2f(xt.x)*at.x + us2f(xt.y)*at.y + us2f(xt.z)*at.z + us2f(xt.w)*at.w;
    p = wred_sum(p);
    int s0 = off[n], s1 = off[n+1], cnt = s1 - s0;
    float a0=0,a1=0,a2=0,a3=0, t0=0,t1=0,t2=0,t3=0;
    if(cnt > 0 && cnt <= 64){
        int jl = (lane < cnt) ? clampi(adjj[s0+lane], NN) : 0;
        float av = (lane < cnt) ? ajv[jl] : 0.f;
        float lg = p + av;
        lg = lg > 0 ? lg : 0.01f*lg;
        float mx = wred_max((lane < cnt) ? lg : -1e30f);
        float ex = (lane < cnt) ? expf(lg - mx) : 0.f;
        float ss = wred_sum(ex);
        float al = ex/ss;
        int it = 0;
        for(; it+4 <= cnt; it += 4){
            int j0=__shfl(jl,it), j1=__shfl(jl,it+1), j2=__shfl(jl,it+2), j3=__shfl(jl,it+3);
            float q0=__shfl(al,it), q1=__shfl(al,it+1), q2=__shfl(al,it+2), q3=__shfl(al,it+3);
            const ushort4* r0 = (const ushort4*)(x + (size_t)j0*EHD);
            const ushort4* r1 = (const ushort4*)(x + (size_t)j1*EHD);
            const ushort4* r2 = (const ushort4*)(x + (size_t)j2*EHD);
            const ushort4* r3 = (const ushort4*)(x + (size_t)j3*EHD);
            ushort4 v0=r0[lane], v1=r1[lane], v2=r2[lane], v3=r3[lane];
            a0 += q0*us2f(v0.x)+q1*us2f(v1.x)+q2*us2f(v2.x)+q3*us2f(v3.x);
            a1 += q0*us2f(v0.y)+q1*us2f(v1.y)+q2*us2f(v2.y)+q3*us2f(v3.y);
            a2 += q0*us2f(v0.z)+q1*us2f(v1.z)+q2*us2f(v2.z)+q3*us2f(v3.z);
            a3 += q0*us2f(v0.w)+q1*us2f(v1.w)+q2*us2f(v2.w)+q3*us2f(v3.w);
            if(tail){
                ushort4 u0=r0[64+lane], u1=r1[64+lane], u2=r2[64+lane], u3=r3[64+lane];
                t0 += q0*us2f(u0.x)+q1*us2f(u1.x)+q2*us2f(u2.x)+q3*us2f(u3.x);
                t1 += q0*us2f(u0.y)+q1*us2f(u1.y)+q2*us2f(u2.y)+q3*us2f(u3.y);
                t2 += q0*us2f(u0.z)+q1*us2f(u1.z)+q2*us2f(u2.z)+q3*us2f(u3.z);
                t3 += q0*us2f(u0.w)+q1*us2f(u1.w)+q2*us2f(u2.w)+q3*us2f(u3.w);
            }
        }
        for(; it < cnt; it++){
            int j0 = __shfl(jl, it);
            float q0 = __shfl(al, it);
            const ushort4* r0 = (const ushort4*)(x + (size_t)j0*EHD);
            ushort4 v0 = r0[lane];
            a0 += q0*us2f(v0.x); a1 += q0*us2f(v0.y); a2 += q0*us2f(v0.z); a3 += q0*us2f(v0.w);
            if(tail){
                ushort4 u0 = r0[64+lane];
                t0 += q0*us2f(u0.x); t1 += q0*us2f(u0.y); t2 += q0*us2f(u0.z); t3 += q0*us2f(u0.w);
            }
        }
    } else if(cnt > 64){
        float mx = -1e30f;
        for(int it=s0; it<s1; it++){
            float lg = p + ajv[clampi(adjj[it], NN)];
            lg = lg > 0 ? lg : 0.01f*lg;
            mx = fmaxf(mx, lg);
        }
        float ss = 0;
        for(int it=s0; it<s1; it++){
            float lg = p + ajv[clampi(adjj[it], NN)];
            lg = lg > 0 ? lg : 0.01f*lg;
            ss += expf(lg - mx);
        }
        for(int it=s0; it<s1; it++){
            int j = clampi(adjj[it], NN);
            float lg = p + ajv[j];
            lg = lg > 0 ? lg : 0.01f*lg;
            float a = expf(lg - mx)/ss;
            const ushort4* row = (const ushort4*)(x + (size_t)j*EHD);
            ushort4 v = row[lane];
            a0 += a*us2f(v.x); a1 += a*us2f(v.y); a2 += a*us2f(v.z); a3 += a*us2f(v.w);
            if(tail){
                ushort4 u = row[64+lane];
                t0 += a*us2f(u.x); t1 += a*us2f(u.y); t2 += a*us2f(u.z); t3 += a*us2f(u.w);
            }
        }
    }
    const float4* f4 = (const float4*)fcw;
    float4 f0 = f4[lane];
    float4 g0 = f4[75 + lane];
    float part = us2f(xv.x)*f0.x + us2f(xv.y)*f0.y + us2f(xv.z)*f0.z + us2f(xv.w)*f0.w
               + fmaxf(a0,0.f)*g0.x + fmaxf(a1,0.f)*g0.y + fmaxf(a2,0.f)*g0.z + fmaxf(a3,0.f)*g0.w;
    if(tail){
        float4 f1 = f4[64 + lane];
        float4 g1 = f4[139 + lane];
        part += us2f(xt.x)*f1.x + us2f(xt.y)*f1.y + us2f(xt.z)*f1.z + us2f(xt.w)*f1.w
              + fmaxf(t0,0.f)*g1.x + fmaxf(t1,0.f)*g1.y + fmaxf(t2,0.f)*g1.z + fmaxf(t3,0.f)*g1.w;
    }
    part = wred_sum(part);
    if(lane == 0) out[n] = part + fcb[0];
}

extern "C" void kernel_launch(void* const* d_in, const int* in_sizes, int n_in,
                              void* d_out, int out_size, void* d_ws, size_t ws_size,
                              hipStream_t stream){
    const float* x_in = (const float*)d_in[0];
    const int*  ht   = (const int*)d_in[1];
    const int*  rel  = (const int*)d_in[2];
    const int*  ji   = (const int*)d_in[3];
    const float* hw1w=(const float*)d_in[5];  const float* hw1b=(const float*)d_in[6];
    const float* hw2w=(const float*)d_in[7];  const float* hw2b=(const float*)d_in[8];
    const float* tc1w=(const float*)d_in[9];  const float* tc1b=(const float*)d_in[10];
    const float* sr1w=(const float*)d_in[11]; const float* sr1b=(const float*)d_in[12];
    const float* wrw =(const float*)d_in[15]; const float* wrb =(const float*)d_in[16];
    const float* wr1w=(const float*)d_in[17]; const float* wr1b=(const float*)d_in[18];
    const float* wr2w=(const float*)d_in[19]; const float* wr2b=(const float*)d_in[20];
    const float* ahw =(const float*)d_in[21]; const float* ah1w=(const float*)d_in[22];
    const float* atw =(const float*)d_in[23];
    const float* ar1 =(const float*)d_in[24]; const float* ar2 =(const float*)d_in[25];
    const float* ar3 =(const float*)d_in[26];
    const float* aiw =(const float*)d_in[27]; const float* ajw =(const float*)d_in[28];
    const float* fcw =(const float*)d_in[29]; const float* fcb =(const float*)d_in[30];
    float* out = (float*)d_out;

    char* w = (char*)d_ws;
    auto alloc = [&](size_t bytes)->char*{ char* p = w; w += (bytes + 255)/256*256; return p; };
    bf16* xF = (bf16*)alloc((size_t)NN*EHD*2);   // 30 MB
    bf16* B  = (bf16*)alloc((size_t)NN*EHD*2);   // 30 MB; CSR tmp -> gcn agg/x1 -> rel tables
    char* Bc = (char*)B;
    // CSR-build tmp arrays (dead before k_gcn first touches B)
    int2* tmp_all = (int2*)(Bc);                      // 4 MB
    int2* tmp_h   = (int2*)(Bc + 4u*1024*1024);       // 2 MB
    int2* tmp_t   = (int2*)(Bc + 8u*1024*1024);       // 2 MB
    int2* tmp_r   = (int2*)(Bc + 12u*1024*1024);      // 2 MB
    // rel-phase aliases (alive after highway2)
    bf16*  sbuf = (bf16*)(Bc);                        // 10 MB
    float* RF   = (float*)(Bc + 11u*1024*1024);
    float* ER   = (float*)(Bc + 12u*1024*1024);
    float* cvec = (float*)(Bc + 14u*1024*1024);
    float* ajv  = (float*)(Bc + 15u*1024*1024);
    short* Wt1 = (short*)alloc((size_t)EHD*EHD*2);
    short* Wt2 = (short*)alloc((size_t)EHD*EHD*2);
    short* Wtc = (short*)alloc((size_t)EHD*THD*2);
    float* dinv = (float*)alloc((size_t)NN*4);
    int* degs   = (int*)alloc((size_t)(3*NN + NR)*4);
    int* deg_all = degs, *deg_h = degs + NN, *deg_t = degs + 2*NN, *cnt_rel = degs + 3*NN;
    int* off_all=(int*)alloc((NN+1)*4);
    int* adj_all=(int*)alloc((size_t)NEA*4);
    int* off_h  =(int*)alloc((NN+1)*4);
    int* adj_h  =(int*)alloc((size_t)NE*4);
    int* off_t  =(int*)alloc((NN+1)*4);
    int* adj_t  =(int*)alloc((size_t)NE*4);
    int* off_r  =(int*)alloc((NR+1)*4);
    int* adj_r  =(int*)alloc((size_t)NE*4);
    int* gcur   =(int*)alloc(4*128*4);
    int* gc_all = gcur, *gc_h = gcur+128, *gc_t = gcur+256, *gc_r = gcur+384;

    // prep (zero degs + cast x + transpose weights) — one launch
    const int NPREP = NN*EHD/4;   // dominates
    k_prep<<<dim3((NPREP+255)/256), dim3(256), 0, stream>>>((const float4*)x_in, (ushort*)xF,
                                                            hw1w, hw2w, tc1w, Wt1, Wt2, Wtc, degs);
    k_count<<<dim3((NEA+255)/256), dim3(256), 0, stream>>>(ji, ht, rel, deg_all, deg_h, deg_t, cnt_rel);
    k_scan<<<dim3(4), dim3(1024), 0, stream>>>(deg_all, off_all, deg_h, off_h, deg_t, off_t, cnt_rel, off_r,
                                               gc_all, gc_h, gc_t, gc_r, dinv);
    k_bin<<<dim3((NEA+2047)/2048, 4), dim3(256), 0, stream>>>(ji, ht, rel, gc_all, gc_h, gc_t, gc_r,
                                                              tmp_all, tmp_h, tmp_t, tmp_r);
    k_place<<<dim3(NBN, 4), dim3(256), 0, stream>>>(off_all, off_h, off_t, off_r,
                                                    tmp_all, tmp_h, tmp_t, tmp_r,
                                                    adj_all, adj_h, adj_t, adj_r);

    const int nb4 = (NN+3)/4;
    const dim3 gg((NN+63)/64, (EHD+63)/64);
    // highway 1: B = gcn(xF); B = sig(xF@hw1+b)*B + (1-sig)*xF
    k_gcn<<<dim3(nb4), dim3(256), 0, stream>>>(xF, B, off_all, adj_all, dinv);
    k_gemm_mfma<1><<<gg, dim3(256), 0, stream>>>(xF, Wt1, hw1b, B, xF, NN, EHD, EHD);
    // highway 2
    k_gcn<<<dim3(nb4), dim3(256), 0, stream>>>(B, xF, off_all, adj_all, dinv);
    k_gemm_mfma<1><<<gg, dim3(256), 0, stream>>>(B, Wt2, hw2b, xF, B, NN, EHD, EHD);
    // rel tables
    k_gemm_mfma<0><<<dim3((NN+63)/64, (THD+63)/64), dim3(256), 0, stream>>>(xF, Wtc, tc1b, sbuf, xF, NN, EHD, THD);
    k_zero_f32<<<dim3((NR*EHD+255)/256), dim3(256), 0, stream>>>(RF, NR*EHD);
    k_relsum2<<<dim3(NR, RCH), dim3(128), 0, stream>>>(sbuf, ht, off_r, adj_r, RF);
    k_relfin<<<dim3(NR), dim3(128), 0, stream>>>(sr1w, sr1b, off_r, RF);
    k_reler<<<dim3(NR, 3), dim3(256), 0, stream>>>(RF, wrw, wrb, wr1w, wr1b, wr2w, wr2b,
                                                   ar1, ar2, ar3, ER, cvec);
    // fused three r2e rounds + ajv
    k_r2e3<<<dim3(nb4), dim3(256), 0, stream>>>(xF, off_h, adj_h, off_t, adj_t, ER, cvec,
                                                ahw, atw, ah1w, ajw, ajv);
    // final GAT + fc
    k_final<<<dim3(nb4), dim3(256), 0, stream>>>(xF, ajv, off_all, adj_all, aiw, fcw, fcb, out);
}

// Round 9
// 734.286 us; speedup vs baseline: 2.4037x; 1.3239x over previous
//
#include <hip/hip_runtime.h>
#include <hip/hip_bf16.h>

typedef __hip_bfloat16 bf16;
typedef __attribute__((ext_vector_type(8))) short bf16x8_t;
typedef __attribute__((ext_vector_type(4))) float f32x4_t;

__device__ __forceinline__ float b2f(bf16 v){ return __bfloat162float(v); }
__device__ __forceinline__ bf16 f2b(float v){ return __float2bfloat16(v); }
__device__ __forceinline__ short tobits(float v){ bf16 b = f2b(v); return *(short*)&b; }
__device__ __forceinline__ float us2f(ushort u){ return __uint_as_float(((unsigned)u)<<16); }
__device__ __forceinline__ ushort f2us(float v){ bf16 b = f2b(v); return *(ushort*)&b; }

#define NN 50000
#define NE 250000
#define NEA 500000
#define NR 300
#define EHD 300
#define THD 100
#define RHD 100
#define RCH 8
#define NBN 98      // node buckets (512 wide)
#define NBR 75      // rel buckets (4 wide)

__device__ __forceinline__ int clampi(int v, int n){ return ((unsigned)v < (unsigned)n) ? v : 0; }

__device__ __forceinline__ float wred_sum(float p){
    #pragma unroll
    for(int m=32;m>=1;m>>=1) p += __shfl_xor(p, m);
    return p;
}
__device__ __forceinline__ float wred_max(float p){
    #pragma unroll
    for(int m=32;m>=1;m>>=1) p = fmaxf(p, __shfl_xor(p, m));
    return p;
}

__global__ void k_zero_f32(float* __restrict__ p, int n){
    int i = blockIdx.x*256 + threadIdx.x;
    if(i < n) p[i] = 0.f;
}

// ---------- fused prep: zero bcnt | bf16 cast of x | 3 weight transposes ----------
__global__ void k_prep(const float4* __restrict__ xin4, ushort* __restrict__ xFu,
                       const float* __restrict__ hw1w, const float* __restrict__ hw2w,
                       const float* __restrict__ tc1w,
                       short* __restrict__ Wt1, short* __restrict__ Wt2, short* __restrict__ Wtc,
                       int* __restrict__ bcnt){
    int i = blockIdx.x*256 + threadIdx.x;
    if(i < 512) bcnt[i] = 0;
    const int N4 = NN*EHD/4;
    if(i < N4){
        float4 v = xin4[i];
        ushort4 o;
        o.x = (ushort)tobits(v.x); o.y = (ushort)tobits(v.y);
        o.z = (ushort)tobits(v.z); o.w = (ushort)tobits(v.w);
        *(ushort4*)(xFu + 4*(size_t)i) = o;
    }
    const int S1 = EHD*EHD, S2 = 2*EHD*EHD, S3 = 2*EHD*EHD + EHD*THD;
    if(i < S1){
        int n = i/EHD, k = i - n*EHD;
        Wt1[i] = tobits(hw1w[(size_t)k*EHD + n]);
    } else if(i < S2){
        int ii = i - S1; int n = ii/EHD, k = ii - n*EHD;
        Wt2[ii] = tobits(hw2w[(size_t)k*EHD + n]);
    } else if(i < S3){
        int ii = i - S2; int n = ii/EHD, k = ii - n*EHD;
        Wtc[ii] = tobits(tc1w[(size_t)k*THD + n]);
    }
}

// ---------- bucket counting via LDS histogram (replaces random-scatter k_count) ----------
__global__ __launch_bounds__(256) void k_bincnt(const int* __restrict__ ji, const int* __restrict__ ht,
                         const int* __restrict__ rel, int* __restrict__ bcnt){
    int s = blockIdx.y;
    int n_s = (s == 0) ? NEA : NE;
    int base_e = blockIdx.x*2048;
    if(base_e >= n_s) return;
    int shift = (s < 3) ? 9 : 2;
    int tid = threadIdx.x;
    __shared__ int h[128];
    if(tid < 128) h[tid] = 0;
    __syncthreads();
    #pragma unroll
    for(int u=0;u<8;u++){
        int e = base_e + u*256 + tid;
        if(e < n_s){
            int key;
            if(s == 0) key = clampi(ji[NEA + e], NN);
            else if(s == 1) key = clampi(ht[e], NN);
            else if(s == 2) key = clampi(ht[NE + e], NN);
            else key = clampi(rel[e], NR);
            atomicAdd(&h[key >> shift], 1);
        }
    }
    __syncthreads();
    if(tid < 128 && h[tid] > 0) atomicAdd(&bcnt[s*128 + tid], h[tid]);
}

// ---------- segmented scan of bucket counts -> gbase[4][129], gcur[4][128] ----------
__global__ void k_bscan(const int* __restrict__ bcnt, int* __restrict__ gbase, int* __restrict__ gcur){
    __shared__ int lds[512];
    int tid = threadIdx.x;   // 512
    int v = bcnt[tid];
    lds[tid] = v; __syncthreads();
    for(int st=1; st<128; st<<=1){
        int add = ((tid & 127) >= st) ? lds[tid-st] : 0;
        __syncthreads();
        lds[tid] += add;
        __syncthreads();
    }
    int s = tid >> 7, b = tid & 127;
    int excl = lds[tid] - v;
    gbase[s*129 + b] = excl;
    gcur[s*128 + b] = excl;
    if(b == 127) gbase[s*129 + 128] = lds[tid];
}

// ---------- Phase C: LDS-staged binning into bucket-ordered tmp (int2 = key,payload) ----------
__global__ __launch_bounds__(256) void k_bin(const int* __restrict__ ji, const int* __restrict__ ht,
                      const int* __restrict__ rel, int* __restrict__ gcur,
                      int2* __restrict__ t0, int2* __restrict__ t1,
                      int2* __restrict__ t2, int2* __restrict__ t3){
    int s = blockIdx.y;
    int n_s = (s == 0) ? NEA : NE;
    int base_e = blockIdx.x*2048;
    if(base_e >= n_s) return;
    int shift = (s < 3) ? 9 : 2;
    int tid = threadIdx.x;
    __shared__ int cnt[128], lof[128], base[128];
    __shared__ int2 buf[2048];
    if(tid < 128) cnt[tid] = 0;
    __syncthreads();
    int kk[8], pp[8], bb[8], ss[8];
    #pragma unroll
    for(int u=0;u<8;u++){
        int e = base_e + u*256 + tid;
        bb[u] = -1;
        if(e < n_s){
            int key, pay;
            if(s == 0){ key = clampi(ji[NEA + e], NN); pay = clampi(ji[e], NN); }
            else if(s == 1){ key = clampi(ht[e], NN); pay = clampi(rel[e], NR); }
            else if(s == 2){ key = clampi(ht[NE + e], NN); pay = clampi(rel[e], NR); }
            else { key = clampi(rel[e], NR); pay = e; }
            int b = key >> shift;
            kk[u] = key; pp[u] = pay; bb[u] = b;
            ss[u] = atomicAdd(&cnt[b], 1);
        }
    }
    __syncthreads();
    if(tid == 0){
        int run = 0;
        for(int b=0;b<128;b++){ lof[b] = run; run += cnt[b]; }
    }
    __syncthreads();
    #pragma unroll
    for(int u=0;u<8;u++){
        if(bb[u] >= 0){
            int pos = lof[bb[u]] + ss[u];
            buf[pos] = make_int2(kk[u], pp[u]);
        }
    }
    __syncthreads();
    if(tid < 128 && cnt[tid] > 0) base[tid] = atomicAdd(&gcur[s*128 + tid], cnt[tid]);
    __syncthreads();
    int2* tmp = (s==0) ? t0 : (s==1) ? t1 : (s==2) ? t2 : t3;
    int total = lof[127] + cnt[127];
    for(int idx=tid; idx<total; idx+=256){
        int2 kp = buf[idx];
        int b = kp.x >> shift;
        tmp[base[b] + (idx - lof[b])] = kp;
    }
}

// ---------- Phase D: windowed CSR fill; derives off[] + dinv from binned data ----------
__global__ __launch_bounds__(256) void k_place(const int* __restrict__ gbase,
                        const int2* __restrict__ t0, const int2* __restrict__ t1,
                        const int2* __restrict__ t2, const int2* __restrict__ t3,
                        int* __restrict__ off_all, int* __restrict__ off_h,
                        int* __restrict__ off_t, int* __restrict__ off_r,
                        int* __restrict__ adj_all, int* __restrict__ adj_h,
                        int* __restrict__ adj_t, int* __restrict__ adj_r,
                        float* __restrict__ dinv){
    int s = blockIdx.y, b = blockIdx.x;
    int NB = (s < 3) ? NBN : NBR;
    if(b >= NB) return;
    int W = (s < 3) ? 512 : 4;
    int len = (s < 3) ? NN : NR;
    const int2* tmp = (s==0) ? t0 : (s==1) ? t1 : (s==2) ? t2 : t3;
    int* off = (s==0) ? off_all : (s==1) ? off_h : (s==2) ? off_t : off_r;
    int* adj = (s==0) ? adj_all : (s==1) ? adj_h : (s==2) ? adj_t : adj_r;
    int node0 = b*W;
    int node1 = node0 + W; if(node1 > len) node1 = len;
    int nloc = node1 - node0;
    int wstart = gbase[s*129 + b], wend = gbase[s*129 + b + 1];
    __shared__ int hist[512];
    __shared__ int cur[512];
    __shared__ int sb[256];
    int tid = threadIdx.x;
    for(int k=tid; k<nloc; k+=256) hist[k] = 0;
    __syncthreads();
    for(int idx = wstart + tid; idx < wend; idx += 256){
        int local = tmp[idx].x - node0;
        if((unsigned)local < (unsigned)nloc) atomicAdd(&hist[local], 1);
    }
    __syncthreads();
    // 512-wide exclusive scan (each thread owns 2 slots)
    int v0 = (2*tid   < nloc) ? hist[2*tid]   : 0;
    int v1 = (2*tid+1 < nloc) ? hist[2*tid+1] : 0;
    int ps = v0 + v1;
    sb[tid] = ps; __syncthreads();
    for(int st=1; st<256; st<<=1){
        int add = (tid >= st) ? sb[tid-st] : 0;
        __syncthreads();
        sb[tid] += add;
        __syncthreads();
    }
    int excl = sb[tid] - ps;
    if(2*tid < nloc){
        int o = wstart + excl;
        off[node0 + 2*tid] = o;
        cur[2*tid] = o;
        if(s == 0) dinv[node0 + 2*tid] = v0 > 0 ? rsqrtf((float)v0) : 0.f;
    }
    if(2*tid+1 < nloc){
        int o = wstart + excl + v0;
        off[node0 + 2*tid+1] = o;
        cur[2*tid+1] = o;
        if(s == 0) dinv[node0 + 2*tid+1] = v1 > 0 ? rsqrtf((float)v1) : 0.f;
    }
    if(b == NB-1 && tid == 0) off[len] = gbase[s*129 + 128];
    __syncthreads();
    for(int idx = wstart + tid; idx < wend; idx += 256){
        int2 kp = tmp[idx];
        int local = kp.x - node0;
        if((unsigned)local < (unsigned)nloc){
            int slot = atomicAdd(&cur[local], 1);
            adj[slot] = kp.y;
        }
    }
}

// ---------- GCN gather: wave per node, unroll-4 ----------
__global__ void k_gcn(const bf16* __restrict__ xs, bf16* __restrict__ xd,
                      const int* __restrict__ off, const int* __restrict__ adjj,
                      const float* __restrict__ dinv){
    int wid = threadIdx.x >> 6, lane = threadIdx.x & 63;
    int n = blockIdx.x*4 + wid;
    if(n >= NN) return;
    float di = dinv[n];
    int s0 = off[n], s1 = off[n+1], cnt = s1 - s0;
    bool tail = lane < 11;
    float a0=0,a1=0,a2=0,a3=0, t0=0,t1=0,t2=0,t3=0;
    if(cnt > 0 && cnt <= 64){
        int jl = (lane < cnt) ? clampi(adjj[s0+lane], NN) : 0;
        float dl = (lane < cnt) ? dinv[jl] : 0.f;
        int it = 0;
        for(; it+4 <= cnt; it += 4){
            int j0=__shfl(jl,it), j1=__shfl(jl,it+1), j2=__shfl(jl,it+2), j3=__shfl(jl,it+3);
            float n0=di*__shfl(dl,it), n1=di*__shfl(dl,it+1), n2=di*__shfl(dl,it+2), n3=di*__shfl(dl,it+3);
            const ushort4* r0 = (const ushort4*)(xs + (size_t)j0*EHD);
            const ushort4* r1 = (const ushort4*)(xs + (size_t)j1*EHD);
            const ushort4* r2 = (const ushort4*)(xs + (size_t)j2*EHD);
            const ushort4* r3 = (const ushort4*)(xs + (size_t)j3*EHD);
            ushort4 v0=r0[lane], v1=r1[lane], v2=r2[lane], v3=r3[lane];
            a0 += n0*us2f(v0.x)+n1*us2f(v1.x)+n2*us2f(v2.x)+n3*us2f(v3.x);
            a1 += n0*us2f(v0.y)+n1*us2f(v1.y)+n2*us2f(v2.y)+n3*us2f(v3.y);
            a2 += n0*us2f(v0.z)+n1*us2f(v1.z)+n2*us2f(v2.z)+n3*us2f(v3.z);
            a3 += n0*us2f(v0.w)+n1*us2f(v1.w)+n2*us2f(v2.w)+n3*us2f(v3.w);
            if(tail){
                ushort4 u0=r0[64+lane], u1=r1[64+lane], u2=r2[64+lane], u3=r3[64+lane];
                t0 += n0*us2f(u0.x)+n1*us2f(u1.x)+n2*us2f(u2.x)+n3*us2f(u3.x);
                t1 += n0*us2f(u0.y)+n1*us2f(u1.y)+n2*us2f(u2.y)+n3*us2f(u3.y);
                t2 += n0*us2f(u0.z)+n1*us2f(u1.z)+n2*us2f(u2.z)+n3*us2f(u3.z);
                t3 += n0*us2f(u0.w)+n1*us2f(u1.w)+n2*us2f(u2.w)+n3*us2f(u3.w);
            }
        }
        for(; it < cnt; it++){
            int j0 = __shfl(jl, it);
            float n0 = di*__shfl(dl, it);
            const ushort4* r0 = (const ushort4*)(xs + (size_t)j0*EHD);
            ushort4 v0 = r0[lane];
            a0 += n0*us2f(v0.x); a1 += n0*us2f(v0.y); a2 += n0*us2f(v0.z); a3 += n0*us2f(v0.w);
            if(tail){
                ushort4 u0 = r0[64+lane];
                t0 += n0*us2f(u0.x); t1 += n0*us2f(u0.y); t2 += n0*us2f(u0.z); t3 += n0*us2f(u0.w);
            }
        }
    } else if(cnt > 64){
        for(int it=s0; it<s1; it++){
            int j = clampi(adjj[it], NN);
            float nr = di * dinv[j];
            const ushort4* row = (const ushort4*)(xs + (size_t)j*EHD);
            ushort4 v = row[lane];
            a0 += nr*us2f(v.x); a1 += nr*us2f(v.y); a2 += nr*us2f(v.z); a3 += nr*us2f(v.w);
            if(tail){
                ushort4 u = row[64+lane];
                t0 += nr*us2f(u.x); t1 += nr*us2f(u.y); t2 += nr*us2f(u.z); t3 += nr*us2f(u.w);
            }
        }
    }
    ushort4* o = (ushort4*)(xd + (size_t)n*EHD);
    ushort4 w0; w0.x=f2us(fmaxf(a0,0.f)); w0.y=f2us(fmaxf(a1,0.f)); w0.z=f2us(fmaxf(a2,0.f)); w0.w=f2us(fmaxf(a3,0.f));
    o[lane] = w0;
    if(tail){
        ushort4 w1; w1.x=f2us(fmaxf(t0,0.f)); w1.y=f2us(fmaxf(t1,0.f)); w1.z=f2us(fmaxf(t2,0.f)); w1.w=f2us(fmaxf(t3,0.f));
        o[64+lane] = w1;
    }
}

// ---------- MFMA GEMM ----------
template<int MODE>
__global__ __launch_bounds__(256) void k_gemm_mfma(const bf16* __restrict__ X,
                       const short* __restrict__ Wt, const float* __restrict__ bias,
                       bf16* __restrict__ out, const bf16* __restrict__ Xprev,
                       int M, int K, int Ncols){
    __shared__ short As[64][40];
    __shared__ short Bs[64][40];
    int tid = threadIdx.x;
    int bm = blockIdx.x*64, bn = blockIdx.y*64;
    int wid = tid>>6, lane = tid&63;
    int wm = (wid&1)*32, wn = (wid>>1)*32;
    int lm = lane&15, lq = lane>>4;
    f32x4_t acc00={0,0,0,0}, acc01={0,0,0,0}, acc10={0,0,0,0}, acc11={0,0,0,0};
    int mrow = tid>>2, kc = (tid&3)*8;
    union U8 { bf16x8_t v; uint2 u[2]; short s[8]; };
    for(int k0=0; k0<K; k0+=32){
        int gk0 = k0 + kc;
        {
            int gm = bm + mrow;
            U8 a;
            if(gm < M && gk0 + 8 <= K){
                const uint2* src = (const uint2*)(X + (size_t)gm*K + gk0);
                a.u[0] = src[0]; a.u[1] = src[1];
            } else {
                #pragma unroll
                for(int j=0;j<8;j++){
                    int gk = gk0 + j;
                    a.s[j] = (gm < M && gk < K) ? (short)*(const short*)(X + (size_t)gm*K + gk) : (short)0;
                }
                if(gm >= M){ a.u[0] = {0,0}; a.u[1] = {0,0}; }
            }
            *(bf16x8_t*)&As[mrow][kc] = a.v;
        }
        {
            int gn = bn + mrow;
            U8 b;
            if(gn < Ncols && gk0 + 8 <= K){
                const uint2* src = (const uint2*)(Wt + (size_t)gn*K + gk0);
                b.u[0] = src[0]; b.u[1] = src[1];
            } else {
                #pragma unroll
                for(int j=0;j<8;j++){
                    int gk = gk0 + j;
                    b.s[j] = (gn < Ncols && gk < K) ? Wt[(size_t)gn*K + gk] : (short)0;
                }
                if(gn >= Ncols){ b.u[0] = {0,0}; b.u[1] = {0,0}; }
            }
            *(bf16x8_t*)&Bs[mrow][kc] = b.v;
        }
        __syncthreads();
        bf16x8_t a0 = *(bf16x8_t*)&As[wm + lm][lq*8];
        bf16x8_t a1 = *(bf16x8_t*)&As[wm + 16 + lm][lq*8];
        bf16x8_t b0 = *(bf16x8_t*)&Bs[wn + lm][lq*8];
        bf16x8_t b1 = *(bf16x8_t*)&Bs[wn + 16 + lm][lq*8];
        acc00 = __builtin_amdgcn_mfma_f32_16x16x32_bf16(a0, b0, acc00, 0, 0, 0);
        acc01 = __builtin_amdgcn_mfma_f32_16x16x32_bf16(a0, b1, acc01, 0, 0, 0);
        acc10 = __builtin_amdgcn_mfma_f32_16x16x32_bf16(a1, b0, acc10, 0, 0, 0);
        acc11 = __builtin_amdgcn_mfma_f32_16x16x32_bf16(a1, b1, acc11, 0, 0, 0);
        __syncthreads();
    }
    #pragma unroll
    for(int tm=0;tm<2;tm++){
        #pragma unroll
        for(int tn=0;tn<2;tn++){
            f32x4_t a = tm==0 ? (tn==0 ? acc00 : acc01) : (tn==0 ? acc10 : acc11);
            int gn = bn + wn + tn*16 + lm;
            if(gn >= Ncols) continue;
            float bi = bias[gn];
            #pragma unroll
            for(int r=0;r<4;r++){
                int gm = bm + wm + tm*16 + lq*4 + r;
                if(gm >= M) continue;
                float t = a[r] + bi;
                size_t p = (size_t)gm*Ncols + gn;
                if(MODE == 0){
                    out[p] = f2b(t);
                } else {
                    float g = 1.f/(1.f + expf(-t));
                    out[p] = f2b(g*b2f(out[p]) + (1.f - g)*b2f(Xprev[p]));
                }
            }
        }
    }
}

// ---------- chunked per-relation sums into RF[r][100..299] ----------
__global__ void k_relsum2(const bf16* __restrict__ s, const int* __restrict__ ht,
                          const int* __restrict__ off_r, const int* __restrict__ adj_r,
                          float* __restrict__ RF){
    int r = blockIdx.x, c = blockIdx.y, d = threadIdx.x;
    int s0 = off_r[r], s1 = off_r[r+1];
    int cnt = s1 - s0;
    if(cnt <= 0) return;
    int per = (cnt + RCH - 1)/RCH;
    int lo = s0 + c*per, hi = lo + per; if(hi > s1) hi = s1;
    if(lo >= hi) return;
    if(d >= THD) return;
    float ah = 0.f, at2 = 0.f;
    for(int it=lo; it<hi; it++){
        int e = clampi(adj_r[it], NE);
        int hh = clampi(ht[e], NN), tt = clampi(ht[NE + e], NN);
        ah  += b2f(s[(size_t)hh*THD + d]);
        at2 += b2f(s[(size_t)tt*THD + d]);
    }
    atomicAdd(&RF[(size_t)r*EHD + THD   + d], ah);
    atomicAdd(&RF[(size_t)r*EHD + 2*THD + d], at2);
}

// ---------- normalize means + x_type ----------
__global__ void k_relfin(const float* __restrict__ sr1w, const float* __restrict__ sr1b,
                         const int* __restrict__ off_r, float* __restrict__ RF){
    int r = blockIdx.x, d = threadIdx.x;
    int cnt = off_r[r+1] - off_r[r];
    float inv = 1.f/(float)(cnt > 1 ? cnt : 1);
    if(d < THD){
        RF[(size_t)r*EHD + THD   + d] *= inv;
        RF[(size_t)r*EHD + 2*THD + d] *= inv;
    }
    __syncthreads();
    if(d < RHD){
        float v = 0.f;
        if(cnt > 0){
            v = sr1b[d];
            for(int k2=0; k2<2*THD; k2++) v += RF[(size_t)r*EHD + THD + k2] * sr1w[k2*RHD + d];
        }
        RF[(size_t)r*EHD + d] = v;
    }
}

// ---------- ER + cvec fused ----------
__global__ void k_reler(const float* __restrict__ RF,
                        const float* w0, const float* b0, const float* w1, const float* b1,
                        const float* w2, const float* b2,
                        const float* ar1, const float* ar2, const float* ar3,
                        float* __restrict__ ER, float* __restrict__ cvec){
    int r = blockIdx.x, kk = blockIdx.y;
    const float* w = kk==0 ? w0 : (kk==1 ? w1 : w2);
    const float* b = kk==0 ? b0 : (kk==1 ? b1 : b2);
    const float* a = kk==0 ? ar1 : (kk==1 ? ar2 : ar3);
    int tid = threadIdx.x;
    float pd = 0.f;
    for(int o = tid; o < EHD; o += 256){
        float v = b[o];
        for(int d=0; d<EHD; d++) v += RF[(size_t)r*EHD + d] * w[(size_t)d*EHD + o];
        ER[((size_t)kk*NR + r)*EHD + o] = v;
        pd += v * a[o];
    }
    __shared__ float red[4];
    pd = wred_sum(pd);
    if((tid & 63) == 0) red[tid>>6] = pd;
    __syncthreads();
    if(tid == 0) cvec[kk*NR + r] = red[0]+red[1]+red[2]+red[3];
}

// ---------- one r2e round on a register-resident x row ----------
__device__ __forceinline__ void r2e_round(float* xv, bool tail, int lane, int s0, int s1,
        const int* __restrict__ adjrel, const float* __restrict__ ERk,
        const float* __restrict__ ck, const float* __restrict__ anode){
    const float4* an4 = (const float4*)anode;
    float4 am = an4[lane];
    float p = xv[0]*am.x + xv[1]*am.y + xv[2]*am.z + xv[3]*am.w;
    if(tail){
        float4 at = an4[64+lane];
        p += xv[4]*at.x + xv[5]*at.y + xv[6]*at.z + xv[7]*at.w;
    }
    p = wred_sum(p);
    int cnt = s1 - s0;
    if(cnt <= 0) return;
    float a0=0,a1=0,a2=0,a3=0, t0=0,t1=0,t2=0,t3=0;
    if(cnt <= 64){
        int rl = (lane < cnt) ? clampi(adjrel[s0+lane], NR) : 0;
        float lg = p + ck[rl];
        lg = lg > 0 ? lg : 0.01f*lg;
        float mx = wred_max((lane < cnt) ? lg : -1e30f);
        float ex = (lane < cnt) ? expf(lg - mx) : 0.f;
        float ss = wred_sum(ex);
        float al = ex/ss;
        int it = 0;
        for(; it+2 <= cnt; it += 2){
            int r0i = __shfl(rl, it), r1i = __shfl(rl, it+1);
            float q0 = __shfl(al, it), q1 = __shfl(al, it+1);
            const float4* e0p = (const float4*)(ERk + (size_t)r0i*EHD);
            const float4* e1p = (const float4*)(ERk + (size_t)r1i*EHD);
            float4 e0 = e0p[lane], e1 = e1p[lane];
            a0 += q0*e0.x + q1*e1.x; a1 += q0*e0.y + q1*e1.y;
            a2 += q0*e0.z + q1*e1.z; a3 += q0*e0.w + q1*e1.w;
            if(tail){
                float4 f0 = e0p[64+lane], f1 = e1p[64+lane];
                t0 += q0*f0.x + q1*f1.x; t1 += q0*f0.y + q1*f1.y;
                t2 += q0*f0.z + q1*f1.z; t3 += q0*f0.w + q1*f1.w;
            }
        }
        if(it < cnt){
            int r0i = __shfl(rl, it);
            float q0 = __shfl(al, it);
            const float4* e0p = (const float4*)(ERk + (size_t)r0i*EHD);
            float4 e0 = e0p[lane];
            a0 += q0*e0.x; a1 += q0*e0.y; a2 += q0*e0.z; a3 += q0*e0.w;
            if(tail){
                float4 f0 = e0p[64+lane];
                t0 += q0*f0.x; t1 += q0*f0.y; t2 += q0*f0.z; t3 += q0*f0.w;
            }
        }
    } else {
        float mx = -1e30f;
        for(int it=s0; it<s1; it++){
            float lg = p + ck[clampi(adjrel[it], NR)];
            lg = lg > 0 ? lg : 0.01f*lg;
            mx = fmaxf(mx, lg);
        }
        float ss = 0;
        for(int it=s0; it<s1; it++){
            float lg = p + ck[clampi(adjrel[it], NR)];
            lg = lg > 0 ? lg : 0.01f*lg;
            ss += expf(lg - mx);
        }
        for(int it=s0; it<s1; it++){
            int r = clampi(adjrel[it], NR);
            float lg = p + ck[r];
            lg = lg > 0 ? lg : 0.01f*lg;
            float a = expf(lg - mx)/ss;
            const float4* er4 = (const float4*)(ERk + (size_t)r*EHD);
            float4 e0 = er4[lane];
            a0 += a*e0.x; a1 += a*e0.y; a2 += a*e0.z; a3 += a*e0.w;
            if(tail){
                float4 e1 = er4[64+lane];
                t0 += a*e1.x; t1 += a*e1.y; t2 += a*e1.z; t3 += a*e1.w;
            }
        }
    }
    xv[0] += fmaxf(a0,0.f); xv[1] += fmaxf(a1,0.f); xv[2] += fmaxf(a2,0.f); xv[3] += fmaxf(a3,0.f);
    if(tail){
        xv[4] += fmaxf(t0,0.f); xv[5] += fmaxf(t1,0.f); xv[6] += fmaxf(t2,0.f); xv[7] += fmaxf(t3,0.f);
    }
}

// ---------- fused: three r2e rounds + ajv ----------
__global__ void k_r2e3(bf16* __restrict__ x,
                       const int* __restrict__ off_h, const int* __restrict__ adj_h,
                       const int* __restrict__ off_t, const int* __restrict__ adj_t,
                       const float* __restrict__ ER, const float* __restrict__ cvec,
                       const float* __restrict__ ahw, const float* __restrict__ atw,
                       const float* __restrict__ ah1w, const float* __restrict__ ajw,
                       float* __restrict__ ajv){
    int wid = threadIdx.x >> 6, lane = threadIdx.x & 63;
    int n = blockIdx.x*4 + wid;
    if(n >= NN) return;
    bool tail = lane < 11;
    ushort4* xr4 = (ushort4*)(x + (size_t)n*EHD);
    float xv[8];
    {
        ushort4 v = xr4[lane];
        xv[0]=us2f(v.x); xv[1]=us2f(v.y); xv[2]=us2f(v.z); xv[3]=us2f(v.w);
        if(tail){
            ushort4 u = xr4[64+lane];
            xv[4]=us2f(u.x); xv[5]=us2f(u.y); xv[6]=us2f(u.z); xv[7]=us2f(u.w);
        } else { xv[4]=0; xv[5]=0; xv[6]=0; xv[7]=0; }
    }
    int h0 = off_h[n], h1 = off_h[n+1];
    int t0_ = off_t[n], t1_ = off_t[n+1];
    r2e_round(xv, tail, lane, h0, h1, adj_h, ER,                    cvec,      ahw);
    r2e_round(xv, tail, lane, t0_, t1_, adj_t, ER + (size_t)NR*EHD, cvec+NR,   atw);
    r2e_round(xv, tail, lane, h0, h1, adj_h, ER + (size_t)2*NR*EHD, cvec+2*NR, ah1w);
    {
        const float4* aj4 = (const float4*)ajw;
        float4 am = aj4[lane];
        float p = xv[0]*am.x + xv[1]*am.y + xv[2]*am.z + xv[3]*am.w;
        if(tail){
            float4 at = aj4[64+lane];
            p += xv[4]*at.x + xv[5]*at.y + xv[6]*at.z + xv[7]*at.w;
        }
        p = wred_sum(p);
        if(lane == 0) ajv[n] = p;
    }
    ushort4 w0; w0.x=f2us(xv[0]); w0.y=f2us(xv[1]); w0.z=f2us(xv[2]); w0.w=f2us(xv[3]);
    xr4[lane] = w0;
    if(tail){
        ushort4 w1; w1.x=f2us(xv[4]); w1.y=f2us(xv[5]); w1.z=f2us(xv[6]); w1.w=f2us(xv[7]);
        xr4[64+lane] = w1;
    }
}

// ---------- final GAT + fc; lane-parallel softmax + unroll-4 gather ----------
__global__ void k_final(const bf16* __restrict__ x, const float* __restrict__ ajv,
                        const int* __restrict__ off, const int* __restrict__ adjj,
                        const float* __restrict__ aiw, const float* __restrict__ fcw,
                        const float* __restrict__ fcb, float* __restrict__ out){
    int wid = threadIdx.x >> 6, lane = threadIdx.x & 63;
    int n = blockIdx.x*4 + wid;
    if(n >= NN) return;
    bool tail = lane < 11;
    const ushort4* xr4 = (const ushort4*)(x + (size_t)n*EHD);
    const float4* ai4 = (const float4*)aiw;
    ushort4 xv = xr4[lane];
    ushort4 xt = tail ? xr4[64+lane] : ushort4{0,0,0,0};
    float4 am = ai4[lane];
    float4 at = tail ? ai4[64+lane] : float4{0,0,0,0};
    float p = us2f(xv.x)*am.x + us2f(xv.y)*am.y + us2f(xv.z)*am.z + us2f(xv.w)*am.w;
    if(tail) p += us2f(xt.x)*at.x + us2f(xt.y)*at.y + us2f(xt.z)*at.z + us2f(xt.w)*at.w;
    p = wred_sum(p);
    int s0 = off[n], s1 = off[n+1], cnt = s1 - s0;
    float a0=0,a1=0,a2=0,a3=0, t0=0,t1=0,t2=0,t3=0;
    if(cnt > 0 && cnt <= 64){
        int jl = (lane < cnt) ? clampi(adjj[s0+lane], NN) : 0;
        float av = (lane < cnt) ? ajv[jl] : 0.f;
        float lg = p + av;
        lg = lg > 0 ? lg : 0.01f*lg;
        float mx = wred_max((lane < cnt) ? lg : -1e30f);
        float ex = (lane < cnt) ? expf(lg - mx) : 0.f;
        float ss = wred_sum(ex);
        float al = ex/ss;
        int it = 0;
        for(; it+4 <= cnt; it += 4){
            int j0=__shfl(jl,it), j1=__shfl(jl,it+1), j2=__shfl(jl,it+2), j3=__shfl(jl,it+3);
            float q0=__shfl(al,it), q1=__shfl(al,it+1), q2=__shfl(al,it+2), q3=__shfl(al,it+3);
            const ushort4* r0 = (const ushort4*)(x + (size_t)j0*EHD);
            const ushort4* r1 = (const ushort4*)(x + (size_t)j1*EHD);
            const ushort4* r2 = (const ushort4*)(x + (size_t)j2*EHD);
            const ushort4* r3 = (const ushort4*)(x + (size_t)j3*EHD);
            ushort4 v0=r0[lane], v1=r1[lane], v2=r2[lane], v3=r3[lane];
            a0 += q0*us2f(v0.x)+q1*us2f(v1.x)+q2*us2f(v2.x)+q3*us2f(v3.x);
            a1 += q0*us2f(v0.y)+q1*us2f(v1.y)+q2*us2f(v2.y)+q3*us2f(v3.y);
            a2 += q0*us2f(v0.z)+q1*us2f(v1.z)+q2*us2f(v2.z)+q3*us2f(v3.z);
            a3 += q0*us2f(v0.w)+q1*us2f(v1.w)+q2*us2f(v2.w)+q3*us2f(v3.w);
            if(tail){
                ushort4 u0=r0[64+lane], u1=r1[64+lane], u2=r2[64+lane], u3=r3[64+lane];
                t0 += q0*us2f(u0.x)+q1*us2f(u1.x)+q2*us2f(u2.x)+q3*us2f(u3.x);
                t1 += q0*us2f(u0.y)+q1*us2f(u1.y)+q2*us2f(u2.y)+q3*us2f(u3.y);
                t2 += q0*us2f(u0.z)+q1*us2f(u1.z)+q2*us2f(u2.z)+q3*us2f(u3.z);
                t3 += q0*us2f(u0.w)+q1*us2f(u1.w)+q2*us2f(u2.w)+q3*us2f(u3.w);
            }
        }
        for(; it < cnt; it++){
            int j0 = __shfl(jl, it);
            float q0 = __shfl(al, it);
            const ushort4* r0 = (const ushort4*)(x + (size_t)j0*EHD);
            ushort4 v0 = r0[lane];
            a0 += q0*us2f(v0.x); a1 += q0*us2f(v0.y); a2 += q0*us2f(v0.z); a3 += q0*us2f(v0.w);
            if(tail){
                ushort4 u0 = r0[64+lane];
                t0 += q0*us2f(u0.x); t1 += q0*us2f(u0.y); t2 += q0*us2f(u0.z); t3 += q0*us2f(u0.w);
            }
        }
    } else if(cnt > 64){
        float mx = -1e30f;
        for(int it=s0; it<s1; it++){
            float lg = p + ajv[clampi(adjj[it], NN)];
            lg = lg > 0 ? lg : 0.01f*lg;
            mx = fmaxf(mx, lg);
        }
        float ss = 0;
        for(int it=s0; it<s1; it++){
            float lg = p + ajv[clampi(adjj[it], NN)];
            lg = lg > 0 ? lg : 0.01f*lg;
            ss += expf(lg - mx);
        }
        for(int it=s0; it<s1; it++){
            int j = clampi(adjj[it], NN);
            float lg = p + ajv[j];
            lg = lg > 0 ? lg : 0.01f*lg;
            float a = expf(lg - mx)/ss;
            const ushort4* row = (const ushort4*)(x + (size_t)j*EHD);
            ushort4 v = row[lane];
            a0 += a*us2f(v.x); a1 += a*us2f(v.y); a2 += a*us2f(v.z); a3 += a*us2f(v.w);
            if(tail){
                ushort4 u = row[64+lane];
                t0 += a*us2f(u.x); t1 += a*us2f(u.y); t2 += a*us2f(u.z); t3 += a*us2f(u.w);
            }
        }
    }
    const float4* f4 = (const float4*)fcw;
    float4 f0 = f4[lane];
    float4 g0 = f4[75 + lane];
    float part = us2f(xv.x)*f0.x + us2f(xv.y)*f0.y + us2f(xv.z)*f0.z + us2f(xv.w)*f0.w
               + fmaxf(a0,0.f)*g0.x + fmaxf(a1,0.f)*g0.y + fmaxf(a2,0.f)*g0.z + fmaxf(a3,0.f)*g0.w;
    if(tail){
        float4 f1 = f4[64 + lane];
        float4 g1 = f4[139 + lane];
        part += us2f(xt.x)*f1.x + us2f(xt.y)*f1.y + us2f(xt.z)*f1.z + us2f(xt.w)*f1.w
              + fmaxf(t0,0.f)*g1.x + fmaxf(t1,0.f)*g1.y + fmaxf(t2,0.f)*g1.z + fmaxf(t3,0.f)*g1.w;
    }
    part = wred_sum(part);
    if(lane == 0) out[n] = part + fcb[0];
}

extern "C" void kernel_launch(void* const* d_in, const int* in_sizes, int n_in,
                              void* d_out, int out_size, void* d_ws, size_t ws_size,
                              hipStream_t stream){
    const float* x_in = (const float*)d_in[0];
    const int*  ht   = (const int*)d_in[1];
    const int*  rel  = (const int*)d_in[2];
    const int*  ji   = (const int*)d_in[3];
    const float* hw1w=(const float*)d_in[5];  const float* hw1b=(const float*)d_in[6];
    const float* hw2w=(const float*)d_in[7];  const float* hw2b=(const float*)d_in[8];
    const float* tc1w=(const float*)d_in[9];  const float* tc1b=(const float*)d_in[10];
    const float* sr1w=(const float*)d_in[11]; const float* sr1b=(const float*)d_in[12];
    const float* wrw =(const float*)d_in[15]; const float* wrb =(const float*)d_in[16];
    const float* wr1w=(const float*)d_in[17]; const float* wr1b=(const float*)d_in[18];
    const float* wr2w=(const float*)d_in[19]; const float* wr2b=(const float*)d_in[20];
    const float* ahw =(const float*)d_in[21]; const float* ah1w=(const float*)d_in[22];
    const float* atw =(const float*)d_in[23];
    const float* ar1 =(const float*)d_in[24]; const float* ar2 =(const float*)d_in[25];
    const float* ar3 =(const float*)d_in[26];
    const float* aiw =(const float*)d_in[27]; const float* ajw =(const float*)d_in[28];
    const float* fcw =(const float*)d_in[29]; const float* fcb =(const float*)d_in[30];
    float* out = (float*)d_out;

    char* w = (char*)d_ws;
    auto alloc = [&](size_t bytes)->char*{ char* p = w; w += (bytes + 255)/256*256; return p; };
    bf16* xF = (bf16*)alloc((size_t)NN*EHD*2);   // 30 MB
    bf16* B  = (bf16*)alloc((size_t)NN*EHD*2);   // 30 MB; CSR tmp -> gcn agg/x1 -> rel tables
    char* Bc = (char*)B;
    int2* tmp_all = (int2*)(Bc);                      // 4 MB
    int2* tmp_h   = (int2*)(Bc + 4u*1024*1024);       // 2 MB
    int2* tmp_t   = (int2*)(Bc + 8u*1024*1024);       // 2 MB
    int2* tmp_r   = (int2*)(Bc + 12u*1024*1024);      // 2 MB
    bf16*  sbuf = (bf16*)(Bc);                        // 10 MB
    float* RF   = (float*)(Bc + 11u*1024*1024);
    float* ER   = (float*)(Bc + 12u*1024*1024);
    float* cvec = (float*)(Bc + 14u*1024*1024);
    float* ajv  = (float*)(Bc + 15u*1024*1024);
    short* Wt1 = (short*)alloc((size_t)EHD*EHD*2);
    short* Wt2 = (short*)alloc((size_t)EHD*EHD*2);
    short* Wtc = (short*)alloc((size_t)EHD*THD*2);
    float* dinv = (float*)alloc((size_t)NN*4);
    int* off_all=(int*)alloc((NN+1)*4);
    int* adj_all=(int*)alloc((size_t)NEA*4);
    int* off_h  =(int*)alloc((NN+1)*4);
    int* adj_h  =(int*)alloc((size_t)NE*4);
    int* off_t  =(int*)alloc((NN+1)*4);
    int* adj_t  =(int*)alloc((size_t)NE*4);
    int* off_r  =(int*)alloc((NR+1)*4);
    int* adj_r  =(int*)alloc((size_t)NE*4);
    int* bcnt   =(int*)alloc(512*4);
    int* gbase  =(int*)alloc(4*129*4);
    int* gcur   =(int*)alloc(4*128*4);

    // prep (zero bcnt + cast x + transpose weights)
    const int NPREP = NN*EHD/4;
    k_prep<<<dim3((NPREP+255)/256), dim3(256), 0, stream>>>((const float4*)x_in, (ushort*)xF,
                                                            hw1w, hw2w, tc1w, Wt1, Wt2, Wtc, bcnt);
    // CSR build: bucket-count (LDS hist) -> scan -> bin -> place (off/dinv derived in-place)
    k_bincnt<<<dim3((NEA+2047)/2048, 4), dim3(256), 0, stream>>>(ji, ht, rel, bcnt);
    k_bscan<<<dim3(1), dim3(512), 0, stream>>>(bcnt, gbase, gcur);
    k_bin<<<dim3((NEA+2047)/2048, 4), dim3(256), 0, stream>>>(ji, ht, rel, gcur,
                                                              tmp_all, tmp_h, tmp_t, tmp_r);
    k_place<<<dim3(NBN, 4), dim3(256), 0, stream>>>(gbase, tmp_all, tmp_h, tmp_t, tmp_r,
                                                    off_all, off_h, off_t, off_r,
                                                    adj_all, adj_h, adj_t, adj_r, dinv);

    const int nb4 = (NN+3)/4;
    const dim3 gg((NN+63)/64, (EHD+63)/64);
    // highway 1: B = gcn(xF); B = sig(xF@hw1+b)*B + (1-sig)*xF
    k_gcn<<<dim3(nb4), dim3(256), 0, stream>>>(xF, B, off_all, adj_all, dinv);
    k_gemm_mfma<1><<<gg, dim3(256), 0, stream>>>(xF, Wt1, hw1b, B, xF, NN, EHD, EHD);
    // highway 2
    k_gcn<<<dim3(nb4), dim3(256), 0, stream>>>(B, xF, off_all, adj_all, dinv);
    k_gemm_mfma<1><<<gg, dim3(256), 0, stream>>>(B, Wt2, hw2b, xF, B, NN, EHD, EHD);
    // rel tables
    k_gemm_mfma<0><<<dim3((NN+63)/64, (THD+63)/64), dim3(256), 0, stream>>>(xF, Wtc, tc1b, sbuf, xF, NN, EHD, THD);
    k_zero_f32<<<dim3((NR*EHD+255)/256), dim3(256), 0, stream>>>(RF, NR*EHD);
    k_relsum2<<<dim3(NR, RCH), dim3(128), 0, stream>>>(sbuf, ht, off_r, adj_r, RF);
    k_relfin<<<dim3(NR), dim3(128), 0, stream>>>(sr1w, sr1b, off_r, RF);
    k_reler<<<dim3(NR, 3), dim3(256), 0, stream>>>(RF, wrw, wrb, wr1w, wr1b, wr2w, wr2b,
                                                   ar1, ar2, ar3, ER, cvec);
    // fused three r2e rounds + ajv
    k_r2e3<<<dim3(nb4), dim3(256), 0, stream>>>(xF, off_h, adj_h, off_t, adj_t, ER, cvec,
                                                ahw, atw, ah1w, ajw, ajv);
    // final GAT + fc
    k_final<<<dim3(nb4), dim3(256), 0, stream>>>(xF, ajv, off_all, adj_all, aiw, fcw, fcb, out);
}